// Round 1
// baseline (656.007 us; speedup 1.0000x reference)
//
#include <hip/hip_runtime.h>
#include <math.h>

// ---------------------------------------------------------------------------
// Swin/Uformer block, MI355X. Sizes fixed: B=4 H=W=256 C=96 NH=3 HD=32 WIN=8
// N=64 HID=384. 4 kernels:
//   kwconv : f32 weights -> bf16, pre-swizzled into MFMA B-fragment order
//   kattn  : LN1 + QKV + window-attn (+rpb bias, softmax) + proj + residual
//   kleff1 : LN2 + FC1 + GELU -> h1 (bf16)
//   kleff2 : depthwise 3x3 + GELU + FC2 + residual -> out
// MFMA 16x16x32 bf16 layouts used throughout:
//   A-frag: lane = (m%16) + 16*(k%32/8), elem = k%8
//   B-frag: lane = (n%16) + 16*(k%32/8), elem = k%8
//   C/D   : row  = 4*(lane/16)+reg, col = lane%16
// ---------------------------------------------------------------------------

typedef __attribute__((ext_vector_type(8))) short bf16x8;
typedef __attribute__((ext_vector_type(4))) float f32x4;

#define MFMA(a, b, c) __builtin_amdgcn_mfma_f32_16x16x32_bf16((a), (b), (c), 0, 0, 0)

// weight tile bases (in 16x32 B-fragment tiles of 64 lanes * 16B)
#define WQ_T 0
#define WKV_T 18
#define WP_T 54
#define W1_T 72
#define W2_T 144
#define NTILES_TOT 216

__device__ __forceinline__ unsigned short f2bf(float f) {
  union { float f; unsigned u; } v; v.f = f;
  unsigned r = v.u + 0x7FFFu + ((v.u >> 16) & 1u);
  return (unsigned short)(r >> 16);
}
__device__ __forceinline__ float bf2f(unsigned short b) {
  union { unsigned u; float f; } v; v.u = ((unsigned)b) << 16; return v.f;
}
__device__ __forceinline__ float gelu(float x) {
  return 0.5f * x * (1.f + erff(x * 0.70710678118654752f));
}
__device__ __forceinline__ bf16x8 ldw(const unsigned short* wswz, int tile, int lane) {
  return *(const bf16x8*)(wswz + ((size_t)(tile * 64 + lane)) * 8);
}

// --------------------------- weight convert/swizzle ------------------------
__global__ void kwconv(const float* __restrict__ wq, const float* __restrict__ wkv,
                       const float* __restrict__ wp, const float* __restrict__ w1,
                       const float* __restrict__ w2, unsigned short* __restrict__ wswz) {
  int tid = blockIdx.x * 256 + threadIdx.x;
  if (tid >= NTILES_TOT * 64) return;
  int e = tid; const float* src; int N, NT;
  if (e < 1152)      { src = wq;  N = 96;  NT = 6; }
  else if (e < 3456) { src = wkv; N = 192; NT = 12; e -= 1152; }
  else if (e < 4608) { src = wp;  N = 96;  NT = 6;  e -= 3456; }
  else if (e < 9216) { src = w1;  N = 384; NT = 24; e -= 4608; }
  else               { src = w2;  N = 96;  NT = 6;  e -= 9216; }
  int lane = e & 63, t = e >> 6;
  int nt = t % NT, kt = t / NT;
  int k0 = kt * 32 + (lane >> 4) * 8;
  int n = nt * 16 + (lane & 15);
  unsigned short* dst = wswz + (size_t)tid * 8;
#pragma unroll
  for (int i = 0; i < 8; ++i) dst[i] = f2bf(src[(size_t)(k0 + i) * N + n]);
}

// --------------------------- attention block -------------------------------
__global__ __launch_bounds__(256) void kattn(
    const float* __restrict__ x, const float* __restrict__ g1, const float* __restrict__ b1,
    const float* __restrict__ bq, const float* __restrict__ bkv,
    const float* __restrict__ rpb, const float* __restrict__ bp,
    const unsigned short* __restrict__ wswz, float* __restrict__ x2) {
  __shared__ __align__(16) unsigned short sm0[4 * 3 * 64 * 8];   // xn_swz, later y_swz (12KB)
  __shared__ __align__(16) unsigned short sm1[24 * 64 * 8];      // q(12 tiles)+k(12) then p(24) (24KB)
  __shared__ __align__(16) unsigned short sm2[3 * 2 * 2 * 64 * 8]; // v (12KB)

  const int tid = threadIdx.x;
  const int lane = tid & 63, w = tid >> 6;
  const int lrow = lane >> 4, lcol = lane & 15;
  const int wi = blockIdx.x;
  const int b = wi >> 10, wy = (wi >> 5) & 31, wx = wi & 31;

  long rowoff[4];
#pragma unroll
  for (int r = 0; r < 4; ++r) {
    int m = w * 16 + lrow * 4 + r;
    int gy = wy * 8 + (m >> 3), gx = wx * 8 + (m & 7);
    rowoff[r] = ((long)b * 65536 + gy * 256 + gx) * 96;
  }

  // ---- phase 0: load x (C/D-layout regs), LN1, write xn to A-swz LDS
  float xv[4][6], xn[4][6], gv[6], bv[6];
#pragma unroll
  for (int nt = 0; nt < 6; ++nt) {
    int c = nt * 16 + lcol;
    gv[nt] = g1[c]; bv[nt] = b1[c];
#pragma unroll
    for (int r = 0; r < 4; ++r) xv[r][nt] = x[rowoff[r] + c];
  }
#pragma unroll
  for (int r = 0; r < 4; ++r) {
    float s = 0.f, sq = 0.f;
#pragma unroll
    for (int nt = 0; nt < 6; ++nt) { float v = xv[r][nt]; s += v; sq += v * v; }
#pragma unroll
    for (int off = 1; off <= 8; off <<= 1) { s += __shfl_xor(s, off, 64); sq += __shfl_xor(sq, off, 64); }
    float mean = s * (1.f / 96.f);
    float var = sq * (1.f / 96.f) - mean * mean;
    float rs = rsqrtf(var + 1e-5f);
#pragma unroll
    for (int nt = 0; nt < 6; ++nt) xn[r][nt] = (xv[r][nt] - mean) * rs * gv[nt] + bv[nt];
  }
#pragma unroll
  for (int r = 0; r < 4; ++r) {
    int mm = lrow * 4 + r;
#pragma unroll
    for (int nt = 0; nt < 6; ++nt) {
      int c = nt * 16 + lcol;
      int kt = c >> 5;
      int lanew = mm + (((c & 31) >> 3) << 4);
      sm0[((w * 3 + kt) * 64 + lanew) * 8 + (c & 7)] = f2bf(xn[r][nt]);
    }
  }
  __syncthreads();

  // ---- phase 1: QKV GEMM (M=64 N=288 K=96), wave w owns m-tile w
  bf16x8 af[3];
#pragma unroll
  for (int kt = 0; kt < 3; ++kt) af[kt] = *(const bf16x8*)(sm0 + ((w * 3 + kt) * 64 + lane) * 8);
  for (int nt = 0; nt < 18; ++nt) {
    f32x4 acc = {0.f, 0.f, 0.f, 0.f};
#pragma unroll
    for (int kt = 0; kt < 3; ++kt) {
      int tile = (nt < 6) ? (WQ_T + kt * 6 + nt) : (WKV_T + kt * 12 + (nt - 6));
      acc = MFMA(af[kt], ldw(wswz, tile, lane), acc);
    }
    int c = nt * 16 + lcol;
#pragma unroll
    for (int r = 0; r < 4; ++r) {
      int m = w * 16 + lrow * 4 + r;
      float val = acc[r];
      if (c < 96) {                 // q (pre-scaled)
        val = (val + bq[c]) * 0.17677669529663687f;
        int head = c >> 5, d = c & 31;
        sm1[((head * 4 + w) * 64 + (m & 15) + ((d >> 3) << 4)) * 8 + (d & 7)] = f2bf(val);
      } else if (c < 192) {         // k
        int kc = c - 96;
        val += bkv[kc];
        int head = kc >> 5, d = kc & 31;
        sm1[((12 + head * 4 + w) * 64 + (m & 15) + ((d >> 3) << 4)) * 8 + (d & 7)] = f2bf(val);
      } else {                      // v (B-frag layout: k-dim = key token)
        int vc = c - 192;
        val += bkv[96 + vc];
        int head = vc >> 5, d = vc & 31;
        int ktile = m >> 5, nt2 = d >> 4;
        sm2[(((head * 2 + ktile) * 2 + nt2) * 64 + (d & 15) + (((m & 31) >> 3) << 4)) * 8 + (m & 7)] = f2bf(val);
      }
    }
  }
  __syncthreads();

  // ---- phase 2: scores. unit u=(head,mtq); wave w owns u = 3w..3w+2
  f32x4 sc[3][4];
#pragma unroll
  for (int uu = 0; uu < 3; ++uu) {
    int u = w * 3 + uu, head = u >> 2, mtq = u & 3;
    bf16x8 aq = *(const bf16x8*)(sm1 + ((head * 4 + mtq) * 64 + lane) * 8);
#pragma unroll
    for (int nt = 0; nt < 4; ++nt) {
      bf16x8 bk = *(const bf16x8*)(sm1 + ((12 + head * 4 + nt) * 64 + lane) * 8);
      f32x4 z = {0.f, 0.f, 0.f, 0.f};
      sc[uu][nt] = MFMA(aq, bk, z);
    }
  }
  __syncthreads();   // all q/k reads done; sm1 may now be overwritten with P

  // ---- phase 3: +rpb bias, softmax (in-register), write P to A-swz LDS
#pragma unroll
  for (int uu = 0; uu < 3; ++uu) {
    int u = w * 3 + uu, head = u >> 2, mtq = u & 3;
#pragma unroll
    for (int nt = 0; nt < 4; ++nt) {
      int ktok = nt * 16 + lcol;
#pragma unroll
      for (int r = 0; r < 4; ++r) {
        int qtok = mtq * 16 + lrow * 4 + r;
        int dy = (qtok >> 3) - (ktok >> 3) + 7;
        int dx = (qtok & 7) - (ktok & 7) + 7;
        sc[uu][nt][r] += rpb[(dy * 15 + dx) * 3 + head];
      }
    }
#pragma unroll
    for (int r = 0; r < 4; ++r) {
      float mx = fmaxf(fmaxf(sc[uu][0][r], sc[uu][1][r]), fmaxf(sc[uu][2][r], sc[uu][3][r]));
#pragma unroll
      for (int off = 1; off <= 8; off <<= 1) mx = fmaxf(mx, __shfl_xor(mx, off, 64));
      float p[4], sum = 0.f;
#pragma unroll
      for (int nt = 0; nt < 4; ++nt) { p[nt] = __expf(sc[uu][nt][r] - mx); sum += p[nt]; }
#pragma unroll
      for (int off = 1; off <= 8; off <<= 1) sum += __shfl_xor(sum, off, 64);
      float inv = 1.f / sum;
#pragma unroll
      for (int nt = 0; nt < 4; ++nt) sc[uu][nt][r] = p[nt] * inv;
    }
#pragma unroll
    for (int nt = 0; nt < 4; ++nt) {
      int ktok = nt * 16 + lcol;
      int ktile = ktok >> 5, lhi = (ktok & 31) >> 3;
#pragma unroll
      for (int r = 0; r < 4; ++r) {
        int mm = lrow * 4 + r;
        sm1[(((head * 4 + mtq) * 2 + ktile) * 64 + mm + (lhi << 4)) * 8 + (ktok & 7)] = f2bf(sc[uu][nt][r]);
      }
    }
  }
  __syncthreads();

  // ---- phase 4: PV, write y to A-swz LDS (reuse sm0; head = k-tile)
#pragma unroll
  for (int uu = 0; uu < 3; ++uu) {
    int u = w * 3 + uu, head = u >> 2, mtq = u & 3;
#pragma unroll
    for (int nt2 = 0; nt2 < 2; ++nt2) {
      f32x4 acc = {0.f, 0.f, 0.f, 0.f};
#pragma unroll
      for (int ktile = 0; ktile < 2; ++ktile) {
        bf16x8 ap = *(const bf16x8*)(sm1 + (((head * 4 + mtq) * 2 + ktile) * 64 + lane) * 8);
        bf16x8 bv8 = *(const bf16x8*)(sm2 + (((head * 2 + ktile) * 2 + nt2) * 64 + lane) * 8);
        acc = MFMA(ap, bv8, acc);
      }
      int d0 = nt2 * 16 + lcol;
#pragma unroll
      for (int r = 0; r < 4; ++r) {
        int mm = lrow * 4 + r;
        sm0[((mtq * 3 + head) * 64 + mm + ((d0 >> 3) << 4)) * 8 + (d0 & 7)] = f2bf(acc[r]);
      }
    }
  }
  __syncthreads();

  // ---- phase 5: proj + bias + residual -> x2
  bf16x8 ay[3];
#pragma unroll
  for (int kt = 0; kt < 3; ++kt) ay[kt] = *(const bf16x8*)(sm0 + ((w * 3 + kt) * 64 + lane) * 8);
#pragma unroll
  for (int nt = 0; nt < 6; ++nt) {
    f32x4 acc = {0.f, 0.f, 0.f, 0.f};
#pragma unroll
    for (int kt = 0; kt < 3; ++kt) acc = MFMA(ay[kt], ldw(wswz, WP_T + kt * 6 + nt, lane), acc);
    int c = nt * 16 + lcol;
    float bpc = bp[c];
#pragma unroll
    for (int r = 0; r < 4; ++r) x2[rowoff[r] + c] = acc[r] + bpc + xv[r][nt];
  }
}

// --------------------------- LN2 + FC1 + GELU ------------------------------
__global__ __launch_bounds__(256) void kleff1(
    const float* __restrict__ x2, const float* __restrict__ g2, const float* __restrict__ b2,
    const float* __restrict__ bl1, const unsigned short* __restrict__ wswz,
    unsigned short* __restrict__ h1) {
  __shared__ __align__(16) unsigned short sm0[4 * 3 * 64 * 8];
  const int tid = threadIdx.x, lane = tid & 63, w = tid >> 6;
  const int lrow = lane >> 4, lcol = lane & 15;
  const long tbase = (long)blockIdx.x * 64;

  float xv[4][6], gv[6], bv[6];
#pragma unroll
  for (int nt = 0; nt < 6; ++nt) {
    int c = nt * 16 + lcol;
    gv[nt] = g2[c]; bv[nt] = b2[c];
#pragma unroll
    for (int r = 0; r < 4; ++r) xv[r][nt] = x2[(tbase + w * 16 + lrow * 4 + r) * 96 + c];
  }
#pragma unroll
  for (int r = 0; r < 4; ++r) {
    float s = 0.f, sq = 0.f;
#pragma unroll
    for (int nt = 0; nt < 6; ++nt) { float v = xv[r][nt]; s += v; sq += v * v; }
#pragma unroll
    for (int off = 1; off <= 8; off <<= 1) { s += __shfl_xor(s, off, 64); sq += __shfl_xor(sq, off, 64); }
    float mean = s * (1.f / 96.f);
    float var = sq * (1.f / 96.f) - mean * mean;
    float rs = rsqrtf(var + 1e-5f);
#pragma unroll
    for (int nt = 0; nt < 6; ++nt) xv[r][nt] = (xv[r][nt] - mean) * rs * gv[nt] + bv[nt];
  }
#pragma unroll
  for (int r = 0; r < 4; ++r) {
    int mm = lrow * 4 + r;
#pragma unroll
    for (int nt = 0; nt < 6; ++nt) {
      int c = nt * 16 + lcol;
      int kt = c >> 5;
      int lanew = mm + (((c & 31) >> 3) << 4);
      sm0[((w * 3 + kt) * 64 + lanew) * 8 + (c & 7)] = f2bf(xv[r][nt]);
    }
  }
  __syncthreads();

  bf16x8 af[3];
#pragma unroll
  for (int kt = 0; kt < 3; ++kt) af[kt] = *(const bf16x8*)(sm0 + ((w * 3 + kt) * 64 + lane) * 8);
  for (int nt = 0; nt < 24; ++nt) {
    f32x4 acc = {0.f, 0.f, 0.f, 0.f};
#pragma unroll
    for (int kt = 0; kt < 3; ++kt) acc = MFMA(af[kt], ldw(wswz, W1_T + kt * 24 + nt, lane), acc);
    int c = nt * 16 + lcol;
    float bb = bl1[c];
#pragma unroll
    for (int r = 0; r < 4; ++r) {
      int m = w * 16 + lrow * 4 + r;
      h1[(tbase + m) * 384 + c] = f2bf(gelu(acc[r] + bb));
    }
  }
}

// --------------- depthwise 3x3 + GELU + FC2 + residual ---------------------
__global__ __launch_bounds__(256) void kleff2(
    const unsigned short* __restrict__ h1, const float* __restrict__ wdw,
    const float* __restrict__ bdw, const float* __restrict__ bl2,
    const unsigned short* __restrict__ wswz, const float* __restrict__ x2,
    float* __restrict__ out) {
  __shared__ __align__(16) unsigned short stage[100 * 192];     // 10x10 halo, 192 ch half
  __shared__ __align__(16) unsigned short xswz[4 * 6 * 64 * 8]; // conv out, A-swz
  const int tid = threadIdx.x, lane = tid & 63, w = tid >> 6;
  const int lrow = lane >> 4, lcol = lane & 15;
  const int bid = blockIdx.x;
  const int b = bid >> 10, ty0 = ((bid >> 5) & 31) * 8, tx0 = (bid & 31) * 8;

  f32x4 acc[6];
#pragma unroll
  for (int nt = 0; nt < 6; ++nt) { f32x4 z = {0.f, 0.f, 0.f, 0.f}; acc[nt] = z; }

  for (int hf = 0; hf < 2; ++hf) {
    // stage 10x10 x 192ch halo tile (zero-padded at image edges)
    for (int idx = tid; idx < 2400; idx += 256) {
      int p = idx / 24, ch = (idx % 24) * 8;
      int gy = ty0 + p / 10 - 1, gx = tx0 + p % 10 - 1;
      uint4 v = make_uint4(0, 0, 0, 0);
      if ((unsigned)gy < 256u && (unsigned)gx < 256u)
        v = *(const uint4*)(h1 + (((long)b * 65536 + gy * 256 + gx) * 384 + hf * 192 + ch));
      *(uint4*)(stage + p * 192 + ch) = v;
    }
    __syncthreads();
    // depthwise conv + bias + gelu, write straight into A-frag slots
#pragma unroll
    for (int j = 0; j < 6; ++j) {
      int e = tid + 256 * j;
      int el = e & 63, t = e >> 6;
      int kt = t % 6, mt = t / 6;
      int m = mt * 16 + (el & 15);
      int ko = kt * 32 + (el >> 4) * 8;
      int tyy = m >> 3, txx = m & 7;
      int cg = hf * 192 + ko;
      float a8[8];
#pragma unroll
      for (int i = 0; i < 8; ++i) a8[i] = 0.f;
#pragma unroll
      for (int dy = 0; dy < 3; ++dy)
#pragma unroll
        for (int dx = 0; dx < 3; ++dx) {
          const unsigned short* s8 = stage + ((tyy + dy) * 10 + (txx + dx)) * 192 + ko;
          int tap = dy * 3 + dx;
#pragma unroll
          for (int i = 0; i < 8; ++i) a8[i] += bf2f(s8[i]) * wdw[(cg + i) * 9 + tap];
        }
      union { unsigned short s[8]; uint4 v; } o;
#pragma unroll
      for (int i = 0; i < 8; ++i) o.s[i] = f2bf(gelu(a8[i] + bdw[cg + i]));
      *(uint4*)(xswz + ((mt * 6 + kt) * 64 + el) * 8) = o.v;
    }
    __syncthreads();
    // FC2 partial GEMM over this half's 6 k-tiles
#pragma unroll
    for (int kt = 0; kt < 6; ++kt) {
      bf16x8 a = *(const bf16x8*)(xswz + ((w * 6 + kt) * 64 + lane) * 8);
      int ktg = hf * 6 + kt;
#pragma unroll
      for (int nt = 0; nt < 6; ++nt)
        acc[nt] = MFMA(a, ldw(wswz, W2_T + ktg * 6 + nt, lane), acc[nt]);
    }
    __syncthreads();
  }
  // epilogue: + bl2 + residual(x2) -> out
#pragma unroll
  for (int nt = 0; nt < 6; ++nt) {
    int c = nt * 16 + lcol;
    float bb = bl2[c];
#pragma unroll
    for (int r = 0; r < 4; ++r) {
      int m = w * 16 + lrow * 4 + r;
      int gy = ty0 + (m >> 3), gx = tx0 + (m & 7);
      long row = (long)b * 65536 + gy * 256 + gx;
      out[row * 96 + c] = acc[nt][r] + bb + x2[row * 96 + c];
    }
  }
}

// ---------------------------------------------------------------------------
extern "C" void kernel_launch(void* const* d_in, const int* in_sizes, int n_in,
                              void* d_out, int out_size, void* d_ws, size_t ws_size,
                              hipStream_t stream) {
  const float* x   = (const float*)d_in[0];
  const float* g1  = (const float*)d_in[1];
  const float* b1  = (const float*)d_in[2];
  const float* wq  = (const float*)d_in[3];
  const float* bq  = (const float*)d_in[4];
  const float* wkv = (const float*)d_in[5];
  const float* bkv = (const float*)d_in[6];
  const float* rpb = (const float*)d_in[7];
  const float* wp  = (const float*)d_in[8];
  const float* bp  = (const float*)d_in[9];
  const float* g2  = (const float*)d_in[10];
  const float* b2  = (const float*)d_in[11];
  const float* w1  = (const float*)d_in[12];
  const float* bl1 = (const float*)d_in[13];
  const float* wdw = (const float*)d_in[14];
  const float* bdw = (const float*)d_in[15];
  const float* w2  = (const float*)d_in[16];
  const float* bl2 = (const float*)d_in[17];

  char* ws = (char*)d_ws;
  unsigned short* wswz = (unsigned short*)ws;                       // 221 KB
  float* x2 = (float*)(ws + (size_t)(4 << 20));                    // 100.7 MB
  unsigned short* h1 = (unsigned short*)(ws + (size_t)(4 << 20) + 100663296); // 201.3 MB
  float* outp = (float*)d_out;

  kwconv<<<54, 256, 0, stream>>>(wq, wkv, wp, w1, w2, wswz);
  kattn<<<4096, 256, 0, stream>>>(x, g1, b1, bq, bkv, rpb, bp, wswz, x2);
  kleff1<<<4096, 256, 0, stream>>>(x2, g2, b2, bl1, wswz, h1);
  kleff2<<<4096, 256, 0, stream>>>(h1, wdw, bdw, bl2, wswz, x2, outp);
}

// Round 2
// 627.571 us; speedup vs baseline: 1.0453x; 1.0453x over previous
//
#include <hip/hip_runtime.h>
#include <math.h>

// ---------------------------------------------------------------------------
// Swin/Uformer block, MI355X. Sizes fixed: B=4 H=W=256 C=96 NH=3 HD=32 WIN=8
// N=64 HID=384. 4 kernels:
//   kwconv : f32 weights -> bf16, pre-swizzled into MFMA B-fragment order
//   kattn  : LN1 + QKV + window-attn (+rpb bias, softmax) + proj + residual
//   kleff1 : LN2 + FC1 + GELU -> h1 (bf16), stores transposed through LDS
//   kleff2 : depthwise 3x3 + GELU + FC2 + residual, channel-quartered
// MFMA 16x16x32 bf16 layouts used throughout:
//   A-frag: lane = (m%16) + 16*(k%32/8), elem = k%8
//   B-frag: lane = (n%16) + 16*(k%32/8), elem = k%8
//   C/D   : row  = 4*(lane/16)+reg, col = lane%16
// ---------------------------------------------------------------------------

typedef __attribute__((ext_vector_type(8))) short bf16x8;
typedef __attribute__((ext_vector_type(4))) float f32x4;

#define MFMA(a, b, c) __builtin_amdgcn_mfma_f32_16x16x32_bf16((a), (b), (c), 0, 0, 0)

// weight tile bases (in 16x32 B-fragment tiles of 64 lanes * 16B)
#define WQ_T 0
#define WKV_T 18
#define WP_T 54
#define W1_T 72
#define W2_T 144
#define NTILES_TOT 216

__device__ __forceinline__ unsigned short f2bf(float f) {
  union { float f; unsigned u; } v; v.f = f;
  unsigned r = v.u + 0x7FFFu + ((v.u >> 16) & 1u);
  return (unsigned short)(r >> 16);
}
__device__ __forceinline__ float bf2f(unsigned short b) {
  union { unsigned u; float f; } v; v.u = ((unsigned)b) << 16; return v.f;
}
__device__ __forceinline__ float asf(unsigned u) {
  union { unsigned u; float f; } v; v.u = u; return v.f;
}
// tanh-form GELU via hardware exp; max abs deviation from exact ~3e-4
__device__ __forceinline__ float gelu(float x) {
  float z = 0.7978845608028654f * x * (1.f + 0.044715f * x * x);
  float a = __expf(-2.f * fabsf(z));
  float t = (1.f - a) / (1.f + a);
  t = copysignf(t, x);
  return 0.5f * x * (1.f + t);
}
__device__ __forceinline__ bf16x8 ldw(const unsigned short* wswz, int tile, int lane) {
  return *(const bf16x8*)(wswz + ((size_t)(tile * 64 + lane)) * 8);
}

// --------------------------- weight convert/swizzle ------------------------
__global__ void kwconv(const float* __restrict__ wq, const float* __restrict__ wkv,
                       const float* __restrict__ wp, const float* __restrict__ w1,
                       const float* __restrict__ w2, unsigned short* __restrict__ wswz) {
  int tid = blockIdx.x * 256 + threadIdx.x;
  if (tid >= NTILES_TOT * 64) return;
  int e = tid; const float* src; int N, NT;
  if (e < 1152)      { src = wq;  N = 96;  NT = 6; }
  else if (e < 3456) { src = wkv; N = 192; NT = 12; e -= 1152; }
  else if (e < 4608) { src = wp;  N = 96;  NT = 6;  e -= 3456; }
  else if (e < 9216) { src = w1;  N = 384; NT = 24; e -= 4608; }
  else               { src = w2;  N = 96;  NT = 6;  e -= 9216; }
  int lane = e & 63, t = e >> 6;
  int nt = t % NT, kt = t / NT;
  int k0 = kt * 32 + (lane >> 4) * 8;
  int n = nt * 16 + (lane & 15);
  unsigned short* dst = wswz + (size_t)tid * 8;
#pragma unroll
  for (int i = 0; i < 8; ++i) dst[i] = f2bf(src[(size_t)(k0 + i) * N + n]);
}

// --------------------------- attention block -------------------------------
__global__ __launch_bounds__(256) void kattn(
    const float* __restrict__ x, const float* __restrict__ g1, const float* __restrict__ b1,
    const float* __restrict__ bq, const float* __restrict__ bkv,
    const float* __restrict__ rpb, const float* __restrict__ bp,
    const unsigned short* __restrict__ wswz, float* __restrict__ x2) {
  __shared__ __align__(16) unsigned short sm0[4 * 3 * 64 * 8];   // xn_swz, later y_swz (12KB)
  __shared__ __align__(16) unsigned short sm1[24 * 64 * 8];      // q(12 tiles)+k(12) then p(24) (24KB)
  __shared__ __align__(16) unsigned short sm2[3 * 2 * 2 * 64 * 8]; // v (12KB)

  const int tid = threadIdx.x;
  const int lane = tid & 63, w = tid >> 6;
  const int lrow = lane >> 4, lcol = lane & 15;
  const int wi = blockIdx.x;
  const int b = wi >> 10, wy = (wi >> 5) & 31, wx = wi & 31;

  long rowoff[4];
#pragma unroll
  for (int r = 0; r < 4; ++r) {
    int m = w * 16 + lrow * 4 + r;
    int gy = wy * 8 + (m >> 3), gx = wx * 8 + (m & 7);
    rowoff[r] = ((long)b * 65536 + gy * 256 + gx) * 96;
  }

  // ---- phase 0: load x (C/D-layout regs), LN1, write xn to A-swz LDS
  float xv[4][6], xn[4][6], gv[6], bv[6];
#pragma unroll
  for (int nt = 0; nt < 6; ++nt) {
    int c = nt * 16 + lcol;
    gv[nt] = g1[c]; bv[nt] = b1[c];
#pragma unroll
    for (int r = 0; r < 4; ++r) xv[r][nt] = x[rowoff[r] + c];
  }
#pragma unroll
  for (int r = 0; r < 4; ++r) {
    float s = 0.f, sq = 0.f;
#pragma unroll
    for (int nt = 0; nt < 6; ++nt) { float v = xv[r][nt]; s += v; sq += v * v; }
#pragma unroll
    for (int off = 1; off <= 8; off <<= 1) { s += __shfl_xor(s, off, 64); sq += __shfl_xor(sq, off, 64); }
    float mean = s * (1.f / 96.f);
    float var = sq * (1.f / 96.f) - mean * mean;
    float rs = rsqrtf(var + 1e-5f);
#pragma unroll
    for (int nt = 0; nt < 6; ++nt) xn[r][nt] = (xv[r][nt] - mean) * rs * gv[nt] + bv[nt];
  }
#pragma unroll
  for (int r = 0; r < 4; ++r) {
    int mm = lrow * 4 + r;
#pragma unroll
    for (int nt = 0; nt < 6; ++nt) {
      int c = nt * 16 + lcol;
      int kt = c >> 5;
      int lanew = mm + (((c & 31) >> 3) << 4);
      sm0[((w * 3 + kt) * 64 + lanew) * 8 + (c & 7)] = f2bf(xn[r][nt]);
    }
  }
  __syncthreads();

  // ---- phase 1: QKV GEMM (M=64 N=288 K=96), wave w owns m-tile w
  bf16x8 af[3];
#pragma unroll
  for (int kt = 0; kt < 3; ++kt) af[kt] = *(const bf16x8*)(sm0 + ((w * 3 + kt) * 64 + lane) * 8);
  for (int nt = 0; nt < 18; ++nt) {
    f32x4 acc = {0.f, 0.f, 0.f, 0.f};
#pragma unroll
    for (int kt = 0; kt < 3; ++kt) {
      int tile = (nt < 6) ? (WQ_T + kt * 6 + nt) : (WKV_T + kt * 12 + (nt - 6));
      acc = MFMA(af[kt], ldw(wswz, tile, lane), acc);
    }
    int c = nt * 16 + lcol;
#pragma unroll
    for (int r = 0; r < 4; ++r) {
      int m = w * 16 + lrow * 4 + r;
      float val = acc[r];
      if (c < 96) {                 // q (pre-scaled)
        val = (val + bq[c]) * 0.17677669529663687f;
        int head = c >> 5, d = c & 31;
        sm1[((head * 4 + w) * 64 + (m & 15) + ((d >> 3) << 4)) * 8 + (d & 7)] = f2bf(val);
      } else if (c < 192) {         // k
        int kc = c - 96;
        val += bkv[kc];
        int head = kc >> 5, d = kc & 31;
        sm1[((12 + head * 4 + w) * 64 + (m & 15) + ((d >> 3) << 4)) * 8 + (d & 7)] = f2bf(val);
      } else {                      // v (B-frag layout: k-dim = key token)
        int vc = c - 192;
        val += bkv[96 + vc];
        int head = vc >> 5, d = vc & 31;
        int ktile = m >> 5, nt2 = d >> 4;
        sm2[(((head * 2 + ktile) * 2 + nt2) * 64 + (d & 15) + (((m & 31) >> 3) << 4)) * 8 + (m & 7)] = f2bf(val);
      }
    }
  }
  __syncthreads();

  // ---- phase 2: scores. unit u=(head,mtq); wave w owns u = 3w..3w+2
  f32x4 sc[3][4];
#pragma unroll
  for (int uu = 0; uu < 3; ++uu) {
    int u = w * 3 + uu, head = u >> 2, mtq = u & 3;
    bf16x8 aq = *(const bf16x8*)(sm1 + ((head * 4 + mtq) * 64 + lane) * 8);
#pragma unroll
    for (int nt = 0; nt < 4; ++nt) {
      bf16x8 bk = *(const bf16x8*)(sm1 + ((12 + head * 4 + nt) * 64 + lane) * 8);
      f32x4 z = {0.f, 0.f, 0.f, 0.f};
      sc[uu][nt] = MFMA(aq, bk, z);
    }
  }
  __syncthreads();   // all q/k reads done; sm1 may now be overwritten with P

  // ---- phase 3: +rpb bias, softmax (in-register), write P to A-swz LDS
#pragma unroll
  for (int uu = 0; uu < 3; ++uu) {
    int u = w * 3 + uu, head = u >> 2, mtq = u & 3;
#pragma unroll
    for (int nt = 0; nt < 4; ++nt) {
      int ktok = nt * 16 + lcol;
#pragma unroll
      for (int r = 0; r < 4; ++r) {
        int qtok = mtq * 16 + lrow * 4 + r;
        int dy = (qtok >> 3) - (ktok >> 3) + 7;
        int dx = (qtok & 7) - (ktok & 7) + 7;
        sc[uu][nt][r] += rpb[(dy * 15 + dx) * 3 + head];
      }
    }
#pragma unroll
    for (int r = 0; r < 4; ++r) {
      float mx = fmaxf(fmaxf(sc[uu][0][r], sc[uu][1][r]), fmaxf(sc[uu][2][r], sc[uu][3][r]));
#pragma unroll
      for (int off = 1; off <= 8; off <<= 1) mx = fmaxf(mx, __shfl_xor(mx, off, 64));
      float p[4], sum = 0.f;
#pragma unroll
      for (int nt = 0; nt < 4; ++nt) { p[nt] = __expf(sc[uu][nt][r] - mx); sum += p[nt]; }
#pragma unroll
      for (int off = 1; off <= 8; off <<= 1) sum += __shfl_xor(sum, off, 64);
      float inv = 1.f / sum;
#pragma unroll
      for (int nt = 0; nt < 4; ++nt) sc[uu][nt][r] = p[nt] * inv;
    }
#pragma unroll
    for (int nt = 0; nt < 4; ++nt) {
      int ktok = nt * 16 + lcol;
      int ktile = ktok >> 5, lhi = (ktok & 31) >> 3;
#pragma unroll
      for (int r = 0; r < 4; ++r) {
        int mm = lrow * 4 + r;
        sm1[(((head * 4 + mtq) * 2 + ktile) * 64 + mm + (lhi << 4)) * 8 + (ktok & 7)] = f2bf(sc[uu][nt][r]);
      }
    }
  }
  __syncthreads();

  // ---- phase 4: PV, write y to A-swz LDS (reuse sm0; head = k-tile)
#pragma unroll
  for (int uu = 0; uu < 3; ++uu) {
    int u = w * 3 + uu, head = u >> 2, mtq = u & 3;
#pragma unroll
    for (int nt2 = 0; nt2 < 2; ++nt2) {
      f32x4 acc = {0.f, 0.f, 0.f, 0.f};
#pragma unroll
      for (int ktile = 0; ktile < 2; ++ktile) {
        bf16x8 ap = *(const bf16x8*)(sm1 + (((head * 4 + mtq) * 2 + ktile) * 64 + lane) * 8);
        bf16x8 bv8 = *(const bf16x8*)(sm2 + (((head * 2 + ktile) * 2 + nt2) * 64 + lane) * 8);
        acc = MFMA(ap, bv8, acc);
      }
      int d0 = nt2 * 16 + lcol;
#pragma unroll
      for (int r = 0; r < 4; ++r) {
        int mm = lrow * 4 + r;
        sm0[((mtq * 3 + head) * 64 + mm + ((d0 >> 3) << 4)) * 8 + (d0 & 7)] = f2bf(acc[r]);
      }
    }
  }
  __syncthreads();

  // ---- phase 5: proj + bias + residual -> x2
  bf16x8 ay[3];
#pragma unroll
  for (int kt = 0; kt < 3; ++kt) ay[kt] = *(const bf16x8*)(sm0 + ((w * 3 + kt) * 64 + lane) * 8);
#pragma unroll
  for (int nt = 0; nt < 6; ++nt) {
    f32x4 acc = {0.f, 0.f, 0.f, 0.f};
#pragma unroll
    for (int kt = 0; kt < 3; ++kt) acc = MFMA(ay[kt], ldw(wswz, WP_T + kt * 6 + nt, lane), acc);
    int c = nt * 16 + lcol;
    float bpc = bp[c];
#pragma unroll
    for (int r = 0; r < 4; ++r) x2[rowoff[r] + c] = acc[r] + bpc + xv[r][nt];
  }
}

// --------------------------- LN2 + FC1 + GELU ------------------------------
__global__ __launch_bounds__(256) void kleff1(
    const float* __restrict__ x2, const float* __restrict__ g2, const float* __restrict__ b2,
    const float* __restrict__ bl1, const unsigned short* __restrict__ wswz,
    unsigned short* __restrict__ h1) {
  __shared__ __align__(16) unsigned short sm0[4 * 3 * 64 * 8];   // 12.3KB
  __shared__ __align__(16) unsigned short trbuf[64 * 200];       // 25.6KB (192ch half, +8 pad)
  const int tid = threadIdx.x, lane = tid & 63, w = tid >> 6;
  const int lrow = lane >> 4, lcol = lane & 15;
  const long tbase = (long)blockIdx.x * 64;

  float xv[4][6], gv[6], bv[6];
#pragma unroll
  for (int nt = 0; nt < 6; ++nt) {
    int c = nt * 16 + lcol;
    gv[nt] = g2[c]; bv[nt] = b2[c];
#pragma unroll
    for (int r = 0; r < 4; ++r) xv[r][nt] = x2[(tbase + w * 16 + lrow * 4 + r) * 96 + c];
  }
#pragma unroll
  for (int r = 0; r < 4; ++r) {
    float s = 0.f, sq = 0.f;
#pragma unroll
    for (int nt = 0; nt < 6; ++nt) { float v = xv[r][nt]; s += v; sq += v * v; }
#pragma unroll
    for (int off = 1; off <= 8; off <<= 1) { s += __shfl_xor(s, off, 64); sq += __shfl_xor(sq, off, 64); }
    float mean = s * (1.f / 96.f);
    float var = sq * (1.f / 96.f) - mean * mean;
    float rs = rsqrtf(var + 1e-5f);
#pragma unroll
    for (int nt = 0; nt < 6; ++nt) xv[r][nt] = (xv[r][nt] - mean) * rs * gv[nt] + bv[nt];
  }
#pragma unroll
  for (int r = 0; r < 4; ++r) {
    int mm = lrow * 4 + r;
#pragma unroll
    for (int nt = 0; nt < 6; ++nt) {
      int c = nt * 16 + lcol;
      int kt = c >> 5;
      int lanew = mm + (((c & 31) >> 3) << 4);
      sm0[((w * 3 + kt) * 64 + lanew) * 8 + (c & 7)] = f2bf(xv[r][nt]);
    }
  }
  __syncthreads();

  bf16x8 af[3];
#pragma unroll
  for (int kt = 0; kt < 3; ++kt) af[kt] = *(const bf16x8*)(sm0 + ((w * 3 + kt) * 64 + lane) * 8);

  for (int half = 0; half < 2; ++half) {
#pragma unroll
    for (int nt2 = 0; nt2 < 12; ++nt2) {
      int nt = half * 12 + nt2;
      f32x4 acc = {0.f, 0.f, 0.f, 0.f};
#pragma unroll
      for (int kt = 0; kt < 3; ++kt) acc = MFMA(af[kt], ldw(wswz, W1_T + kt * 24 + nt, lane), acc);
      int cl = nt2 * 16 + lcol;                 // 0..191 within half
      float bb = bl1[half * 192 + cl];
#pragma unroll
      for (int r = 0; r < 4; ++r) {
        int m = w * 16 + lrow * 4 + r;
        trbuf[m * 200 + cl] = f2bf(gelu(acc[r] + bb));
      }
    }
    __syncthreads();
    // coalesced writeout: 1536 x 16B chunks
#pragma unroll
    for (int j = 0; j < 6; ++j) {
      int idx = tid + j * 256;
      int token = idx / 24, c0 = (idx % 24) * 8;
      uint4 v = *(const uint4*)(trbuf + token * 200 + c0);
      *(uint4*)(h1 + (tbase + token) * 384 + half * 192 + c0) = v;
    }
    __syncthreads();
  }
}

// --------------- depthwise 3x3 + GELU + FC2 + residual ---------------------
// channel-quartered: 96 ch per pass; LDS 38.8KB -> 4 blocks/CU
__global__ __launch_bounds__(256) void kleff2(
    const unsigned short* __restrict__ h1, const float* __restrict__ wdw,
    const float* __restrict__ bdw, const float* __restrict__ bl2,
    const unsigned short* __restrict__ wswz, const float* __restrict__ x2,
    float* __restrict__ out) {
  __shared__ __align__(16) unsigned short stage[12 * 101 * 8];  // 19.4KB: [g][pix][8ch]
  __shared__ __align__(16) unsigned short xswz[12 * 520];       // 12.5KB: A-frag tiles, pad 8
  __shared__ __align__(16) unsigned short wdwb[9 * 384];        // 6.9KB: [tap][ch] bf16
  const int tid = threadIdx.x, lane = tid & 63, w = tid >> 6;
  const int lrow = lane >> 4, lcol = lane & 15;
  const int bid = blockIdx.x;
  const int b = bid >> 10, ty0 = ((bid >> 5) & 31) * 8, tx0 = (bid & 31) * 8;

  // stage depthwise weights transposed [tap][384] once
  for (int idx = tid; idx < 3456; idx += 256) {
    int ch = idx / 9, tap = idx - ch * 9;
    wdwb[tap * 384 + ch] = f2bf(wdw[idx]);
  }

  f32x4 acc[6];
#pragma unroll
  for (int nt = 0; nt < 6; ++nt) { f32x4 z = {0.f, 0.f, 0.f, 0.f}; acc[nt] = z; }

  const int m = lane;                    // token this thread convolves
  const int tyy = m >> 3, txx = m & 7;

  for (int q = 0; q < 4; ++q) {
    __syncthreads();                     // wdwb ready (q=0) / xswz reads done (q>0)
    // ---- stage 10x10 halo, 96 ch, layout [g][pix][8]
    for (int idx = tid; idx < 1200; idx += 256) {
      int p = idx / 12, g = idx - p * 12;
      int gy = ty0 + p / 10 - 1, gx = tx0 + p % 10 - 1;
      uint4 v = make_uint4(0, 0, 0, 0);
      if ((unsigned)gy < 256u && (unsigned)gx < 256u)
        v = *(const uint4*)(h1 + (((long)b * 65536 + gy * 256 + gx) * 384 + q * 96 + g * 8));
      *(uint4*)(stage + (g * 101 + p) * 8) = v;
    }
    __syncthreads();
    // ---- depthwise conv + bias + gelu -> xswz (A-frag layout)
#pragma unroll
    for (int jj = 0; jj < 3; ++jj) {
      int g = jj * 4 + w;                // channel group 0..11 (8ch)
      int cg = q * 96 + g * 8;
      float a8[8];
#pragma unroll
      for (int i = 0; i < 8; ++i) a8[i] = 0.f;
#pragma unroll
      for (int dy = 0; dy < 3; ++dy)
#pragma unroll
        for (int dx = 0; dx < 3; ++dx) {
          uint4 dv = *(const uint4*)(stage + (g * 101 + (tyy + dy) * 10 + (txx + dx)) * 8);
          uint4 wv = *(const uint4*)(wdwb + (dy * 3 + dx) * 384 + cg);
          const unsigned* du = (const unsigned*)&dv;
          const unsigned* wu = (const unsigned*)&wv;
#pragma unroll
          for (int j = 0; j < 4; ++j) {
            a8[2 * j]     = fmaf(asf(du[j] << 16), asf(wu[j] << 16), a8[2 * j]);
            a8[2 * j + 1] = fmaf(asf(du[j] & 0xffff0000u), asf(wu[j] & 0xffff0000u), a8[2 * j + 1]);
          }
        }
      union { unsigned short s[8]; uint4 v; } o;
#pragma unroll
      for (int i = 0; i < 8; ++i) o.s[i] = f2bf(gelu(a8[i] + bdw[cg + i]));
      // A-frag slot: mt = m>>4, kt = g>>2, lane_a = (m&15)+((g&3)<<4), elems = 8ch
      *(uint4*)(xswz + ((m >> 4) * 3 + (g >> 2)) * 520 + ((m & 15) + ((g & 3) << 4)) * 8) = o.v;
    }
    __syncthreads();
    // ---- FC2 partial GEMM: wave w owns m-tile w; 3 k-tiles this quarter
#pragma unroll
    for (int kt = 0; kt < 3; ++kt) {
      bf16x8 a = *(const bf16x8*)(xswz + (w * 3 + kt) * 520 + lane * 8);
      int ktg = q * 3 + kt;
#pragma unroll
      for (int nt = 0; nt < 6; ++nt)
        acc[nt] = MFMA(a, ldw(wswz, W2_T + ktg * 6 + nt, lane), acc[nt]);
    }
  }
  // ---- epilogue: + bl2 + residual(x2) -> out
#pragma unroll
  for (int nt = 0; nt < 6; ++nt) {
    int c = nt * 16 + lcol;
    float bb = bl2[c];
#pragma unroll
    for (int r = 0; r < 4; ++r) {
      int mm = w * 16 + lrow * 4 + r;
      int gy = ty0 + (mm >> 3), gx = tx0 + (mm & 7);
      long row = (long)b * 65536 + gy * 256 + gx;
      out[row * 96 + c] = acc[nt][r] + bb + x2[row * 96 + c];
    }
  }
}

// ---------------------------------------------------------------------------
extern "C" void kernel_launch(void* const* d_in, const int* in_sizes, int n_in,
                              void* d_out, int out_size, void* d_ws, size_t ws_size,
                              hipStream_t stream) {
  const float* x   = (const float*)d_in[0];
  const float* g1  = (const float*)d_in[1];
  const float* b1  = (const float*)d_in[2];
  const float* wq  = (const float*)d_in[3];
  const float* bq  = (const float*)d_in[4];
  const float* wkv = (const float*)d_in[5];
  const float* bkv = (const float*)d_in[6];
  const float* rpb = (const float*)d_in[7];
  const float* wp  = (const float*)d_in[8];
  const float* bp  = (const float*)d_in[9];
  const float* g2  = (const float*)d_in[10];
  const float* b2  = (const float*)d_in[11];
  const float* w1  = (const float*)d_in[12];
  const float* bl1 = (const float*)d_in[13];
  const float* wdw = (const float*)d_in[14];
  const float* bdw = (const float*)d_in[15];
  const float* w2  = (const float*)d_in[16];
  const float* bl2 = (const float*)d_in[17];

  char* ws = (char*)d_ws;
  unsigned short* wswz = (unsigned short*)ws;                       // 221 KB
  float* x2 = (float*)(ws + (size_t)(4 << 20));                    // 100.7 MB
  unsigned short* h1 = (unsigned short*)(ws + (size_t)(4 << 20) + 100663296); // 201.3 MB
  float* outp = (float*)d_out;

  kwconv<<<54, 256, 0, stream>>>(wq, wkv, wp, w1, w2, wswz);
  kattn<<<4096, 256, 0, stream>>>(x, g1, b1, bq, bkv, rpb, bp, wswz, x2);
  kleff1<<<4096, 256, 0, stream>>>(x2, g2, b2, bl1, wswz, h1);
  kleff2<<<4096, 256, 0, stream>>>(h1, wdw, bdw, bl2, wswz, x2, outp);
}

// Round 3
// 613.326 us; speedup vs baseline: 1.0696x; 1.0232x over previous
//
#include <hip/hip_runtime.h>
#include <math.h>

// ---------------------------------------------------------------------------
// Swin/Uformer block, MI355X. Sizes fixed: B=4 H=W=256 C=96 NH=3 HD=32 WIN=8
// N=64 HID=384. 4 kernels:
//   kwconv : f32 weights -> bf16 pre-swizzled B-frags; + wdw transposed f32
//   kattn  : LN1 + QKV + window-attn (+rpb bias, softmax) + proj + residual
//   kleff1 : LN2 + FC1 + GELU -> h1 (bf16), stores transposed through LDS
//   kleff2 : depthwise 3x3 + GELU + FC2 + residual, conv computed per-lane
//            directly into MFMA A-fragments (no activation LDS, no barriers)
// MFMA 16x16x32 bf16 layouts used throughout:
//   A-frag: lane = (m%16) + 16*(k%32/8), elem = k%8
//   B-frag: lane = (n%16) + 16*(k%32/8), elem = k%8
//   C/D   : row  = 4*(lane/16)+reg, col = lane%16
// ---------------------------------------------------------------------------

typedef __attribute__((ext_vector_type(8))) short bf16x8;
typedef __attribute__((ext_vector_type(4))) float f32x4;

#define MFMA(a, b, c) __builtin_amdgcn_mfma_f32_16x16x32_bf16((a), (b), (c), 0, 0, 0)

// weight tile bases (in 16x32 B-fragment tiles of 64 lanes * 16B)
#define WQ_T 0
#define WKV_T 18
#define WP_T 54
#define W1_T 72
#define W2_T 144
#define NTILES_TOT 216

__device__ __forceinline__ unsigned short f2bf(float f) {
  union { float f; unsigned u; } v; v.f = f;
  unsigned r = v.u + 0x7FFFu + ((v.u >> 16) & 1u);
  return (unsigned short)(r >> 16);
}
__device__ __forceinline__ float asf(unsigned u) {
  union { unsigned u; float f; } v; v.u = u; return v.f;
}
// gelu(x) = x * sigmoid(2z), z = 0.7978845608 x (1 + 0.044715 x^2)
// == tanh-form exactly; ~7 VALU ops. max dev from exact erf-gelu ~3e-4.
__device__ __forceinline__ float gelu(float x) {
  float t = x * x;
  float w = x * fmaf(t, -0.07135941f, -1.5957691f);   // -2z
  float a = __expf(w);
  return x * __builtin_amdgcn_rcpf(1.f + a);
}
__device__ __forceinline__ bf16x8 ldw(const unsigned short* wswz, int tile, int lane) {
  return *(const bf16x8*)(wswz + ((size_t)(tile * 64 + lane)) * 8);
}
__device__ __forceinline__ int xcd_swz(int bid) {   // 4096 % 8 == 0 -> bijective
  return (bid & 7) * 512 + (bid >> 3);
}

// --------------------------- weight convert/swizzle ------------------------
__global__ void kwconv(const float* __restrict__ wq, const float* __restrict__ wkv,
                       const float* __restrict__ wp, const float* __restrict__ w1,
                       const float* __restrict__ w2, const float* __restrict__ wdw,
                       unsigned short* __restrict__ wswz, float* __restrict__ wdwT) {
  int tid = blockIdx.x * 256 + threadIdx.x;
  if (tid >= NTILES_TOT * 64) {
    int i = tid - NTILES_TOT * 64;
    if (i < 3456) {                       // wdw (384,1,3,3) -> wdwT [tap][384]
      int ch = i % 384, tap = i / 384;
      wdwT[tap * 384 + ch] = wdw[ch * 9 + tap];
    }
    return;
  }
  int e = tid; const float* src; int N, NT;
  if (e < 1152)      { src = wq;  N = 96;  NT = 6; }
  else if (e < 3456) { src = wkv; N = 192; NT = 12; e -= 1152; }
  else if (e < 4608) { src = wp;  N = 96;  NT = 6;  e -= 3456; }
  else if (e < 9216) { src = w1;  N = 384; NT = 24; e -= 4608; }
  else               { src = w2;  N = 96;  NT = 6;  e -= 9216; }
  int lane = e & 63, t = e >> 6;
  int nt = t % NT, kt = t / NT;
  int k0 = kt * 32 + (lane >> 4) * 8;
  int n = nt * 16 + (lane & 15);
  unsigned short* dst = wswz + (size_t)tid * 8;
#pragma unroll
  for (int i = 0; i < 8; ++i) dst[i] = f2bf(src[(size_t)(k0 + i) * N + n]);
}

// --------------------------- attention block -------------------------------
__global__ __launch_bounds__(256) void kattn(
    const float* __restrict__ x, const float* __restrict__ g1, const float* __restrict__ b1,
    const float* __restrict__ bq, const float* __restrict__ bkv,
    const float* __restrict__ rpb, const float* __restrict__ bp,
    const unsigned short* __restrict__ wswz, float* __restrict__ x2) {
  __shared__ __align__(16) unsigned short sm0[4 * 3 * 64 * 8];   // xn_swz, later y_swz (12KB)
  __shared__ __align__(16) unsigned short sm1[24 * 64 * 8];      // q(12 tiles)+k(12) then p(24) (24KB)
  __shared__ __align__(16) unsigned short sm2[3 * 2 * 2 * 64 * 8]; // v (12KB)

  const int tid = threadIdx.x;
  const int lane = tid & 63, w = tid >> 6;
  const int lrow = lane >> 4, lcol = lane & 15;
  const int wi = xcd_swz(blockIdx.x);
  const int b = wi >> 10, wy = (wi >> 5) & 31, wx = wi & 31;

  long rowoff[4];
#pragma unroll
  for (int r = 0; r < 4; ++r) {
    int m = w * 16 + lrow * 4 + r;
    int gy = wy * 8 + (m >> 3), gx = wx * 8 + (m & 7);
    rowoff[r] = ((long)b * 65536 + gy * 256 + gx) * 96;
  }

  // ---- phase 0: load x (C/D-layout regs), LN1, write xn to A-swz LDS
  float xv[4][6], xn[4][6], gv[6], bv[6];
#pragma unroll
  for (int nt = 0; nt < 6; ++nt) {
    int c = nt * 16 + lcol;
    gv[nt] = g1[c]; bv[nt] = b1[c];
#pragma unroll
    for (int r = 0; r < 4; ++r) xv[r][nt] = x[rowoff[r] + c];
  }
#pragma unroll
  for (int r = 0; r < 4; ++r) {
    float s = 0.f, sq = 0.f;
#pragma unroll
    for (int nt = 0; nt < 6; ++nt) { float v = xv[r][nt]; s += v; sq += v * v; }
#pragma unroll
    for (int off = 1; off <= 8; off <<= 1) { s += __shfl_xor(s, off, 64); sq += __shfl_xor(sq, off, 64); }
    float mean = s * (1.f / 96.f);
    float var = sq * (1.f / 96.f) - mean * mean;
    float rs = rsqrtf(var + 1e-5f);
#pragma unroll
    for (int nt = 0; nt < 6; ++nt) xn[r][nt] = (xv[r][nt] - mean) * rs * gv[nt] + bv[nt];
  }
#pragma unroll
  for (int r = 0; r < 4; ++r) {
    int mm = lrow * 4 + r;
#pragma unroll
    for (int nt = 0; nt < 6; ++nt) {
      int c = nt * 16 + lcol;
      int kt = c >> 5;
      int lanew = mm + (((c & 31) >> 3) << 4);
      sm0[((w * 3 + kt) * 64 + lanew) * 8 + (c & 7)] = f2bf(xn[r][nt]);
    }
  }
  __syncthreads();

  // ---- phase 1: QKV GEMM (M=64 N=288 K=96), wave w owns m-tile w
  bf16x8 af[3];
#pragma unroll
  for (int kt = 0; kt < 3; ++kt) af[kt] = *(const bf16x8*)(sm0 + ((w * 3 + kt) * 64 + lane) * 8);
  for (int nt = 0; nt < 18; ++nt) {
    f32x4 acc = {0.f, 0.f, 0.f, 0.f};
#pragma unroll
    for (int kt = 0; kt < 3; ++kt) {
      int tile = (nt < 6) ? (WQ_T + kt * 6 + nt) : (WKV_T + kt * 12 + (nt - 6));
      acc = MFMA(af[kt], ldw(wswz, tile, lane), acc);
    }
    int c = nt * 16 + lcol;
#pragma unroll
    for (int r = 0; r < 4; ++r) {
      int m = w * 16 + lrow * 4 + r;
      float val = acc[r];
      if (c < 96) {                 // q (pre-scaled)
        val = (val + bq[c]) * 0.17677669529663687f;
        int head = c >> 5, d = c & 31;
        sm1[((head * 4 + w) * 64 + (m & 15) + ((d >> 3) << 4)) * 8 + (d & 7)] = f2bf(val);
      } else if (c < 192) {         // k
        int kc = c - 96;
        val += bkv[kc];
        int head = kc >> 5, d = kc & 31;
        sm1[((12 + head * 4 + w) * 64 + (m & 15) + ((d >> 3) << 4)) * 8 + (d & 7)] = f2bf(val);
      } else {                      // v (B-frag layout: k-dim = key token)
        int vc = c - 192;
        val += bkv[96 + vc];
        int head = vc >> 5, d = vc & 31;
        int ktile = m >> 5, nt2 = d >> 4;
        sm2[(((head * 2 + ktile) * 2 + nt2) * 64 + (d & 15) + (((m & 31) >> 3) << 4)) * 8 + (m & 7)] = f2bf(val);
      }
    }
  }
  __syncthreads();

  // ---- phase 2: scores. unit u=(head,mtq); wave w owns u = 3w..3w+2
  f32x4 sc[3][4];
#pragma unroll
  for (int uu = 0; uu < 3; ++uu) {
    int u = w * 3 + uu, head = u >> 2, mtq = u & 3;
    bf16x8 aq = *(const bf16x8*)(sm1 + ((head * 4 + mtq) * 64 + lane) * 8);
#pragma unroll
    for (int nt = 0; nt < 4; ++nt) {
      bf16x8 bk = *(const bf16x8*)(sm1 + ((12 + head * 4 + nt) * 64 + lane) * 8);
      f32x4 z = {0.f, 0.f, 0.f, 0.f};
      sc[uu][nt] = MFMA(aq, bk, z);
    }
  }
  __syncthreads();   // all q/k reads done; sm1 may now be overwritten with P

  // ---- phase 3: +rpb bias, softmax (in-register), write P to A-swz LDS
#pragma unroll
  for (int uu = 0; uu < 3; ++uu) {
    int u = w * 3 + uu, head = u >> 2, mtq = u & 3;
#pragma unroll
    for (int nt = 0; nt < 4; ++nt) {
      int ktok = nt * 16 + lcol;
#pragma unroll
      for (int r = 0; r < 4; ++r) {
        int qtok = mtq * 16 + lrow * 4 + r;
        int dy = (qtok >> 3) - (ktok >> 3) + 7;
        int dx = (qtok & 7) - (ktok & 7) + 7;
        sc[uu][nt][r] += rpb[(dy * 15 + dx) * 3 + head];
      }
    }
#pragma unroll
    for (int r = 0; r < 4; ++r) {
      float mx = fmaxf(fmaxf(sc[uu][0][r], sc[uu][1][r]), fmaxf(sc[uu][2][r], sc[uu][3][r]));
#pragma unroll
      for (int off = 1; off <= 8; off <<= 1) mx = fmaxf(mx, __shfl_xor(mx, off, 64));
      float p[4], sum = 0.f;
#pragma unroll
      for (int nt = 0; nt < 4; ++nt) { p[nt] = __expf(sc[uu][nt][r] - mx); sum += p[nt]; }
#pragma unroll
      for (int off = 1; off <= 8; off <<= 1) sum += __shfl_xor(sum, off, 64);
      float inv = 1.f / sum;
#pragma unroll
      for (int nt = 0; nt < 4; ++nt) sc[uu][nt][r] = p[nt] * inv;
    }
#pragma unroll
    for (int nt = 0; nt < 4; ++nt) {
      int ktok = nt * 16 + lcol;
      int ktile = ktok >> 5, lhi = (ktok & 31) >> 3;
#pragma unroll
      for (int r = 0; r < 4; ++r) {
        int mm = lrow * 4 + r;
        sm1[(((head * 4 + mtq) * 2 + ktile) * 64 + mm + (lhi << 4)) * 8 + (ktok & 7)] = f2bf(sc[uu][nt][r]);
      }
    }
  }
  __syncthreads();

  // ---- phase 4: PV, write y to A-swz LDS (reuse sm0; head = k-tile)
#pragma unroll
  for (int uu = 0; uu < 3; ++uu) {
    int u = w * 3 + uu, head = u >> 2, mtq = u & 3;
#pragma unroll
    for (int nt2 = 0; nt2 < 2; ++nt2) {
      f32x4 acc = {0.f, 0.f, 0.f, 0.f};
#pragma unroll
      for (int ktile = 0; ktile < 2; ++ktile) {
        bf16x8 ap = *(const bf16x8*)(sm1 + (((head * 4 + mtq) * 2 + ktile) * 64 + lane) * 8);
        bf16x8 bv8 = *(const bf16x8*)(sm2 + (((head * 2 + ktile) * 2 + nt2) * 64 + lane) * 8);
        acc = MFMA(ap, bv8, acc);
      }
      int d0 = nt2 * 16 + lcol;
#pragma unroll
      for (int r = 0; r < 4; ++r) {
        int mm = lrow * 4 + r;
        sm0[((mtq * 3 + head) * 64 + mm + ((d0 >> 3) << 4)) * 8 + (d0 & 7)] = f2bf(acc[r]);
      }
    }
  }
  __syncthreads();

  // ---- phase 5: proj + bias + residual -> x2
  bf16x8 ay[3];
#pragma unroll
  for (int kt = 0; kt < 3; ++kt) ay[kt] = *(const bf16x8*)(sm0 + ((w * 3 + kt) * 64 + lane) * 8);
#pragma unroll
  for (int nt = 0; nt < 6; ++nt) {
    f32x4 acc = {0.f, 0.f, 0.f, 0.f};
#pragma unroll
    for (int kt = 0; kt < 3; ++kt) acc = MFMA(ay[kt], ldw(wswz, WP_T + kt * 6 + nt, lane), acc);
    int c = nt * 16 + lcol;
    float bpc = bp[c];
#pragma unroll
    for (int r = 0; r < 4; ++r) x2[rowoff[r] + c] = acc[r] + bpc + xv[r][nt];
  }
}

// --------------------------- LN2 + FC1 + GELU ------------------------------
__global__ __launch_bounds__(256) void kleff1(
    const float* __restrict__ x2, const float* __restrict__ g2, const float* __restrict__ b2,
    const float* __restrict__ bl1, const unsigned short* __restrict__ wswz,
    unsigned short* __restrict__ h1) {
  __shared__ __align__(16) unsigned short sm0[4 * 3 * 64 * 8];   // 12.3KB
  __shared__ __align__(16) unsigned short trbuf[64 * 200];       // 25.6KB (192ch half, +8 pad)
  const int tid = threadIdx.x, lane = tid & 63, w = tid >> 6;
  const int lrow = lane >> 4, lcol = lane & 15;
  const long tbase = (long)xcd_swz(blockIdx.x) * 64;

  float xv[4][6], gv[6], bv[6];
#pragma unroll
  for (int nt = 0; nt < 6; ++nt) {
    int c = nt * 16 + lcol;
    gv[nt] = g2[c]; bv[nt] = b2[c];
#pragma unroll
    for (int r = 0; r < 4; ++r) xv[r][nt] = x2[(tbase + w * 16 + lrow * 4 + r) * 96 + c];
  }
#pragma unroll
  for (int r = 0; r < 4; ++r) {
    float s = 0.f, sq = 0.f;
#pragma unroll
    for (int nt = 0; nt < 6; ++nt) { float v = xv[r][nt]; s += v; sq += v * v; }
#pragma unroll
    for (int off = 1; off <= 8; off <<= 1) { s += __shfl_xor(s, off, 64); sq += __shfl_xor(sq, off, 64); }
    float mean = s * (1.f / 96.f);
    float var = sq * (1.f / 96.f) - mean * mean;
    float rs = rsqrtf(var + 1e-5f);
#pragma unroll
    for (int nt = 0; nt < 6; ++nt) xv[r][nt] = (xv[r][nt] - mean) * rs * gv[nt] + bv[nt];
  }
#pragma unroll
  for (int r = 0; r < 4; ++r) {
    int mm = lrow * 4 + r;
#pragma unroll
    for (int nt = 0; nt < 6; ++nt) {
      int c = nt * 16 + lcol;
      int kt = c >> 5;
      int lanew = mm + (((c & 31) >> 3) << 4);
      sm0[((w * 3 + kt) * 64 + lanew) * 8 + (c & 7)] = f2bf(xv[r][nt]);
    }
  }
  __syncthreads();

  bf16x8 af[3];
#pragma unroll
  for (int kt = 0; kt < 3; ++kt) af[kt] = *(const bf16x8*)(sm0 + ((w * 3 + kt) * 64 + lane) * 8);

  for (int half = 0; half < 2; ++half) {
#pragma unroll
    for (int nt2 = 0; nt2 < 12; ++nt2) {
      int nt = half * 12 + nt2;
      f32x4 acc = {0.f, 0.f, 0.f, 0.f};
#pragma unroll
      for (int kt = 0; kt < 3; ++kt) acc = MFMA(af[kt], ldw(wswz, W1_T + kt * 24 + nt, lane), acc);
      int cl = nt2 * 16 + lcol;                 // 0..191 within half
      float bb = bl1[half * 192 + cl];
#pragma unroll
      for (int r = 0; r < 4; ++r) {
        int m = w * 16 + lrow * 4 + r;
        trbuf[m * 200 + cl] = f2bf(gelu(acc[r] + bb));
      }
    }
    __syncthreads();
    // coalesced writeout: 1536 x 16B chunks
#pragma unroll
    for (int j = 0; j < 6; ++j) {
      int idx = tid + j * 256;
      int token = idx / 24, c0 = (idx % 24) * 8;
      uint4 v = *(const uint4*)(trbuf + token * 200 + c0);
      *(uint4*)(h1 + (tbase + token) * 384 + half * 192 + c0) = v;
    }
    __syncthreads();
  }
}

// --------------- depthwise 3x3 + GELU + FC2 + residual ---------------------
// conv computed per-lane directly into the consuming lane's A-fragment:
// lane l of wave w owns pixel w*16+(l&15), channels kt*32+(l>>4)*8 .. +7.
// No activation LDS, no per-tile barriers; h1 neighborhood read from L2.
__global__ __launch_bounds__(256) void kleff2(
    const unsigned short* __restrict__ h1, const float* __restrict__ wdwT,
    const float* __restrict__ bdw, const float* __restrict__ bl2,
    const unsigned short* __restrict__ wswz, const float* __restrict__ x2,
    float* __restrict__ out) {
  __shared__ __align__(16) float wsh[9 * 384];   // 13.8KB transposed f32 dw weights
  const int tid = threadIdx.x, lane = tid & 63, w = tid >> 6;
  const int lrow = lane >> 4, lcol = lane & 15;
  const int bid = xcd_swz(blockIdx.x);
  const int b = bid >> 10, ty0 = ((bid >> 5) & 31) * 8, tx0 = (bid & 31) * 8;

  // stage dw weights once (864 float4)
  for (int i = tid; i < 864; i += 256)
    *(float4*)(wsh + i * 4) = *(const float4*)(wdwT + i * 4);

  const int px = w * 16 + (lane & 15);       // this lane's pixel 0..63
  const int gy = ty0 + (px >> 3), gx = tx0 + (px & 7);
  const int cg0 = (lane >> 4) * 8;           // channel sub-offset in k-tile

  const unsigned short* p9[9];
  bool ok9[9];
#pragma unroll
  for (int dy = 0; dy < 3; ++dy)
#pragma unroll
    for (int dx = 0; dx < 3; ++dx) {
      int t = dy * 3 + dx;
      int yy = gy + dy - 1, xx = gx + dx - 1;
      ok9[t] = ((unsigned)yy < 256u) && ((unsigned)xx < 256u);
      p9[t] = h1 + (((long)b * 65536 + yy * 256 + xx) * 384 + cg0);
    }

  f32x4 acc[6];
#pragma unroll
  for (int nt = 0; nt < 6; ++nt) { f32x4 z = {0.f, 0.f, 0.f, 0.f}; acc[nt] = z; }

  __syncthreads();

  for (int kt = 0; kt < 12; ++kt) {
    const int ch = kt * 32 + cg0;
    float a8[8];
#pragma unroll
    for (int i = 0; i < 8; ++i) a8[i] = 0.f;
#pragma unroll
    for (int t = 0; t < 9; ++t) {
      uint4 dv = make_uint4(0u, 0u, 0u, 0u);
      if (ok9[t]) dv = *(const uint4*)(p9[t] + kt * 32);
      float wf[8];
      *(float4*)(wf)     = *(const float4*)(wsh + t * 384 + ch);
      *(float4*)(wf + 4) = *(const float4*)(wsh + t * 384 + ch + 4);
      const unsigned* du = (const unsigned*)&dv;
#pragma unroll
      for (int j = 0; j < 4; ++j) {
        a8[2 * j]     = fmaf(asf(du[j] << 16),         wf[2 * j],     a8[2 * j]);
        a8[2 * j + 1] = fmaf(asf(du[j] & 0xffff0000u), wf[2 * j + 1], a8[2 * j + 1]);
      }
    }
    float bw[8];
    *(float4*)(bw)     = *(const float4*)(bdw + ch);
    *(float4*)(bw + 4) = *(const float4*)(bdw + ch + 4);
    union { unsigned short s[8]; bf16x8 v; } pk;
#pragma unroll
    for (int i = 0; i < 8; ++i) pk.s[i] = f2bf(gelu(a8[i] + bw[i]));
#pragma unroll
    for (int nt = 0; nt < 6; ++nt)
      acc[nt] = MFMA(pk.v, ldw(wswz, W2_T + kt * 6 + nt, lane), acc[nt]);
  }

  // ---- epilogue: + bl2 + residual(x2) -> out
#pragma unroll
  for (int nt = 0; nt < 6; ++nt) {
    int c = nt * 16 + lcol;
    float bb = bl2[c];
#pragma unroll
    for (int r = 0; r < 4; ++r) {
      int mm = w * 16 + lrow * 4 + r;
      int oy = ty0 + (mm >> 3), ox = tx0 + (mm & 7);
      long row = (long)b * 65536 + oy * 256 + ox;
      out[row * 96 + c] = acc[nt][r] + bb + x2[row * 96 + c];
    }
  }
}

// ---------------------------------------------------------------------------
extern "C" void kernel_launch(void* const* d_in, const int* in_sizes, int n_in,
                              void* d_out, int out_size, void* d_ws, size_t ws_size,
                              hipStream_t stream) {
  const float* x   = (const float*)d_in[0];
  const float* g1  = (const float*)d_in[1];
  const float* b1  = (const float*)d_in[2];
  const float* wq  = (const float*)d_in[3];
  const float* bq  = (const float*)d_in[4];
  const float* wkv = (const float*)d_in[5];
  const float* bkv = (const float*)d_in[6];
  const float* rpb = (const float*)d_in[7];
  const float* wp  = (const float*)d_in[8];
  const float* bp  = (const float*)d_in[9];
  const float* g2  = (const float*)d_in[10];
  const float* b2  = (const float*)d_in[11];
  const float* w1  = (const float*)d_in[12];
  const float* bl1 = (const float*)d_in[13];
  const float* wdw = (const float*)d_in[14];
  const float* bdw = (const float*)d_in[15];
  const float* w2  = (const float*)d_in[16];
  const float* bl2 = (const float*)d_in[17];

  char* ws = (char*)d_ws;
  unsigned short* wswz = (unsigned short*)ws;                      // 221 KB
  float* wdwT = (float*)(ws + (size_t)(256 << 10));                // 13.8 KB @256KB
  float* x2 = (float*)(ws + (size_t)(4 << 20));                    // 100.7 MB
  unsigned short* h1 = (unsigned short*)(ws + (size_t)(4 << 20) + 100663296); // 201.3 MB
  float* outp = (float*)d_out;

  kwconv<<<68, 256, 0, stream>>>(wq, wkv, wp, w1, w2, wdw, wswz, wdwT);
  kattn<<<4096, 256, 0, stream>>>(x, g1, b1, bq, bkv, rpb, bp, wswz, x2);
  kleff1<<<4096, 256, 0, stream>>>(x2, g2, b2, bl1, wswz, h1);
  kleff2<<<4096, 256, 0, stream>>>(h1, wdwT, bdw, bl2, wswz, x2, outp);
}

// Round 4
// 606.814 us; speedup vs baseline: 1.0811x; 1.0107x over previous
//
#include <hip/hip_runtime.h>
#include <math.h>

// ---------------------------------------------------------------------------
// Swin/Uformer block, MI355X. Sizes fixed: B=4 H=W=256 C=96 NH=3 HD=32 WIN=8
// N=64 HID=384. 4 kernels:
//   kwconv : f32 weights -> bf16 pre-swizzled B-frags; + wdw transposed f32
//   kattn  : LN1 + QKV + window-attn (+rpb bias, softmax) + proj + residual
//   kleff1 : LN2 + FC1 + GELU -> h1 (bf16), stores transposed through LDS
//   kleff2 : depthwise 3x3 + GELU + FC2 + residual; per-lane conv into MFMA
//            A-frags, register double-buffer prefetch, interior/edge split
// MFMA 16x16x32 bf16 layouts used throughout:
//   A-frag: lane = (m%16) + 16*(k%32/8), elem = k%8
//   B-frag: lane = (n%16) + 16*(k%32/8), elem = k%8
//   C/D   : row  = 4*(lane/16)+reg, col = lane%16
// ---------------------------------------------------------------------------

typedef __attribute__((ext_vector_type(8))) short bf16x8;
typedef __attribute__((ext_vector_type(4))) float f32x4;
typedef __attribute__((ext_vector_type(2))) float f32x2;

#define MFMA(a, b, c) __builtin_amdgcn_mfma_f32_16x16x32_bf16((a), (b), (c), 0, 0, 0)

// weight tile bases (in 16x32 B-fragment tiles of 64 lanes * 16B)
#define WQ_T 0
#define WKV_T 18
#define WP_T 54
#define W1_T 72
#define W2_T 144
#define NTILES_TOT 216

__device__ __forceinline__ unsigned short f2bf(float f) {
  union { float f; unsigned u; } v; v.f = f;
  unsigned r = v.u + 0x7FFFu + ((v.u >> 16) & 1u);
  return (unsigned short)(r >> 16);
}
__device__ __forceinline__ float asf(unsigned u) {
  union { unsigned u; float f; } v; v.u = u; return v.f;
}
__device__ __forceinline__ unsigned cvtpk_bf16(float lo, float hi) {
  unsigned r;
  asm("v_cvt_pk_bf16_f32 %0, %1, %2" : "=v"(r) : "v"(lo), "v"(hi));
  return r;
}
// gelu(x) = x * sigmoid(2z), z = 0.7978845608 x (1 + 0.044715 x^2)
// == tanh-form exactly; ~7 VALU ops. max dev from exact erf-gelu ~3e-4.
__device__ __forceinline__ float gelu(float x) {
  float t = x * x;
  float w = x * fmaf(t, -0.07135941f, -1.5957691f);   // -2z
  float a = __expf(w);
  return x * __builtin_amdgcn_rcpf(1.f + a);
}
__device__ __forceinline__ bf16x8 ldw(const unsigned short* wswz, int tile, int lane) {
  return *(const bf16x8*)(wswz + ((size_t)(tile * 64 + lane)) * 8);
}
__device__ __forceinline__ int xcd_swz(int bid) {   // 4096 % 8 == 0 -> bijective
  return (bid & 7) * 512 + (bid >> 3);
}

// --------------------------- weight convert/swizzle ------------------------
__global__ void kwconv(const float* __restrict__ wq, const float* __restrict__ wkv,
                       const float* __restrict__ wp, const float* __restrict__ w1,
                       const float* __restrict__ w2, const float* __restrict__ wdw,
                       unsigned short* __restrict__ wswz, float* __restrict__ wdwT) {
  int tid = blockIdx.x * 256 + threadIdx.x;
  if (tid >= NTILES_TOT * 64) {
    int i = tid - NTILES_TOT * 64;
    if (i < 3456) {                       // wdw (384,1,3,3) -> wdwT [tap][384]
      int ch = i % 384, tap = i / 384;
      wdwT[tap * 384 + ch] = wdw[ch * 9 + tap];
    }
    return;
  }
  int e = tid; const float* src; int N, NT;
  if (e < 1152)      { src = wq;  N = 96;  NT = 6; }
  else if (e < 3456) { src = wkv; N = 192; NT = 12; e -= 1152; }
  else if (e < 4608) { src = wp;  N = 96;  NT = 6;  e -= 3456; }
  else if (e < 9216) { src = w1;  N = 384; NT = 24; e -= 4608; }
  else               { src = w2;  N = 96;  NT = 6;  e -= 9216; }
  int lane = e & 63, t = e >> 6;
  int nt = t % NT, kt = t / NT;
  int k0 = kt * 32 + (lane >> 4) * 8;
  int n = nt * 16 + (lane & 15);
  unsigned short* dst = wswz + (size_t)tid * 8;
#pragma unroll
  for (int i = 0; i < 8; ++i) dst[i] = f2bf(src[(size_t)(k0 + i) * N + n]);
}

// --------------------------- attention block -------------------------------
__global__ __launch_bounds__(256) void kattn(
    const float* __restrict__ x, const float* __restrict__ g1, const float* __restrict__ b1,
    const float* __restrict__ bq, const float* __restrict__ bkv,
    const float* __restrict__ rpb, const float* __restrict__ bp,
    const unsigned short* __restrict__ wswz, float* __restrict__ x2) {
  __shared__ __align__(16) unsigned short sm0[4 * 3 * 64 * 8];   // xn_swz, later y_swz (12KB)
  __shared__ __align__(16) unsigned short sm1[24 * 64 * 8];      // q(12 tiles)+k(12) then p(24) (24KB)
  __shared__ __align__(16) unsigned short sm2[3 * 2 * 2 * 64 * 8]; // v (12KB)

  const int tid = threadIdx.x;
  const int lane = tid & 63, w = tid >> 6;
  const int lrow = lane >> 4, lcol = lane & 15;
  const int wi = xcd_swz(blockIdx.x);
  const int b = wi >> 10, wy = (wi >> 5) & 31, wx = wi & 31;

  long rowoff[4];
#pragma unroll
  for (int r = 0; r < 4; ++r) {
    int m = w * 16 + lrow * 4 + r;
    int gy = wy * 8 + (m >> 3), gx = wx * 8 + (m & 7);
    rowoff[r] = ((long)b * 65536 + gy * 256 + gx) * 96;
  }

  // ---- phase 0: load x (C/D-layout regs), LN1, write xn to A-swz LDS
  float xv[4][6], xn[4][6], gv[6], bv[6];
#pragma unroll
  for (int nt = 0; nt < 6; ++nt) {
    int c = nt * 16 + lcol;
    gv[nt] = g1[c]; bv[nt] = b1[c];
#pragma unroll
    for (int r = 0; r < 4; ++r) xv[r][nt] = x[rowoff[r] + c];
  }
#pragma unroll
  for (int r = 0; r < 4; ++r) {
    float s = 0.f, sq = 0.f;
#pragma unroll
    for (int nt = 0; nt < 6; ++nt) { float v = xv[r][nt]; s += v; sq += v * v; }
#pragma unroll
    for (int off = 1; off <= 8; off <<= 1) { s += __shfl_xor(s, off, 64); sq += __shfl_xor(sq, off, 64); }
    float mean = s * (1.f / 96.f);
    float var = sq * (1.f / 96.f) - mean * mean;
    float rs = rsqrtf(var + 1e-5f);
#pragma unroll
    for (int nt = 0; nt < 6; ++nt) xn[r][nt] = (xv[r][nt] - mean) * rs * gv[nt] + bv[nt];
  }
#pragma unroll
  for (int r = 0; r < 4; ++r) {
    int mm = lrow * 4 + r;
#pragma unroll
    for (int nt = 0; nt < 6; ++nt) {
      int c = nt * 16 + lcol;
      int kt = c >> 5;
      int lanew = mm + (((c & 31) >> 3) << 4);
      sm0[((w * 3 + kt) * 64 + lanew) * 8 + (c & 7)] = f2bf(xn[r][nt]);
    }
  }
  __syncthreads();

  // ---- phase 1: QKV GEMM (M=64 N=288 K=96), wave w owns m-tile w
  bf16x8 af[3];
#pragma unroll
  for (int kt = 0; kt < 3; ++kt) af[kt] = *(const bf16x8*)(sm0 + ((w * 3 + kt) * 64 + lane) * 8);
  for (int nt = 0; nt < 18; ++nt) {
    f32x4 acc = {0.f, 0.f, 0.f, 0.f};
#pragma unroll
    for (int kt = 0; kt < 3; ++kt) {
      int tile = (nt < 6) ? (WQ_T + kt * 6 + nt) : (WKV_T + kt * 12 + (nt - 6));
      acc = MFMA(af[kt], ldw(wswz, tile, lane), acc);
    }
    int c = nt * 16 + lcol;
#pragma unroll
    for (int r = 0; r < 4; ++r) {
      int m = w * 16 + lrow * 4 + r;
      float val = acc[r];
      if (c < 96) {                 // q (pre-scaled)
        val = (val + bq[c]) * 0.17677669529663687f;
        int head = c >> 5, d = c & 31;
        sm1[((head * 4 + w) * 64 + (m & 15) + ((d >> 3) << 4)) * 8 + (d & 7)] = f2bf(val);
      } else if (c < 192) {         // k
        int kc = c - 96;
        val += bkv[kc];
        int head = kc >> 5, d = kc & 31;
        sm1[((12 + head * 4 + w) * 64 + (m & 15) + ((d >> 3) << 4)) * 8 + (d & 7)] = f2bf(val);
      } else {                      // v (B-frag layout: k-dim = key token)
        int vc = c - 192;
        val += bkv[96 + vc];
        int head = vc >> 5, d = vc & 31;
        int ktile = m >> 5, nt2 = d >> 4;
        sm2[(((head * 2 + ktile) * 2 + nt2) * 64 + (d & 15) + (((m & 31) >> 3) << 4)) * 8 + (m & 7)] = f2bf(val);
      }
    }
  }
  __syncthreads();

  // ---- phase 2: scores. unit u=(head,mtq); wave w owns u = 3w..3w+2
  f32x4 sc[3][4];
#pragma unroll
  for (int uu = 0; uu < 3; ++uu) {
    int u = w * 3 + uu, head = u >> 2, mtq = u & 3;
    bf16x8 aq = *(const bf16x8*)(sm1 + ((head * 4 + mtq) * 64 + lane) * 8);
#pragma unroll
    for (int nt = 0; nt < 4; ++nt) {
      bf16x8 bk = *(const bf16x8*)(sm1 + ((12 + head * 4 + nt) * 64 + lane) * 8);
      f32x4 z = {0.f, 0.f, 0.f, 0.f};
      sc[uu][nt] = MFMA(aq, bk, z);
    }
  }
  __syncthreads();   // all q/k reads done; sm1 may now be overwritten with P

  // ---- phase 3: +rpb bias, softmax (in-register), write P to A-swz LDS
#pragma unroll
  for (int uu = 0; uu < 3; ++uu) {
    int u = w * 3 + uu, head = u >> 2, mtq = u & 3;
#pragma unroll
    for (int nt = 0; nt < 4; ++nt) {
      int ktok = nt * 16 + lcol;
#pragma unroll
      for (int r = 0; r < 4; ++r) {
        int qtok = mtq * 16 + lrow * 4 + r;
        int dy = (qtok >> 3) - (ktok >> 3) + 7;
        int dx = (qtok & 7) - (ktok & 7) + 7;
        sc[uu][nt][r] += rpb[(dy * 15 + dx) * 3 + head];
      }
    }
#pragma unroll
    for (int r = 0; r < 4; ++r) {
      float mx = fmaxf(fmaxf(sc[uu][0][r], sc[uu][1][r]), fmaxf(sc[uu][2][r], sc[uu][3][r]));
#pragma unroll
      for (int off = 1; off <= 8; off <<= 1) mx = fmaxf(mx, __shfl_xor(mx, off, 64));
      float p[4], sum = 0.f;
#pragma unroll
      for (int nt = 0; nt < 4; ++nt) { p[nt] = __expf(sc[uu][nt][r] - mx); sum += p[nt]; }
#pragma unroll
      for (int off = 1; off <= 8; off <<= 1) sum += __shfl_xor(sum, off, 64);
      float inv = 1.f / sum;
#pragma unroll
      for (int nt = 0; nt < 4; ++nt) sc[uu][nt][r] = p[nt] * inv;
    }
#pragma unroll
    for (int nt = 0; nt < 4; ++nt) {
      int ktok = nt * 16 + lcol;
      int ktile = ktok >> 5, lhi = (ktok & 31) >> 3;
#pragma unroll
      for (int r = 0; r < 4; ++r) {
        int mm = lrow * 4 + r;
        sm1[(((head * 4 + mtq) * 2 + ktile) * 64 + mm + (lhi << 4)) * 8 + (ktok & 7)] = f2bf(sc[uu][nt][r]);
      }
    }
  }
  __syncthreads();

  // ---- phase 4: PV, write y to A-swz LDS (reuse sm0; head = k-tile)
#pragma unroll
  for (int uu = 0; uu < 3; ++uu) {
    int u = w * 3 + uu, head = u >> 2, mtq = u & 3;
#pragma unroll
    for (int nt2 = 0; nt2 < 2; ++nt2) {
      f32x4 acc = {0.f, 0.f, 0.f, 0.f};
#pragma unroll
      for (int ktile = 0; ktile < 2; ++ktile) {
        bf16x8 ap = *(const bf16x8*)(sm1 + (((head * 4 + mtq) * 2 + ktile) * 64 + lane) * 8);
        bf16x8 bv8 = *(const bf16x8*)(sm2 + (((head * 2 + ktile) * 2 + nt2) * 64 + lane) * 8);
        acc = MFMA(ap, bv8, acc);
      }
      int d0 = nt2 * 16 + lcol;
#pragma unroll
      for (int r = 0; r < 4; ++r) {
        int mm = lrow * 4 + r;
        sm0[((mtq * 3 + head) * 64 + mm + ((d0 >> 3) << 4)) * 8 + (d0 & 7)] = f2bf(acc[r]);
      }
    }
  }
  __syncthreads();

  // ---- phase 5: proj + bias + residual -> x2
  bf16x8 ay[3];
#pragma unroll
  for (int kt = 0; kt < 3; ++kt) ay[kt] = *(const bf16x8*)(sm0 + ((w * 3 + kt) * 64 + lane) * 8);
#pragma unroll
  for (int nt = 0; nt < 6; ++nt) {
    f32x4 acc = {0.f, 0.f, 0.f, 0.f};
#pragma unroll
    for (int kt = 0; kt < 3; ++kt) acc = MFMA(ay[kt], ldw(wswz, WP_T + kt * 6 + nt, lane), acc);
    int c = nt * 16 + lcol;
    float bpc = bp[c];
#pragma unroll
    for (int r = 0; r < 4; ++r) x2[rowoff[r] + c] = acc[r] + bpc + xv[r][nt];
  }
}

// --------------------------- LN2 + FC1 + GELU ------------------------------
__global__ __launch_bounds__(256) void kleff1(
    const float* __restrict__ x2, const float* __restrict__ g2, const float* __restrict__ b2,
    const float* __restrict__ bl1, const unsigned short* __restrict__ wswz,
    unsigned short* __restrict__ h1) {
  __shared__ __align__(16) unsigned short sm0[4 * 3 * 64 * 8];   // 12.3KB
  __shared__ __align__(16) unsigned short trbuf[64 * 200];       // 25.6KB (192ch half, +8 pad)
  const int tid = threadIdx.x, lane = tid & 63, w = tid >> 6;
  const int lrow = lane >> 4, lcol = lane & 15;
  const long tbase = (long)xcd_swz(blockIdx.x) * 64;

  float xv[4][6], gv[6], bv[6];
#pragma unroll
  for (int nt = 0; nt < 6; ++nt) {
    int c = nt * 16 + lcol;
    gv[nt] = g2[c]; bv[nt] = b2[c];
#pragma unroll
    for (int r = 0; r < 4; ++r) xv[r][nt] = x2[(tbase + w * 16 + lrow * 4 + r) * 96 + c];
  }
#pragma unroll
  for (int r = 0; r < 4; ++r) {
    float s = 0.f, sq = 0.f;
#pragma unroll
    for (int nt = 0; nt < 6; ++nt) { float v = xv[r][nt]; s += v; sq += v * v; }
#pragma unroll
    for (int off = 1; off <= 8; off <<= 1) { s += __shfl_xor(s, off, 64); sq += __shfl_xor(sq, off, 64); }
    float mean = s * (1.f / 96.f);
    float var = sq * (1.f / 96.f) - mean * mean;
    float rs = rsqrtf(var + 1e-5f);
#pragma unroll
    for (int nt = 0; nt < 6; ++nt) xv[r][nt] = (xv[r][nt] - mean) * rs * gv[nt] + bv[nt];
  }
#pragma unroll
  for (int r = 0; r < 4; ++r) {
    int mm = lrow * 4 + r;
#pragma unroll
    for (int nt = 0; nt < 6; ++nt) {
      int c = nt * 16 + lcol;
      int kt = c >> 5;
      int lanew = mm + (((c & 31) >> 3) << 4);
      sm0[((w * 3 + kt) * 64 + lanew) * 8 + (c & 7)] = f2bf(xv[r][nt]);
    }
  }
  __syncthreads();

  bf16x8 af[3];
#pragma unroll
  for (int kt = 0; kt < 3; ++kt) af[kt] = *(const bf16x8*)(sm0 + ((w * 3 + kt) * 64 + lane) * 8);

  for (int half = 0; half < 2; ++half) {
#pragma unroll
    for (int nt2 = 0; nt2 < 12; ++nt2) {
      int nt = half * 12 + nt2;
      f32x4 acc = {0.f, 0.f, 0.f, 0.f};
#pragma unroll
      for (int kt = 0; kt < 3; ++kt) acc = MFMA(af[kt], ldw(wswz, W1_T + kt * 24 + nt, lane), acc);
      int cl = nt2 * 16 + lcol;                 // 0..191 within half
      float bb = bl1[half * 192 + cl];
#pragma unroll
      for (int r = 0; r < 4; ++r) {
        int m = w * 16 + lrow * 4 + r;
        trbuf[m * 200 + cl] = f2bf(gelu(acc[r] + bb));
      }
    }
    __syncthreads();
    // coalesced writeout: 1536 x 16B chunks
#pragma unroll
    for (int j = 0; j < 6; ++j) {
      int idx = tid + j * 256;
      int token = idx / 24, c0 = (idx % 24) * 8;
      uint4 v = *(const uint4*)(trbuf + token * 200 + c0);
      *(uint4*)(h1 + (tbase + token) * 384 + half * 192 + c0) = v;
    }
    __syncthreads();
  }
}

// --------------- depthwise 3x3 + GELU + FC2 + residual ---------------------
// conv computed per-lane directly into the consuming lane's A-fragment:
// lane l of wave w owns pixel w*16+(l&15), channels kt*32+(l>>4)*8 .. +7.
// Register double-buffer prefetch; interior blocks take unconditional path.
__device__ __forceinline__ bf16x8 dwconv_gelu(const uint4* cur,
    const float* wsh, const float* wb, int ch) {
  f32x2 a2[4];
#pragma unroll
  for (int j = 0; j < 4; ++j) a2[j] = (f32x2){0.f, 0.f};
#pragma unroll
  for (int t = 0; t < 9; ++t) {
    f32x4 wlo = *(const f32x4*)(wsh + t * 384 + ch);
    f32x4 whi = *(const f32x4*)(wsh + t * 384 + ch + 4);
    const unsigned* du = (const unsigned*)(cur + t);
    f32x2 d0 = { asf(du[0] << 16), asf(du[0] & 0xffff0000u) };
    f32x2 d1 = { asf(du[1] << 16), asf(du[1] & 0xffff0000u) };
    f32x2 d2 = { asf(du[2] << 16), asf(du[2] & 0xffff0000u) };
    f32x2 d3 = { asf(du[3] << 16), asf(du[3] & 0xffff0000u) };
    f32x2 w0 = {wlo.x, wlo.y}, w1 = {wlo.z, wlo.w};
    f32x2 w2v = {whi.x, whi.y}, w3 = {whi.z, whi.w};
    a2[0] += d0 * w0; a2[1] += d1 * w1; a2[2] += d2 * w2v; a2[3] += d3 * w3;
  }
  f32x4 blo = *(const f32x4*)(wb + ch);
  f32x4 bhi = *(const f32x4*)(wb + ch + 4);
  union { unsigned u[4]; bf16x8 v; } pk;
  pk.u[0] = cvtpk_bf16(gelu(a2[0].x + blo.x), gelu(a2[0].y + blo.y));
  pk.u[1] = cvtpk_bf16(gelu(a2[1].x + blo.z), gelu(a2[1].y + blo.w));
  pk.u[2] = cvtpk_bf16(gelu(a2[2].x + bhi.x), gelu(a2[2].y + bhi.y));
  pk.u[3] = cvtpk_bf16(gelu(a2[3].x + bhi.z), gelu(a2[3].y + bhi.w));
  return pk.v;
}

__global__ __launch_bounds__(256) void kleff2(
    const unsigned short* __restrict__ h1, const float* __restrict__ wdwT,
    const float* __restrict__ bdw, const float* __restrict__ bl2,
    const unsigned short* __restrict__ wswz, const float* __restrict__ x2,
    float* __restrict__ out) {
  __shared__ __align__(16) float wsh[9 * 384 + 384];   // 15.4KB: taps f32 + bias f32
  const int tid = threadIdx.x, lane = tid & 63, w = tid >> 6;
  const int lrow = lane >> 4, lcol = lane & 15;
  const int bid = xcd_swz(blockIdx.x);
  const int b = bid >> 10, ty0 = ((bid >> 5) & 31) * 8, tx0 = (bid & 31) * 8;

  // stage dw weights + bias once (960 float4)
  for (int i = tid; i < 960; i += 256) {
    float4 v = (i < 864) ? ((const float4*)wdwT)[i] : ((const float4*)bdw)[i - 864];
    ((float4*)wsh)[i] = v;
  }
  const float* wb = wsh + 3456;

  const int px = w * 16 + lcol;              // this lane's pixel 0..63
  const int gy = ty0 + (px >> 3), gx = tx0 + (px & 7);
  const int cg0 = lrow * 8;                  // channel sub-offset in k-tile

  const unsigned short* p9[9];
#pragma unroll
  for (int dy = 0; dy < 3; ++dy)
#pragma unroll
    for (int dx = 0; dx < 3; ++dx)
      p9[dy * 3 + dx] = h1 + (((long)b * 65536 + (gy + dy - 1) * 256 + (gx + dx - 1)) * 384 + cg0);

  f32x4 acc[6];
#pragma unroll
  for (int nt = 0; nt < 6; ++nt) { f32x4 z = {0.f, 0.f, 0.f, 0.f}; acc[nt] = z; }

  __syncthreads();

  const bool edge = (ty0 == 0) | (ty0 == 248) | (tx0 == 0) | (tx0 == 248);
  if (!edge) {
    // -------- interior fast path: unconditional loads, 2-deep ping-pong
    uint4 bufA[9], bufB[9];
#pragma unroll
    for (int t = 0; t < 9; ++t) bufA[t] = *(const uint4*)(p9[t]);
#pragma unroll
    for (int k2 = 0; k2 < 6; ++k2) {
      const int ktA = 2 * k2, ktB = 2 * k2 + 1;
#pragma unroll
      for (int t = 0; t < 9; ++t) bufB[t] = *(const uint4*)(p9[t] + ktB * 32);
      bf16x8 pa = dwconv_gelu(bufA, wsh, wb, ktA * 32 + cg0);
#pragma unroll
      for (int nt = 0; nt < 6; ++nt)
        acc[nt] = MFMA(pa, ldw(wswz, W2_T + ktA * 6 + nt, lane), acc[nt]);
      if (k2 < 5) {
#pragma unroll
        for (int t = 0; t < 9; ++t) bufA[t] = *(const uint4*)(p9[t] + (ktB + 1) * 32);
      }
      bf16x8 pb = dwconv_gelu(bufB, wsh, wb, ktB * 32 + cg0);
#pragma unroll
      for (int nt = 0; nt < 6; ++nt)
        acc[nt] = MFMA(pb, ldw(wswz, W2_T + ktB * 6 + nt, lane), acc[nt]);
    }
  } else {
    // -------- edge path: predicated loads (12% of blocks)
    bool ok9[9];
#pragma unroll
    for (int dy = 0; dy < 3; ++dy)
#pragma unroll
      for (int dx = 0; dx < 3; ++dx)
        ok9[dy * 3 + dx] = ((unsigned)(gy + dy - 1) < 256u) && ((unsigned)(gx + dx - 1) < 256u);
    for (int kt = 0; kt < 12; ++kt) {
      uint4 cur[9];
#pragma unroll
      for (int t = 0; t < 9; ++t) {
        uint4 dv = make_uint4(0u, 0u, 0u, 0u);
        if (ok9[t]) dv = *(const uint4*)(p9[t] + kt * 32);
        cur[t] = dv;
      }
      bf16x8 pa = dwconv_gelu(cur, wsh, wb, kt * 32 + cg0);
#pragma unroll
      for (int nt = 0; nt < 6; ++nt)
        acc[nt] = MFMA(pa, ldw(wswz, W2_T + kt * 6 + nt, lane), acc[nt]);
    }
  }

  // ---- epilogue: + bl2 + residual(x2) -> out
#pragma unroll
  for (int nt = 0; nt < 6; ++nt) {
    int c = nt * 16 + lcol;
    float bb = bl2[c];
#pragma unroll
    for (int r = 0; r < 4; ++r) {
      int mm = w * 16 + lrow * 4 + r;
      int oy = ty0 + (mm >> 3), ox = tx0 + (mm & 7);
      long row = (long)b * 65536 + oy * 256 + ox;
      out[row * 96 + c] = acc[nt][r] + bb + x2[row * 96 + c];
    }
  }
}

// ---------------------------------------------------------------------------
extern "C" void kernel_launch(void* const* d_in, const int* in_sizes, int n_in,
                              void* d_out, int out_size, void* d_ws, size_t ws_size,
                              hipStream_t stream) {
  const float* x   = (const float*)d_in[0];
  const float* g1  = (const float*)d_in[1];
  const float* b1  = (const float*)d_in[2];
  const float* wq  = (const float*)d_in[3];
  const float* bq  = (const float*)d_in[4];
  const float* wkv = (const float*)d_in[5];
  const float* bkv = (const float*)d_in[6];
  const float* rpb = (const float*)d_in[7];
  const float* wp  = (const float*)d_in[8];
  const float* bp  = (const float*)d_in[9];
  const float* g2  = (const float*)d_in[10];
  const float* b2  = (const float*)d_in[11];
  const float* w1  = (const float*)d_in[12];
  const float* bl1 = (const float*)d_in[13];
  const float* wdw = (const float*)d_in[14];
  const float* bdw = (const float*)d_in[15];
  const float* w2  = (const float*)d_in[16];
  const float* bl2 = (const float*)d_in[17];

  char* ws = (char*)d_ws;
  unsigned short* wswz = (unsigned short*)ws;                      // 221 KB
  float* wdwT = (float*)(ws + (size_t)(256 << 10));                // 13.8 KB @256KB
  float* x2 = (float*)(ws + (size_t)(4 << 20));                    // 100.7 MB
  unsigned short* h1 = (unsigned short*)(ws + (size_t)(4 << 20) + 100663296); // 201.3 MB
  float* outp = (float*)d_out;

  kwconv<<<68, 256, 0, stream>>>(wq, wkv, wp, w1, w2, wdw, wswz, wdwT);
  kattn<<<4096, 256, 0, stream>>>(x, g1, b1, bq, bkv, rpb, bp, wswz, x2);
  kleff1<<<4096, 256, 0, stream>>>(x2, g2, b2, bl1, wswz, h1);
  kleff2<<<4096, 256, 0, stream>>>(h1, wdwT, bdw, bl2, wswz, x2, outp);
}

// Round 5
// 593.322 us; speedup vs baseline: 1.1057x; 1.0227x over previous
//
#include <hip/hip_runtime.h>
#include <math.h>

// ---------------------------------------------------------------------------
// Swin/Uformer block, MI355X. Sizes fixed: B=4 H=W=256 C=96 NH=3 HD=32 WIN=8
// N=64 HID=384. 4 kernels:
//   kwconv : f32 weights -> bf16 pre-swizzled B-frags; + wdw transposed f32
//   kattn  : LN1 + QKV + window-attn (+rpb bias, softmax) + proj + residual
//   kleff1 : LN2 + FC1 + GELU -> h1 (bf16), stores transposed through LDS
//   kleff2 : depthwise 3x3 + GELU + FC2 + residual; per-lane conv into MFMA
//            A-frags; 2-deep (pair) register prefetch, __launch_bounds__(256,2)
// MFMA 16x16x32 bf16 layouts used throughout:
//   A-frag: lane = (m%16) + 16*(k%32/8), elem = k%8
//   B-frag: lane = (n%16) + 16*(k%32/8), elem = k%8
//   C/D   : row  = 4*(lane/16)+reg, col = lane%16
// ---------------------------------------------------------------------------

typedef __attribute__((ext_vector_type(8))) short bf16x8;
typedef __attribute__((ext_vector_type(4))) float f32x4;
typedef __attribute__((ext_vector_type(2))) float f32x2;

#define MFMA(a, b, c) __builtin_amdgcn_mfma_f32_16x16x32_bf16((a), (b), (c), 0, 0, 0)

// weight tile bases (in 16x32 B-fragment tiles of 64 lanes * 16B)
#define WQ_T 0
#define WKV_T 18
#define WP_T 54
#define W1_T 72
#define W2_T 144
#define NTILES_TOT 216

__device__ __forceinline__ unsigned short f2bf(float f) {
  union { float f; unsigned u; } v; v.f = f;
  unsigned r = v.u + 0x7FFFu + ((v.u >> 16) & 1u);
  return (unsigned short)(r >> 16);
}
__device__ __forceinline__ float asf(unsigned u) {
  union { unsigned u; float f; } v; v.u = u; return v.f;
}
__device__ __forceinline__ unsigned cvtpk_bf16(float lo, float hi) {
  unsigned r;
  asm("v_cvt_pk_bf16_f32 %0, %1, %2" : "=v"(r) : "v"(lo), "v"(hi));
  return r;
}
// gelu(x) = x * sigmoid(2z), z = 0.7978845608 x (1 + 0.044715 x^2)
__device__ __forceinline__ float gelu(float x) {
  float t = x * x;
  float w = x * fmaf(t, -0.07135941f, -1.5957691f);   // -2z
  float a = __expf(w);
  return x * __builtin_amdgcn_rcpf(1.f + a);
}
__device__ __forceinline__ bf16x8 ldw(const unsigned short* wswz, int tile, int lane) {
  return *(const bf16x8*)(wswz + ((size_t)(tile * 64 + lane)) * 8);
}
__device__ __forceinline__ int xcd_swz(int bid) {   // 4096 % 8 == 0 -> bijective
  return (bid & 7) * 512 + (bid >> 3);
}

// --------------------------- weight convert/swizzle ------------------------
__global__ void kwconv(const float* __restrict__ wq, const float* __restrict__ wkv,
                       const float* __restrict__ wp, const float* __restrict__ w1,
                       const float* __restrict__ w2, const float* __restrict__ wdw,
                       unsigned short* __restrict__ wswz, float* __restrict__ wdwT) {
  int tid = blockIdx.x * 256 + threadIdx.x;
  if (tid >= NTILES_TOT * 64) {
    int i = tid - NTILES_TOT * 64;
    if (i < 3456) {                       // wdw (384,1,3,3) -> wdwT [tap][384]
      int ch = i % 384, tap = i / 384;
      wdwT[tap * 384 + ch] = wdw[ch * 9 + tap];
    }
    return;
  }
  int e = tid; const float* src; int N, NT;
  if (e < 1152)      { src = wq;  N = 96;  NT = 6; }
  else if (e < 3456) { src = wkv; N = 192; NT = 12; e -= 1152; }
  else if (e < 4608) { src = wp;  N = 96;  NT = 6;  e -= 3456; }
  else if (e < 9216) { src = w1;  N = 384; NT = 24; e -= 4608; }
  else               { src = w2;  N = 96;  NT = 6;  e -= 9216; }
  int lane = e & 63, t = e >> 6;
  int nt = t % NT, kt = t / NT;
  int k0 = kt * 32 + (lane >> 4) * 8;
  int n = nt * 16 + (lane & 15);
  unsigned short* dst = wswz + (size_t)tid * 8;
#pragma unroll
  for (int i = 0; i < 8; ++i) dst[i] = f2bf(src[(size_t)(k0 + i) * N + n]);
}

// --------------------------- attention block -------------------------------
__global__ __launch_bounds__(256) void kattn(
    const float* __restrict__ x, const float* __restrict__ g1, const float* __restrict__ b1,
    const float* __restrict__ bq, const float* __restrict__ bkv,
    const float* __restrict__ rpb, const float* __restrict__ bp,
    const unsigned short* __restrict__ wswz, float* __restrict__ x2) {
  __shared__ __align__(16) unsigned short sm0[4 * 3 * 64 * 8];   // xn_swz, later y_swz (12KB)
  __shared__ __align__(16) unsigned short sm1[24 * 64 * 8];      // q(12 tiles)+k(12) then p(24) (24KB)
  __shared__ __align__(16) unsigned short sm2[3 * 2 * 2 * 64 * 8]; // v (12KB)

  const int tid = threadIdx.x;
  const int lane = tid & 63, w = tid >> 6;
  const int lrow = lane >> 4, lcol = lane & 15;
  const int wi = xcd_swz(blockIdx.x);
  const int b = wi >> 10, wy = (wi >> 5) & 31, wx = wi & 31;

  long rowoff[4];
#pragma unroll
  for (int r = 0; r < 4; ++r) {
    int m = w * 16 + lrow * 4 + r;
    int gy = wy * 8 + (m >> 3), gx = wx * 8 + (m & 7);
    rowoff[r] = ((long)b * 65536 + gy * 256 + gx) * 96;
  }

  // ---- phase 0: load x (C/D-layout regs), LN1, write xn to A-swz LDS
  float xv[4][6], xn[4][6], gv[6], bv[6];
#pragma unroll
  for (int nt = 0; nt < 6; ++nt) {
    int c = nt * 16 + lcol;
    gv[nt] = g1[c]; bv[nt] = b1[c];
#pragma unroll
    for (int r = 0; r < 4; ++r) xv[r][nt] = x[rowoff[r] + c];
  }
#pragma unroll
  for (int r = 0; r < 4; ++r) {
    float s = 0.f, sq = 0.f;
#pragma unroll
    for (int nt = 0; nt < 6; ++nt) { float v = xv[r][nt]; s += v; sq += v * v; }
#pragma unroll
    for (int off = 1; off <= 8; off <<= 1) { s += __shfl_xor(s, off, 64); sq += __shfl_xor(sq, off, 64); }
    float mean = s * (1.f / 96.f);
    float var = sq * (1.f / 96.f) - mean * mean;
    float rs = rsqrtf(var + 1e-5f);
#pragma unroll
    for (int nt = 0; nt < 6; ++nt) xn[r][nt] = (xv[r][nt] - mean) * rs * gv[nt] + bv[nt];
  }
#pragma unroll
  for (int r = 0; r < 4; ++r) {
    int mm = lrow * 4 + r;
#pragma unroll
    for (int nt = 0; nt < 6; ++nt) {
      int c = nt * 16 + lcol;
      int kt = c >> 5;
      int lanew = mm + (((c & 31) >> 3) << 4);
      sm0[((w * 3 + kt) * 64 + lanew) * 8 + (c & 7)] = f2bf(xn[r][nt]);
    }
  }
  __syncthreads();

  // ---- phase 1: QKV GEMM (M=64 N=288 K=96), wave w owns m-tile w
  bf16x8 af[3];
#pragma unroll
  for (int kt = 0; kt < 3; ++kt) af[kt] = *(const bf16x8*)(sm0 + ((w * 3 + kt) * 64 + lane) * 8);
  for (int nt = 0; nt < 18; ++nt) {
    f32x4 acc = {0.f, 0.f, 0.f, 0.f};
#pragma unroll
    for (int kt = 0; kt < 3; ++kt) {
      int tile = (nt < 6) ? (WQ_T + kt * 6 + nt) : (WKV_T + kt * 12 + (nt - 6));
      acc = MFMA(af[kt], ldw(wswz, tile, lane), acc);
    }
    int c = nt * 16 + lcol;
#pragma unroll
    for (int r = 0; r < 4; ++r) {
      int m = w * 16 + lrow * 4 + r;
      float val = acc[r];
      if (c < 96) {                 // q (pre-scaled)
        val = (val + bq[c]) * 0.17677669529663687f;
        int head = c >> 5, d = c & 31;
        sm1[((head * 4 + w) * 64 + (m & 15) + ((d >> 3) << 4)) * 8 + (d & 7)] = f2bf(val);
      } else if (c < 192) {         // k
        int kc = c - 96;
        val += bkv[kc];
        int head = kc >> 5, d = kc & 31;
        sm1[((12 + head * 4 + w) * 64 + (m & 15) + ((d >> 3) << 4)) * 8 + (d & 7)] = f2bf(val);
      } else {                      // v (B-frag layout: k-dim = key token)
        int vc = c - 192;
        val += bkv[96 + vc];
        int head = vc >> 5, d = vc & 31;
        int ktile = m >> 5, nt2 = d >> 4;
        sm2[(((head * 2 + ktile) * 2 + nt2) * 64 + (d & 15) + (((m & 31) >> 3) << 4)) * 8 + (m & 7)] = f2bf(val);
      }
    }
  }
  __syncthreads();

  // ---- phase 2: scores. unit u=(head,mtq); wave w owns u = 3w..3w+2
  f32x4 sc[3][4];
#pragma unroll
  for (int uu = 0; uu < 3; ++uu) {
    int u = w * 3 + uu, head = u >> 2, mtq = u & 3;
    bf16x8 aq = *(const bf16x8*)(sm1 + ((head * 4 + mtq) * 64 + lane) * 8);
#pragma unroll
    for (int nt = 0; nt < 4; ++nt) {
      bf16x8 bk = *(const bf16x8*)(sm1 + ((12 + head * 4 + nt) * 64 + lane) * 8);
      f32x4 z = {0.f, 0.f, 0.f, 0.f};
      sc[uu][nt] = MFMA(aq, bk, z);
    }
  }
  __syncthreads();   // all q/k reads done; sm1 may now be overwritten with P

  // ---- phase 3: +rpb bias, softmax (in-register), write P to A-swz LDS
#pragma unroll
  for (int uu = 0; uu < 3; ++uu) {
    int u = w * 3 + uu, head = u >> 2, mtq = u & 3;
#pragma unroll
    for (int nt = 0; nt < 4; ++nt) {
      int ktok = nt * 16 + lcol;
#pragma unroll
      for (int r = 0; r < 4; ++r) {
        int qtok = mtq * 16 + lrow * 4 + r;
        int dy = (qtok >> 3) - (ktok >> 3) + 7;
        int dx = (qtok & 7) - (ktok & 7) + 7;
        sc[uu][nt][r] += rpb[(dy * 15 + dx) * 3 + head];
      }
    }
#pragma unroll
    for (int r = 0; r < 4; ++r) {
      float mx = fmaxf(fmaxf(sc[uu][0][r], sc[uu][1][r]), fmaxf(sc[uu][2][r], sc[uu][3][r]));
#pragma unroll
      for (int off = 1; off <= 8; off <<= 1) mx = fmaxf(mx, __shfl_xor(mx, off, 64));
      float p[4], sum = 0.f;
#pragma unroll
      for (int nt = 0; nt < 4; ++nt) { p[nt] = __expf(sc[uu][nt][r] - mx); sum += p[nt]; }
#pragma unroll
      for (int off = 1; off <= 8; off <<= 1) sum += __shfl_xor(sum, off, 64);
      float inv = 1.f / sum;
#pragma unroll
      for (int nt = 0; nt < 4; ++nt) sc[uu][nt][r] = p[nt] * inv;
    }
#pragma unroll
    for (int nt = 0; nt < 4; ++nt) {
      int ktok = nt * 16 + lcol;
      int ktile = ktok >> 5, lhi = (ktok & 31) >> 3;
#pragma unroll
      for (int r = 0; r < 4; ++r) {
        int mm = lrow * 4 + r;
        sm1[(((head * 4 + mtq) * 2 + ktile) * 64 + mm + (lhi << 4)) * 8 + (ktok & 7)] = f2bf(sc[uu][nt][r]);
      }
    }
  }
  __syncthreads();

  // ---- phase 4: PV, write y to A-swz LDS (reuse sm0; head = k-tile)
#pragma unroll
  for (int uu = 0; uu < 3; ++uu) {
    int u = w * 3 + uu, head = u >> 2, mtq = u & 3;
#pragma unroll
    for (int nt2 = 0; nt2 < 2; ++nt2) {
      f32x4 acc = {0.f, 0.f, 0.f, 0.f};
#pragma unroll
      for (int ktile = 0; ktile < 2; ++ktile) {
        bf16x8 ap = *(const bf16x8*)(sm1 + (((head * 4 + mtq) * 2 + ktile) * 64 + lane) * 8);
        bf16x8 bv8 = *(const bf16x8*)(sm2 + (((head * 2 + ktile) * 2 + nt2) * 64 + lane) * 8);
        acc = MFMA(ap, bv8, acc);
      }
      int d0 = nt2 * 16 + lcol;
#pragma unroll
      for (int r = 0; r < 4; ++r) {
        int mm = lrow * 4 + r;
        sm0[((mtq * 3 + head) * 64 + mm + ((d0 >> 3) << 4)) * 8 + (d0 & 7)] = f2bf(acc[r]);
      }
    }
  }
  __syncthreads();

  // ---- phase 5: proj + bias + residual -> x2
  bf16x8 ay[3];
#pragma unroll
  for (int kt = 0; kt < 3; ++kt) ay[kt] = *(const bf16x8*)(sm0 + ((w * 3 + kt) * 64 + lane) * 8);
#pragma unroll
  for (int nt = 0; nt < 6; ++nt) {
    f32x4 acc = {0.f, 0.f, 0.f, 0.f};
#pragma unroll
    for (int kt = 0; kt < 3; ++kt) acc = MFMA(ay[kt], ldw(wswz, WP_T + kt * 6 + nt, lane), acc);
    int c = nt * 16 + lcol;
    float bpc = bp[c];
#pragma unroll
    for (int r = 0; r < 4; ++r) x2[rowoff[r] + c] = acc[r] + bpc + xv[r][nt];
  }
}

// --------------------------- LN2 + FC1 + GELU ------------------------------
__global__ __launch_bounds__(256) void kleff1(
    const float* __restrict__ x2, const float* __restrict__ g2, const float* __restrict__ b2,
    const float* __restrict__ bl1, const unsigned short* __restrict__ wswz,
    unsigned short* __restrict__ h1) {
  __shared__ __align__(16) unsigned short sm0[4 * 3 * 64 * 8];   // 12.3KB
  __shared__ __align__(16) unsigned short trbuf[64 * 200];       // 25.6KB (192ch half, +8 pad)
  const int tid = threadIdx.x, lane = tid & 63, w = tid >> 6;
  const int lrow = lane >> 4, lcol = lane & 15;
  const long tbase = (long)xcd_swz(blockIdx.x) * 64;

  float xv[4][6], gv[6], bv[6];
#pragma unroll
  for (int nt = 0; nt < 6; ++nt) {
    int c = nt * 16 + lcol;
    gv[nt] = g2[c]; bv[nt] = b2[c];
#pragma unroll
    for (int r = 0; r < 4; ++r) xv[r][nt] = x2[(tbase + w * 16 + lrow * 4 + r) * 96 + c];
  }
#pragma unroll
  for (int r = 0; r < 4; ++r) {
    float s = 0.f, sq = 0.f;
#pragma unroll
    for (int nt = 0; nt < 6; ++nt) { float v = xv[r][nt]; s += v; sq += v * v; }
#pragma unroll
    for (int off = 1; off <= 8; off <<= 1) { s += __shfl_xor(s, off, 64); sq += __shfl_xor(sq, off, 64); }
    float mean = s * (1.f / 96.f);
    float var = sq * (1.f / 96.f) - mean * mean;
    float rs = rsqrtf(var + 1e-5f);
#pragma unroll
    for (int nt = 0; nt < 6; ++nt) xv[r][nt] = (xv[r][nt] - mean) * rs * gv[nt] + bv[nt];
  }
#pragma unroll
  for (int r = 0; r < 4; ++r) {
    int mm = lrow * 4 + r;
#pragma unroll
    for (int nt = 0; nt < 6; ++nt) {
      int c = nt * 16 + lcol;
      int kt = c >> 5;
      int lanew = mm + (((c & 31) >> 3) << 4);
      sm0[((w * 3 + kt) * 64 + lanew) * 8 + (c & 7)] = f2bf(xv[r][nt]);
    }
  }
  __syncthreads();

  bf16x8 af[3];
#pragma unroll
  for (int kt = 0; kt < 3; ++kt) af[kt] = *(const bf16x8*)(sm0 + ((w * 3 + kt) * 64 + lane) * 8);

  for (int half = 0; half < 2; ++half) {
#pragma unroll
    for (int nt2 = 0; nt2 < 12; ++nt2) {
      int nt = half * 12 + nt2;
      f32x4 acc = {0.f, 0.f, 0.f, 0.f};
#pragma unroll
      for (int kt = 0; kt < 3; ++kt) acc = MFMA(af[kt], ldw(wswz, W1_T + kt * 24 + nt, lane), acc);
      int cl = nt2 * 16 + lcol;                 // 0..191 within half
      float bb = bl1[half * 192 + cl];
#pragma unroll
      for (int r = 0; r < 4; ++r) {
        int m = w * 16 + lrow * 4 + r;
        trbuf[m * 200 + cl] = f2bf(gelu(acc[r] + bb));
      }
    }
    __syncthreads();
    // coalesced writeout: 1536 x 16B chunks
#pragma unroll
    for (int j = 0; j < 6; ++j) {
      int idx = tid + j * 256;
      int token = idx / 24, c0 = (idx % 24) * 8;
      uint4 v = *(const uint4*)(trbuf + token * 200 + c0);
      *(uint4*)(h1 + (tbase + token) * 384 + half * 192 + c0) = v;
    }
    __syncthreads();
  }
}

// --------------- depthwise 3x3 + GELU + FC2 + residual ---------------------
// conv computed per-lane directly into the consuming lane's A-fragment:
// lane l of wave w owns pixel w*16+(l&15), channels kt*32+(l>>4)*8 .. +7.
// 2-deep pair prefetch (18 uint4 in flight), 3 row-pointers + imm offsets.
__device__ __forceinline__ bf16x8 dwconv_gelu(const uint4* cur,
    const float* wsh, const float* wb, int ch) {
  f32x2 a2[4];
#pragma unroll
  for (int j = 0; j < 4; ++j) a2[j] = (f32x2){0.f, 0.f};
#pragma unroll
  for (int t = 0; t < 9; ++t) {
    f32x4 wlo = *(const f32x4*)(wsh + t * 384 + ch);
    f32x4 whi = *(const f32x4*)(wsh + t * 384 + ch + 4);
    const unsigned* du = (const unsigned*)(cur + t);
    f32x2 d0 = { asf(du[0] << 16), asf(du[0] & 0xffff0000u) };
    f32x2 d1 = { asf(du[1] << 16), asf(du[1] & 0xffff0000u) };
    f32x2 d2 = { asf(du[2] << 16), asf(du[2] & 0xffff0000u) };
    f32x2 d3 = { asf(du[3] << 16), asf(du[3] & 0xffff0000u) };
    f32x2 w0 = {wlo.x, wlo.y}, w1 = {wlo.z, wlo.w};
    f32x2 w2v = {whi.x, whi.y}, w3 = {whi.z, whi.w};
    a2[0] += d0 * w0; a2[1] += d1 * w1; a2[2] += d2 * w2v; a2[3] += d3 * w3;
  }
  f32x4 blo = *(const f32x4*)(wb + ch);
  f32x4 bhi = *(const f32x4*)(wb + ch + 4);
  union { unsigned u[4]; bf16x8 v; } pk;
  pk.u[0] = cvtpk_bf16(gelu(a2[0].x + blo.x), gelu(a2[0].y + blo.y));
  pk.u[1] = cvtpk_bf16(gelu(a2[1].x + blo.z), gelu(a2[1].y + blo.w));
  pk.u[2] = cvtpk_bf16(gelu(a2[2].x + bhi.x), gelu(a2[2].y + bhi.y));
  pk.u[3] = cvtpk_bf16(gelu(a2[3].x + bhi.z), gelu(a2[3].y + bhi.w));
  return pk.v;
}

// load the 18 taps of k-tile pair kp (kt = 2kp, 2kp+1) -- interior path
#define LOADPAIR(buf, kp)                                                     \
  {                                                                           \
    _Pragma("unroll")                                                         \
    for (int dy = 0; dy < 3; ++dy) {                                          \
      const char* base = (const char*)pr[dy];                                 \
      _Pragma("unroll")                                                       \
      for (int dx = 0; dx < 3; ++dx) {                                        \
        buf[dy * 3 + dx]     = *(const uint4*)(base + (dx - 1) * 768 + (kp) * 128);      \
        buf[9 + dy * 3 + dx] = *(const uint4*)(base + (dx - 1) * 768 + (kp) * 128 + 64); \
      }                                                                       \
    }                                                                         \
  }

#define COMPUTEPAIR(buf, kp)                                                  \
  {                                                                           \
    bf16x8 pa = dwconv_gelu(buf, wsh, wb, (2 * (kp)) * 32 + cg0);             \
    _Pragma("unroll")                                                         \
    for (int nt = 0; nt < 6; ++nt)                                            \
      acc[nt] = MFMA(pa, ldw(wswz, W2_T + (2 * (kp)) * 6 + nt, lane), acc[nt]); \
    bf16x8 pb = dwconv_gelu(buf + 9, wsh, wb, (2 * (kp) + 1) * 32 + cg0);     \
    _Pragma("unroll")                                                         \
    for (int nt = 0; nt < 6; ++nt)                                            \
      acc[nt] = MFMA(pb, ldw(wswz, W2_T + (2 * (kp) + 1) * 6 + nt, lane), acc[nt]); \
  }

__global__ __launch_bounds__(256, 2) void kleff2(
    const unsigned short* __restrict__ h1, const float* __restrict__ wdwT,
    const float* __restrict__ bdw, const float* __restrict__ bl2,
    const unsigned short* __restrict__ wswz, const float* __restrict__ x2,
    float* __restrict__ out) {
  __shared__ __align__(16) float wsh[9 * 384 + 384];   // 15.4KB: taps f32 + bias f32
  const int tid = threadIdx.x, lane = tid & 63, w = tid >> 6;
  const int lrow = lane >> 4, lcol = lane & 15;
  const int bid = xcd_swz(blockIdx.x);
  const int b = bid >> 10, ty0 = ((bid >> 5) & 31) * 8, tx0 = (bid & 31) * 8;

  // stage dw weights + bias once (960 float4)
  for (int i = tid; i < 960; i += 256) {
    float4 v = (i < 864) ? ((const float4*)wdwT)[i] : ((const float4*)bdw)[i - 864];
    ((float4*)wsh)[i] = v;
  }
  const float* wb = wsh + 3456;

  const int px = w * 16 + lcol;              // this lane's pixel 0..63
  const int gy = ty0 + (px >> 3), gx = tx0 + (px & 7);
  const int cg0 = lrow * 8;                  // channel sub-offset in k-tile

  // 3 row base pointers (center column); dx and kt folded into imm offsets
  const unsigned short* pr[3];
#pragma unroll
  for (int dy = 0; dy < 3; ++dy)
    pr[dy] = h1 + (((long)b * 65536 + (gy + dy - 1) * 256 + gx) * 384 + cg0);

  f32x4 acc[6];
#pragma unroll
  for (int nt = 0; nt < 6; ++nt) { f32x4 z = {0.f, 0.f, 0.f, 0.f}; acc[nt] = z; }

  __syncthreads();

  const bool edge = (ty0 == 0) | (ty0 == 248) | (tx0 == 0) | (tx0 == 248);
  if (!edge) {
    // -------- interior fast path: 2-deep pair pipeline, fully unrolled
    uint4 bE[18], bO[18];
    LOADPAIR(bE, 0);
    LOADPAIR(bO, 1);
    COMPUTEPAIR(bE, 0);
    LOADPAIR(bE, 2);
    COMPUTEPAIR(bO, 1);
    LOADPAIR(bO, 3);
    COMPUTEPAIR(bE, 2);
    LOADPAIR(bE, 4);
    COMPUTEPAIR(bO, 3);
    LOADPAIR(bO, 5);
    COMPUTEPAIR(bE, 4);
    COMPUTEPAIR(bO, 5);
  } else {
    // -------- edge path: predicated loads (12% of blocks)
    bool ok9[9];
#pragma unroll
    for (int dy = 0; dy < 3; ++dy)
#pragma unroll
      for (int dx = 0; dx < 3; ++dx)
        ok9[dy * 3 + dx] = ((unsigned)(gy + dy - 1) < 256u) && ((unsigned)(gx + dx - 1) < 256u);
    for (int kt = 0; kt < 12; ++kt) {
      uint4 cur[9];
#pragma unroll
      for (int dy = 0; dy < 3; ++dy)
#pragma unroll
        for (int dx = 0; dx < 3; ++dx) {
          uint4 dv = make_uint4(0u, 0u, 0u, 0u);
          if (ok9[dy * 3 + dx])
            dv = *(const uint4*)((const char*)pr[dy] + (dx - 1) * 768 + kt * 64);
          cur[dy * 3 + dx] = dv;
        }
      bf16x8 pa = dwconv_gelu(cur, wsh, wb, kt * 32 + cg0);
#pragma unroll
      for (int nt = 0; nt < 6; ++nt)
        acc[nt] = MFMA(pa, ldw(wswz, W2_T + kt * 6 + nt, lane), acc[nt]);
    }
  }

  // ---- epilogue: + bl2 + residual(x2) -> out
#pragma unroll
  for (int nt = 0; nt < 6; ++nt) {
    int c = nt * 16 + lcol;
    float bb = bl2[c];
#pragma unroll
    for (int r = 0; r < 4; ++r) {
      int mm = w * 16 + lrow * 4 + r;
      int oy = ty0 + (mm >> 3), ox = tx0 + (mm & 7);
      long row = (long)b * 65536 + oy * 256 + ox;
      out[row * 96 + c] = acc[nt][r] + bb + x2[row * 96 + c];
    }
  }
}

// ---------------------------------------------------------------------------
extern "C" void kernel_launch(void* const* d_in, const int* in_sizes, int n_in,
                              void* d_out, int out_size, void* d_ws, size_t ws_size,
                              hipStream_t stream) {
  const float* x   = (const float*)d_in[0];
  const float* g1  = (const float*)d_in[1];
  const float* b1  = (const float*)d_in[2];
  const float* wq  = (const float*)d_in[3];
  const float* bq  = (const float*)d_in[4];
  const float* wkv = (const float*)d_in[5];
  const float* bkv = (const float*)d_in[6];
  const float* rpb = (const float*)d_in[7];
  const float* wp  = (const float*)d_in[8];
  const float* bp  = (const float*)d_in[9];
  const float* g2  = (const float*)d_in[10];
  const float* b2  = (const float*)d_in[11];
  const float* w1  = (const float*)d_in[12];
  const float* bl1 = (const float*)d_in[13];
  const float* wdw = (const float*)d_in[14];
  const float* bdw = (const float*)d_in[15];
  const float* w2  = (const float*)d_in[16];
  const float* bl2 = (const float*)d_in[17];

  char* ws = (char*)d_ws;
  unsigned short* wswz = (unsigned short*)ws;                      // 221 KB
  float* wdwT = (float*)(ws + (size_t)(256 << 10));                // 13.8 KB @256KB
  float* x2 = (float*)(ws + (size_t)(4 << 20));                    // 100.7 MB
  unsigned short* h1 = (unsigned short*)(ws + (size_t)(4 << 20) + 100663296); // 201.3 MB
  float* outp = (float*)d_out;

  kwconv<<<68, 256, 0, stream>>>(wq, wkv, wp, w1, w2, wdw, wswz, wdwT);
  kattn<<<4096, 256, 0, stream>>>(x, g1, b1, bq, bkv, rpb, bp, wswz, x2);
  kleff1<<<4096, 256, 0, stream>>>(x2, g2, b2, bl1, wswz, h1);
  kleff2<<<4096, 256, 0, stream>>>(h1, wdwT, bdw, bl2, wswz, x2, outp);
}

// Round 6
// 576.088 us; speedup vs baseline: 1.1387x; 1.0299x over previous
//
#include <hip/hip_runtime.h>
#include <math.h>

// ---------------------------------------------------------------------------
// Swin/Uformer block, MI355X. Sizes fixed: B=4 H=W=256 C=96 NH=3 HD=32 WIN=8
// N=64 HID=384. 4 kernels:
//   kwconv : f32 weights -> bf16 pre-swizzled B-frags; + wdw transposed f32
//   kattn  : LN1 + QKV + window-attn (+rpb bias, softmax) + proj + residual
//   kleff1 : LN2 + FC1 + GELU -> h1 (bf16), stores transposed through LDS
//   kleff2 : depthwise 3x3 + GELU + FC2 + residual; per-lane conv into MFMA
//            A-frags; inline-asm load pipeline (counted vmcnt), zeropage halo
// MFMA 16x16x32 bf16 layouts used throughout:
//   A-frag: lane = (m%16) + 16*(k%32/8), elem = k%8
//   B-frag: lane = (n%16) + 16*(k%32/8), elem = k%8
//   C/D   : row  = 4*(lane/16)+reg, col = lane%16
// ---------------------------------------------------------------------------

typedef __attribute__((ext_vector_type(8))) short bf16x8;
typedef __attribute__((ext_vector_type(4))) float f32x4;
typedef __attribute__((ext_vector_type(2))) float f32x2;

#define MFMA(a, b, c) __builtin_amdgcn_mfma_f32_16x16x32_bf16((a), (b), (c), 0, 0, 0)

// weight tile bases (in 16x32 B-fragment tiles of 64 lanes * 16B)
#define WQ_T 0
#define WKV_T 18
#define WP_T 54
#define W1_T 72
#define W2_T 144
#define NTILES_TOT 216

__device__ __forceinline__ unsigned short f2bf(float f) {
  union { float f; unsigned u; } v; v.f = f;
  unsigned r = v.u + 0x7FFFu + ((v.u >> 16) & 1u);
  return (unsigned short)(r >> 16);
}
__device__ __forceinline__ float asf(unsigned u) {
  union { unsigned u; float f; } v; v.u = u; return v.f;
}
__device__ __forceinline__ unsigned cvtpk_bf16(float lo, float hi) {
  unsigned r;
  asm("v_cvt_pk_bf16_f32 %0, %1, %2" : "=v"(r) : "v"(lo), "v"(hi));
  return r;
}
// gelu(x) = x * sigmoid(2z), z = 0.7978845608 x (1 + 0.044715 x^2)
__device__ __forceinline__ float gelu(float x) {
  float t = x * x;
  float w = x * fmaf(t, -0.07135941f, -1.5957691f);   // -2z
  float a = __expf(w);
  return x * __builtin_amdgcn_rcpf(1.f + a);
}
__device__ __forceinline__ bf16x8 ldw(const unsigned short* wswz, int tile, int lane) {
  return *(const bf16x8*)(wswz + ((size_t)(tile * 64 + lane)) * 8);
}
__device__ __forceinline__ int xcd_swz(int bid) {   // 4096 % 8 == 0 -> bijective
  return (bid & 7) * 512 + (bid >> 3);
}

// --------------------------- weight convert/swizzle ------------------------
__global__ void kwconv(const float* __restrict__ wq, const float* __restrict__ wkv,
                       const float* __restrict__ wp, const float* __restrict__ w1,
                       const float* __restrict__ w2, const float* __restrict__ wdw,
                       unsigned short* __restrict__ wswz, float* __restrict__ wdwT) {
  int tid = blockIdx.x * 256 + threadIdx.x;
  if (tid >= NTILES_TOT * 64) {
    int i = tid - NTILES_TOT * 64;
    if (i < 3456) {                       // wdw (384,1,3,3) -> wdwT [tap][384]
      int ch = i % 384, tap = i / 384;
      wdwT[tap * 384 + ch] = wdw[ch * 9 + tap];
    }
    return;
  }
  int e = tid; const float* src; int N, NT;
  if (e < 1152)      { src = wq;  N = 96;  NT = 6; }
  else if (e < 3456) { src = wkv; N = 192; NT = 12; e -= 1152; }
  else if (e < 4608) { src = wp;  N = 96;  NT = 6;  e -= 3456; }
  else if (e < 9216) { src = w1;  N = 384; NT = 24; e -= 4608; }
  else               { src = w2;  N = 96;  NT = 6;  e -= 9216; }
  int lane = e & 63, t = e >> 6;
  int nt = t % NT, kt = t / NT;
  int k0 = kt * 32 + (lane >> 4) * 8;
  int n = nt * 16 + (lane & 15);
  unsigned short* dst = wswz + (size_t)tid * 8;
#pragma unroll
  for (int i = 0; i < 8; ++i) dst[i] = f2bf(src[(size_t)(k0 + i) * N + n]);
}

// --------------------------- attention block -------------------------------
__global__ __launch_bounds__(256) void kattn(
    const float* __restrict__ x, const float* __restrict__ g1, const float* __restrict__ b1,
    const float* __restrict__ bq, const float* __restrict__ bkv,
    const float* __restrict__ rpb, const float* __restrict__ bp,
    const unsigned short* __restrict__ wswz, float* __restrict__ x2) {
  __shared__ __align__(16) unsigned short sm0[4 * 3 * 64 * 8];   // xn_swz, later y_swz (12KB)
  __shared__ __align__(16) unsigned short sm1[24 * 64 * 8];      // q(12 tiles)+k(12) then p(24) (24KB)
  __shared__ __align__(16) unsigned short sm2[3 * 2 * 2 * 64 * 8]; // v (12KB)

  const int tid = threadIdx.x;
  const int lane = tid & 63, w = tid >> 6;
  const int lrow = lane >> 4, lcol = lane & 15;
  const int wi = xcd_swz(blockIdx.x);
  const int b = wi >> 10, wy = (wi >> 5) & 31, wx = wi & 31;

  long rowoff[4];
#pragma unroll
  for (int r = 0; r < 4; ++r) {
    int m = w * 16 + lrow * 4 + r;
    int gy = wy * 8 + (m >> 3), gx = wx * 8 + (m & 7);
    rowoff[r] = ((long)b * 65536 + gy * 256 + gx) * 96;
  }

  // ---- phase 0: load x (C/D-layout regs), LN1, write xn to A-swz LDS
  float xv[4][6], xn[4][6], gv[6], bv[6];
#pragma unroll
  for (int nt = 0; nt < 6; ++nt) {
    int c = nt * 16 + lcol;
    gv[nt] = g1[c]; bv[nt] = b1[c];
#pragma unroll
    for (int r = 0; r < 4; ++r) xv[r][nt] = x[rowoff[r] + c];
  }
#pragma unroll
  for (int r = 0; r < 4; ++r) {
    float s = 0.f, sq = 0.f;
#pragma unroll
    for (int nt = 0; nt < 6; ++nt) { float v = xv[r][nt]; s += v; sq += v * v; }
#pragma unroll
    for (int off = 1; off <= 8; off <<= 1) { s += __shfl_xor(s, off, 64); sq += __shfl_xor(sq, off, 64); }
    float mean = s * (1.f / 96.f);
    float var = sq * (1.f / 96.f) - mean * mean;
    float rs = rsqrtf(var + 1e-5f);
#pragma unroll
    for (int nt = 0; nt < 6; ++nt) xn[r][nt] = (xv[r][nt] - mean) * rs * gv[nt] + bv[nt];
  }
#pragma unroll
  for (int r = 0; r < 4; ++r) {
    int mm = lrow * 4 + r;
#pragma unroll
    for (int nt = 0; nt < 6; ++nt) {
      int c = nt * 16 + lcol;
      int kt = c >> 5;
      int lanew = mm + (((c & 31) >> 3) << 4);
      sm0[((w * 3 + kt) * 64 + lanew) * 8 + (c & 7)] = f2bf(xn[r][nt]);
    }
  }
  __syncthreads();

  // ---- phase 1: QKV GEMM (M=64 N=288 K=96), wave w owns m-tile w
  bf16x8 af[3];
#pragma unroll
  for (int kt = 0; kt < 3; ++kt) af[kt] = *(const bf16x8*)(sm0 + ((w * 3 + kt) * 64 + lane) * 8);
  for (int nt = 0; nt < 18; ++nt) {
    f32x4 acc = {0.f, 0.f, 0.f, 0.f};
#pragma unroll
    for (int kt = 0; kt < 3; ++kt) {
      int tile = (nt < 6) ? (WQ_T + kt * 6 + nt) : (WKV_T + kt * 12 + (nt - 6));
      acc = MFMA(af[kt], ldw(wswz, tile, lane), acc);
    }
    int c = nt * 16 + lcol;
#pragma unroll
    for (int r = 0; r < 4; ++r) {
      int m = w * 16 + lrow * 4 + r;
      float val = acc[r];
      if (c < 96) {                 // q (pre-scaled)
        val = (val + bq[c]) * 0.17677669529663687f;
        int head = c >> 5, d = c & 31;
        sm1[((head * 4 + w) * 64 + (m & 15) + ((d >> 3) << 4)) * 8 + (d & 7)] = f2bf(val);
      } else if (c < 192) {         // k
        int kc = c - 96;
        val += bkv[kc];
        int head = kc >> 5, d = kc & 31;
        sm1[((12 + head * 4 + w) * 64 + (m & 15) + ((d >> 3) << 4)) * 8 + (d & 7)] = f2bf(val);
      } else {                      // v (B-frag layout: k-dim = key token)
        int vc = c - 192;
        val += bkv[96 + vc];
        int head = vc >> 5, d = vc & 31;
        int ktile = m >> 5, nt2 = d >> 4;
        sm2[(((head * 2 + ktile) * 2 + nt2) * 64 + (d & 15) + (((m & 31) >> 3) << 4)) * 8 + (m & 7)] = f2bf(val);
      }
    }
  }
  __syncthreads();

  // ---- phase 2: scores. unit u=(head,mtq); wave w owns u = 3w..3w+2
  f32x4 sc[3][4];
#pragma unroll
  for (int uu = 0; uu < 3; ++uu) {
    int u = w * 3 + uu, head = u >> 2, mtq = u & 3;
    bf16x8 aq = *(const bf16x8*)(sm1 + ((head * 4 + mtq) * 64 + lane) * 8);
#pragma unroll
    for (int nt = 0; nt < 4; ++nt) {
      bf16x8 bk = *(const bf16x8*)(sm1 + ((12 + head * 4 + nt) * 64 + lane) * 8);
      f32x4 z = {0.f, 0.f, 0.f, 0.f};
      sc[uu][nt] = MFMA(aq, bk, z);
    }
  }
  __syncthreads();   // all q/k reads done; sm1 may now be overwritten with P

  // ---- phase 3: +rpb bias, softmax (in-register), write P to A-swz LDS
#pragma unroll
  for (int uu = 0; uu < 3; ++uu) {
    int u = w * 3 + uu, head = u >> 2, mtq = u & 3;
#pragma unroll
    for (int nt = 0; nt < 4; ++nt) {
      int ktok = nt * 16 + lcol;
#pragma unroll
      for (int r = 0; r < 4; ++r) {
        int qtok = mtq * 16 + lrow * 4 + r;
        int dy = (qtok >> 3) - (ktok >> 3) + 7;
        int dx = (qtok & 7) - (ktok & 7) + 7;
        sc[uu][nt][r] += rpb[(dy * 15 + dx) * 3 + head];
      }
    }
#pragma unroll
    for (int r = 0; r < 4; ++r) {
      float mx = fmaxf(fmaxf(sc[uu][0][r], sc[uu][1][r]), fmaxf(sc[uu][2][r], sc[uu][3][r]));
#pragma unroll
      for (int off = 1; off <= 8; off <<= 1) mx = fmaxf(mx, __shfl_xor(mx, off, 64));
      float p[4], sum = 0.f;
#pragma unroll
      for (int nt = 0; nt < 4; ++nt) { p[nt] = __expf(sc[uu][nt][r] - mx); sum += p[nt]; }
#pragma unroll
      for (int off = 1; off <= 8; off <<= 1) sum += __shfl_xor(sum, off, 64);
      float inv = 1.f / sum;
#pragma unroll
      for (int nt = 0; nt < 4; ++nt) sc[uu][nt][r] = p[nt] * inv;
    }
#pragma unroll
    for (int nt = 0; nt < 4; ++nt) {
      int ktok = nt * 16 + lcol;
      int ktile = ktok >> 5, lhi = (ktok & 31) >> 3;
#pragma unroll
      for (int r = 0; r < 4; ++r) {
        int mm = lrow * 4 + r;
        sm1[(((head * 4 + mtq) * 2 + ktile) * 64 + mm + (lhi << 4)) * 8 + (ktok & 7)] = f2bf(sc[uu][nt][r]);
      }
    }
  }
  __syncthreads();

  // ---- phase 4: PV, write y to A-swz LDS (reuse sm0; head = k-tile)
#pragma unroll
  for (int uu = 0; uu < 3; ++uu) {
    int u = w * 3 + uu, head = u >> 2, mtq = u & 3;
#pragma unroll
    for (int nt2 = 0; nt2 < 2; ++nt2) {
      f32x4 acc = {0.f, 0.f, 0.f, 0.f};
#pragma unroll
      for (int ktile = 0; ktile < 2; ++ktile) {
        bf16x8 ap = *(const bf16x8*)(sm1 + (((head * 4 + mtq) * 2 + ktile) * 64 + lane) * 8);
        bf16x8 bv8 = *(const bf16x8*)(sm2 + (((head * 2 + ktile) * 2 + nt2) * 64 + lane) * 8);
        acc = MFMA(ap, bv8, acc);
      }
      int d0 = nt2 * 16 + lcol;
#pragma unroll
      for (int r = 0; r < 4; ++r) {
        int mm = lrow * 4 + r;
        sm0[((mtq * 3 + head) * 64 + mm + ((d0 >> 3) << 4)) * 8 + (d0 & 7)] = f2bf(acc[r]);
      }
    }
  }
  __syncthreads();

  // ---- phase 5: proj + bias + residual -> x2
  bf16x8 ay[3];
#pragma unroll
  for (int kt = 0; kt < 3; ++kt) ay[kt] = *(const bf16x8*)(sm0 + ((w * 3 + kt) * 64 + lane) * 8);
#pragma unroll
  for (int nt = 0; nt < 6; ++nt) {
    f32x4 acc = {0.f, 0.f, 0.f, 0.f};
#pragma unroll
    for (int kt = 0; kt < 3; ++kt) acc = MFMA(ay[kt], ldw(wswz, WP_T + kt * 6 + nt, lane), acc);
    int c = nt * 16 + lcol;
    float bpc = bp[c];
#pragma unroll
    for (int r = 0; r < 4; ++r) x2[rowoff[r] + c] = acc[r] + bpc + xv[r][nt];
  }
}

// --------------------------- LN2 + FC1 + GELU ------------------------------
__global__ __launch_bounds__(256) void kleff1(
    const float* __restrict__ x2, const float* __restrict__ g2, const float* __restrict__ b2,
    const float* __restrict__ bl1, const unsigned short* __restrict__ wswz,
    unsigned short* __restrict__ h1) {
  __shared__ __align__(16) unsigned short sm0[4 * 3 * 64 * 8];   // 12.3KB
  __shared__ __align__(16) unsigned short trbuf[64 * 200];       // 25.6KB (192ch half, +8 pad)
  const int tid = threadIdx.x, lane = tid & 63, w = tid >> 6;
  const int lrow = lane >> 4, lcol = lane & 15;
  const long tbase = (long)xcd_swz(blockIdx.x) * 64;

  float xv[4][6], gv[6], bv[6];
#pragma unroll
  for (int nt = 0; nt < 6; ++nt) {
    int c = nt * 16 + lcol;
    gv[nt] = g2[c]; bv[nt] = b2[c];
#pragma unroll
    for (int r = 0; r < 4; ++r) xv[r][nt] = x2[(tbase + w * 16 + lrow * 4 + r) * 96 + c];
  }
#pragma unroll
  for (int r = 0; r < 4; ++r) {
    float s = 0.f, sq = 0.f;
#pragma unroll
    for (int nt = 0; nt < 6; ++nt) { float v = xv[r][nt]; s += v; sq += v * v; }
#pragma unroll
    for (int off = 1; off <= 8; off <<= 1) { s += __shfl_xor(s, off, 64); sq += __shfl_xor(sq, off, 64); }
    float mean = s * (1.f / 96.f);
    float var = sq * (1.f / 96.f) - mean * mean;
    float rs = rsqrtf(var + 1e-5f);
#pragma unroll
    for (int nt = 0; nt < 6; ++nt) xv[r][nt] = (xv[r][nt] - mean) * rs * gv[nt] + bv[nt];
  }
#pragma unroll
  for (int r = 0; r < 4; ++r) {
    int mm = lrow * 4 + r;
#pragma unroll
    for (int nt = 0; nt < 6; ++nt) {
      int c = nt * 16 + lcol;
      int kt = c >> 5;
      int lanew = mm + (((c & 31) >> 3) << 4);
      sm0[((w * 3 + kt) * 64 + lanew) * 8 + (c & 7)] = f2bf(xv[r][nt]);
    }
  }
  __syncthreads();

  bf16x8 af[3];
#pragma unroll
  for (int kt = 0; kt < 3; ++kt) af[kt] = *(const bf16x8*)(sm0 + ((w * 3 + kt) * 64 + lane) * 8);

  for (int half = 0; half < 2; ++half) {
#pragma unroll
    for (int nt2 = 0; nt2 < 12; ++nt2) {
      int nt = half * 12 + nt2;
      f32x4 acc = {0.f, 0.f, 0.f, 0.f};
#pragma unroll
      for (int kt = 0; kt < 3; ++kt) acc = MFMA(af[kt], ldw(wswz, W1_T + kt * 24 + nt, lane), acc);
      int cl = nt2 * 16 + lcol;                 // 0..191 within half
      float bb = bl1[half * 192 + cl];
#pragma unroll
      for (int r = 0; r < 4; ++r) {
        int m = w * 16 + lrow * 4 + r;
        trbuf[m * 200 + cl] = f2bf(gelu(acc[r] + bb));
      }
    }
    __syncthreads();
    // coalesced writeout: 1536 x 16B chunks
#pragma unroll
    for (int j = 0; j < 6; ++j) {
      int idx = tid + j * 256;
      int token = idx / 24, c0 = (idx % 24) * 8;
      uint4 v = *(const uint4*)(trbuf + token * 200 + c0);
      *(uint4*)(h1 + (tbase + token) * 384 + half * 192 + c0) = v;
    }
    __syncthreads();
  }
}

// --------------- depthwise 3x3 + GELU + FC2 + residual ---------------------
// conv computed per-lane directly into the consuming lane's A-fragment:
// lane l of wave w owns pixel w*16+(l&15), channels kt*32+(l>>4)*8 .. +7.
// Inline-asm load pipeline: D(k+2) and W(k+2) issued at end of phase k,
// vmcnt(15)+sched_barrier at each phase head. Invalid halo taps point at a
// zeroed 4KB page so all loads are unconditional (zero-padding for free).
__device__ __forceinline__ bf16x8 dwconv_gelu(const uint4* cur,
    const float* wsh, const float* wb, int ch) {
  f32x2 a2[4];
#pragma unroll
  for (int j = 0; j < 4; ++j) a2[j] = (f32x2){0.f, 0.f};
#pragma unroll
  for (int t = 0; t < 9; ++t) {
    f32x4 wlo = *(const f32x4*)(wsh + t * 384 + ch);
    f32x4 whi = *(const f32x4*)(wsh + t * 384 + ch + 4);
    const unsigned* du = (const unsigned*)(cur + t);
    f32x2 d0 = { asf(du[0] << 16), asf(du[0] & 0xffff0000u) };
    f32x2 d1 = { asf(du[1] << 16), asf(du[1] & 0xffff0000u) };
    f32x2 d2 = { asf(du[2] << 16), asf(du[2] & 0xffff0000u) };
    f32x2 d3 = { asf(du[3] << 16), asf(du[3] & 0xffff0000u) };
    f32x2 w0 = {wlo.x, wlo.y}, w1 = {wlo.z, wlo.w};
    f32x2 w2v = {whi.x, whi.y}, w3 = {whi.z, whi.w};
    a2[0] += d0 * w0; a2[1] += d1 * w1; a2[2] += d2 * w2v; a2[3] += d3 * w3;
  }
  f32x4 blo = *(const f32x4*)(wb + ch);
  f32x4 bhi = *(const f32x4*)(wb + ch + 4);
  union { unsigned u[4]; bf16x8 v; } pk;
  pk.u[0] = cvtpk_bf16(gelu(a2[0].x + blo.x), gelu(a2[0].y + blo.y));
  pk.u[1] = cvtpk_bf16(gelu(a2[1].x + blo.z), gelu(a2[1].y + blo.w));
  pk.u[2] = cvtpk_bf16(gelu(a2[2].x + bhi.x), gelu(a2[2].y + bhi.y));
  pk.u[3] = cvtpk_bf16(gelu(a2[3].x + bhi.z), gelu(a2[3].y + bhi.w));
  return pk.v;
}

// pinned 16B load the scheduler cannot sink
#define GLD16(dst, ptr, off)                                        \
  asm volatile("global_load_dwordx4 %0, %1, off offset:%c2"         \
               : "=v"(dst) : "v"(ptr), "i"(off))

// issue conv-data loads for k-tile kt into dD[s] (9 loads)
#define LOAD_D(s, kt)                                               \
  { _Pragma("unroll") for (int t = 0; t < 9; ++t)                   \
      GLD16(dD[s][t], p9[t], (kt) * 64); }

// issue W2 B-frag loads for next k-tile into dW[s] (6 loads); bump pointers
#define LOAD_W(s)                                                   \
  { GLD16(dW[s][0], wp0, 0);    GLD16(dW[s][1], wp0, 1024);         \
    GLD16(dW[s][2], wp0, 2048); GLD16(dW[s][3], wp0, 3072);         \
    GLD16(dW[s][4], wp4, 0);    GLD16(dW[s][5], wp4, 1024);         \
    wp0 += 6144; wp4 += 6144; }

#define VMWAIT(n)                                                   \
  { asm volatile("s_waitcnt vmcnt(" #n ")" ::: "memory");           \
    __builtin_amdgcn_sched_barrier(0); }

#define PHASE_COMPUTE(s, kt)                                        \
  { bf16x8 pa = dwconv_gelu(dD[s], wsh, wb, (kt) * 32 + cg0);       \
    _Pragma("unroll") for (int nt = 0; nt < 6; ++nt)                \
      acc[nt] = MFMA(pa, dW[s][nt], acc[nt]); }

__global__ __launch_bounds__(256, 2) void kleff2(
    const unsigned short* __restrict__ h1, const float* __restrict__ wdwT,
    const float* __restrict__ bdw, const float* __restrict__ bl2,
    const unsigned short* __restrict__ wswz, const float* __restrict__ x2,
    const char* __restrict__ zp, float* __restrict__ out) {
  __shared__ __align__(16) float wsh[9 * 384 + 384];   // 15.4KB: taps f32 + bias f32
  const int tid = threadIdx.x, lane = tid & 63, w = tid >> 6;
  const int lrow = lane >> 4, lcol = lane & 15;
  const int bid = xcd_swz(blockIdx.x);
  const int b = bid >> 10, ty0 = ((bid >> 5) & 31) * 8, tx0 = (bid & 31) * 8;

  // stage dw weights + bias once (960 float4)
  for (int i = tid; i < 960; i += 256) {
    float4 v = (i < 864) ? ((const float4*)wdwT)[i] : ((const float4*)bdw)[i - 864];
    ((float4*)wsh)[i] = v;
  }
  const float* wb = wsh + 3456;

  const int px = w * 16 + lcol;              // this lane's pixel 0..63
  const int gy = ty0 + (px >> 3), gx = tx0 + (px & 7);
  const int cg0 = lrow * 8;                  // channel sub-offset in k-tile

  // 9 per-tap pointers; out-of-image taps -> zeropage (reads return 0)
  const unsigned short* p9[9];
#pragma unroll
  for (int dy = 0; dy < 3; ++dy)
#pragma unroll
    for (int dx = 0; dx < 3; ++dx) {
      int yy = gy + dy - 1, xx = gx + dx - 1;
      bool ok = ((unsigned)yy < 256u) && ((unsigned)xx < 256u);
      const unsigned short* p =
          h1 + (((long)b * 65536 + (long)yy * 256 + xx) * 384 + cg0);
      p9[dy * 3 + dx] = ok ? p : (const unsigned short*)zp;
    }

  const char* wp0 = (const char*)wswz + W2_T * 1024 + lane * 16;
  const char* wp4 = wp0 + 4096;

  f32x4 acc[6];
#pragma unroll
  for (int nt = 0; nt < 6; ++nt) { f32x4 z = {0.f, 0.f, 0.f, 0.f}; acc[nt] = z; }

  __syncthreads();

  uint4 dD[2][9]; bf16x8 dW[2][6];
  // prologue: kt=0 and kt=1 in flight (30 loads)
  LOAD_W(0) LOAD_D(0, 0)
  LOAD_W(1) LOAD_D(1, 1)
  // steady state: wait for kt k (leave k+1 in flight), compute k, issue k+2
  VMWAIT(15) PHASE_COMPUTE(0, 0)  LOAD_W(0) LOAD_D(0, 2)
  VMWAIT(15) PHASE_COMPUTE(1, 1)  LOAD_W(1) LOAD_D(1, 3)
  VMWAIT(15) PHASE_COMPUTE(0, 2)  LOAD_W(0) LOAD_D(0, 4)
  VMWAIT(15) PHASE_COMPUTE(1, 3)  LOAD_W(1) LOAD_D(1, 5)
  VMWAIT(15) PHASE_COMPUTE(0, 4)  LOAD_W(0) LOAD_D(0, 6)
  VMWAIT(15) PHASE_COMPUTE(1, 5)  LOAD_W(1) LOAD_D(1, 7)
  VMWAIT(15) PHASE_COMPUTE(0, 6)  LOAD_W(0) LOAD_D(0, 8)
  VMWAIT(15) PHASE_COMPUTE(1, 7)  LOAD_W(1) LOAD_D(1, 9)
  VMWAIT(15) PHASE_COMPUTE(0, 8)  LOAD_W(0) LOAD_D(0, 10)
  VMWAIT(15) PHASE_COMPUTE(1, 9)  LOAD_W(1) LOAD_D(1, 11)
  VMWAIT(15) PHASE_COMPUTE(0, 10)
  VMWAIT(0)  PHASE_COMPUTE(1, 11)

  // ---- epilogue: + bl2 + residual(x2) -> out
#pragma unroll
  for (int nt = 0; nt < 6; ++nt) {
    int c = nt * 16 + lcol;
    float bb = bl2[c];
#pragma unroll
    for (int r = 0; r < 4; ++r) {
      int mm = w * 16 + lrow * 4 + r;
      int oy = ty0 + (mm >> 3), ox = tx0 + (mm & 7);
      long row = (long)b * 65536 + oy * 256 + ox;
      out[row * 96 + c] = acc[nt][r] + bb + x2[row * 96 + c];
    }
  }
}

// ---------------------------------------------------------------------------
extern "C" void kernel_launch(void* const* d_in, const int* in_sizes, int n_in,
                              void* d_out, int out_size, void* d_ws, size_t ws_size,
                              hipStream_t stream) {
  const float* x   = (const float*)d_in[0];
  const float* g1  = (const float*)d_in[1];
  const float* b1  = (const float*)d_in[2];
  const float* wq  = (const float*)d_in[3];
  const float* bq  = (const float*)d_in[4];
  const float* wkv = (const float*)d_in[5];
  const float* bkv = (const float*)d_in[6];
  const float* rpb = (const float*)d_in[7];
  const float* wp  = (const float*)d_in[8];
  const float* bp  = (const float*)d_in[9];
  const float* g2  = (const float*)d_in[10];
  const float* b2  = (const float*)d_in[11];
  const float* w1  = (const float*)d_in[12];
  const float* bl1 = (const float*)d_in[13];
  const float* wdw = (const float*)d_in[14];
  const float* bdw = (const float*)d_in[15];
  const float* w2  = (const float*)d_in[16];
  const float* bl2 = (const float*)d_in[17];

  char* ws = (char*)d_ws;
  unsigned short* wswz = (unsigned short*)ws;                      // 221 KB
  float* wdwT = (float*)(ws + (size_t)(256 << 10));                // 13.8 KB @256KB
  char* zp = ws + (size_t)(2 << 20);                               // 4 KB zeropage @2MB
  float* x2 = (float*)(ws + (size_t)(4 << 20));                    // 100.7 MB
  unsigned short* h1 = (unsigned short*)(ws + (size_t)(4 << 20) + 100663296); // 201.3 MB
  float* outp = (float*)d_out;

  hipMemsetAsync(zp, 0, 4096, stream);
  kwconv<<<68, 256, 0, stream>>>(wq, wkv, wp, w1, w2, wdw, wswz, wdwT);
  kattn<<<4096, 256, 0, stream>>>(x, g1, b1, bq, bkv, rpb, bp, wswz, x2);
  kleff1<<<4096, 256, 0, stream>>>(x2, g2, b2, bl1, wswz, h1);
  kleff2<<<4096, 256, 0, stream>>>(h1, wdwT, bdw, bl2, wswz, x2, zp, outp);
}

// Round 7
// 574.536 us; speedup vs baseline: 1.1418x; 1.0027x over previous
//
#include <hip/hip_runtime.h>
#include <math.h>

// ---------------------------------------------------------------------------
// Swin/Uformer block, MI355X. Sizes fixed: B=4 H=W=256 C=96 NH=3 HD=32 WIN=8
// N=64 HID=384. 4 kernels:
//   kwconv : f32 weights -> bf16 pre-swizzled B-frags; + wdw transposed f32
//   kattn  : LN1 + QKV + window-attn (+rpb bias, softmax) + proj + residual
//   kleff1 : LN2 + FC1 + GELU -> h1 (bf16), stores transposed through LDS
//   kleff2 : depthwise 3x3 + GELU + FC2 + residual; per-lane conv into MFMA
//            A-frags; inline-asm load pipeline (counted vmcnt), zeropage halo
// MFMA 16x16x32 bf16 layouts used throughout:
//   A-frag: lane = (m%16) + 16*(k%32/8), elem = k%8
//   B-frag: lane = (n%16) + 16*(k%32/8), elem = k%8
//   C/D   : row  = 4*(lane/16)+reg, col = lane%16
// ---------------------------------------------------------------------------

typedef __attribute__((ext_vector_type(8))) short bf16x8;
typedef __attribute__((ext_vector_type(4))) float f32x4;
typedef __attribute__((ext_vector_type(2))) float f32x2;

#define MFMA(a, b, c) __builtin_amdgcn_mfma_f32_16x16x32_bf16((a), (b), (c), 0, 0, 0)

// weight tile bases (in 16x32 B-fragment tiles of 64 lanes * 16B)
#define WQ_T 0
#define WKV_T 18
#define WP_T 54
#define W1_T 72
#define W2_T 144
#define NTILES_TOT 216

__device__ __forceinline__ unsigned short f2bf(float f) {
  union { float f; unsigned u; } v; v.f = f;
  unsigned r = v.u + 0x7FFFu + ((v.u >> 16) & 1u);
  return (unsigned short)(r >> 16);
}
__device__ __forceinline__ float asf(unsigned u) {
  union { unsigned u; float f; } v; v.u = u; return v.f;
}
__device__ __forceinline__ unsigned cvtpk_bf16(float lo, float hi) {
  unsigned r;
  asm("v_cvt_pk_bf16_f32 %0, %1, %2" : "=v"(r) : "v"(lo), "v"(hi));
  return r;
}
// gelu(x) = x * sigmoid(2z), z = 0.7978845608 x (1 + 0.044715 x^2)
__device__ __forceinline__ float gelu(float x) {
  float t = x * x;
  float w = x * fmaf(t, -0.07135941f, -1.5957691f);   // -2z
  float a = __expf(w);
  return x * __builtin_amdgcn_rcpf(1.f + a);
}
__device__ __forceinline__ bf16x8 ldw(const unsigned short* wswz, int tile, int lane) {
  return *(const bf16x8*)(wswz + ((size_t)(tile * 64 + lane)) * 8);
}
__device__ __forceinline__ int xcd_swz(int bid) {   // 4096 % 8 == 0 -> bijective
  return (bid & 7) * 512 + (bid >> 3);
}

// --------------------------- weight convert/swizzle ------------------------
__global__ void kwconv(const float* __restrict__ wq, const float* __restrict__ wkv,
                       const float* __restrict__ wp, const float* __restrict__ w1,
                       const float* __restrict__ w2, const float* __restrict__ wdw,
                       unsigned short* __restrict__ wswz, float* __restrict__ wdwT) {
  int tid = blockIdx.x * 256 + threadIdx.x;
  if (tid >= NTILES_TOT * 64) {
    int i = tid - NTILES_TOT * 64;
    if (i < 3456) {                       // wdw (384,1,3,3) -> wdwT [tap][384]
      int ch = i % 384, tap = i / 384;
      wdwT[tap * 384 + ch] = wdw[ch * 9 + tap];
    }
    return;
  }
  int e = tid; const float* src; int N, NT;
  if (e < 1152)      { src = wq;  N = 96;  NT = 6; }
  else if (e < 3456) { src = wkv; N = 192; NT = 12; e -= 1152; }
  else if (e < 4608) { src = wp;  N = 96;  NT = 6;  e -= 3456; }
  else if (e < 9216) { src = w1;  N = 384; NT = 24; e -= 4608; }
  else               { src = w2;  N = 96;  NT = 6;  e -= 9216; }
  int lane = e & 63, t = e >> 6;
  int nt = t % NT, kt = t / NT;
  int k0 = kt * 32 + (lane >> 4) * 8;
  int n = nt * 16 + (lane & 15);
  unsigned short* dst = wswz + (size_t)tid * 8;
#pragma unroll
  for (int i = 0; i < 8; ++i) dst[i] = f2bf(src[(size_t)(k0 + i) * N + n]);
}

// --------------------------- attention block -------------------------------
__global__ __launch_bounds__(256) void kattn(
    const float* __restrict__ x, const float* __restrict__ g1, const float* __restrict__ b1,
    const float* __restrict__ bq, const float* __restrict__ bkv,
    const float* __restrict__ rpb, const float* __restrict__ bp,
    const unsigned short* __restrict__ wswz, float* __restrict__ x2) {
  __shared__ __align__(16) unsigned short sm0[4 * 3 * 64 * 8];   // xn_swz, later y_swz (12KB)
  __shared__ __align__(16) unsigned short sm1[24 * 64 * 8];      // q(12 tiles)+k(12) then p(24) (24KB)
  __shared__ __align__(16) unsigned short sm2[3 * 2 * 2 * 64 * 8]; // v (12KB)

  const int tid = threadIdx.x;
  const int lane = tid & 63, w = tid >> 6;
  const int lrow = lane >> 4, lcol = lane & 15;
  const int wi = xcd_swz(blockIdx.x);
  const int b = wi >> 10, wy = (wi >> 5) & 31, wx = wi & 31;

  long rowoff[4];
#pragma unroll
  for (int r = 0; r < 4; ++r) {
    int m = w * 16 + lrow * 4 + r;
    int gy = wy * 8 + (m >> 3), gx = wx * 8 + (m & 7);
    rowoff[r] = ((long)b * 65536 + gy * 256 + gx) * 96;
  }

  // ---- phase 0: load x (C/D-layout regs), LN1, write xn to A-swz LDS
  float xv[4][6], xn[4][6], gv[6], bv[6];
#pragma unroll
  for (int nt = 0; nt < 6; ++nt) {
    int c = nt * 16 + lcol;
    gv[nt] = g1[c]; bv[nt] = b1[c];
#pragma unroll
    for (int r = 0; r < 4; ++r) xv[r][nt] = x[rowoff[r] + c];
  }
#pragma unroll
  for (int r = 0; r < 4; ++r) {
    float s = 0.f, sq = 0.f;
#pragma unroll
    for (int nt = 0; nt < 6; ++nt) { float v = xv[r][nt]; s += v; sq += v * v; }
#pragma unroll
    for (int off = 1; off <= 8; off <<= 1) { s += __shfl_xor(s, off, 64); sq += __shfl_xor(sq, off, 64); }
    float mean = s * (1.f / 96.f);
    float var = sq * (1.f / 96.f) - mean * mean;
    float rs = rsqrtf(var + 1e-5f);
#pragma unroll
    for (int nt = 0; nt < 6; ++nt) xn[r][nt] = (xv[r][nt] - mean) * rs * gv[nt] + bv[nt];
  }
#pragma unroll
  for (int r = 0; r < 4; ++r) {
    int mm = lrow * 4 + r;
#pragma unroll
    for (int nt = 0; nt < 6; ++nt) {
      int c = nt * 16 + lcol;
      int kt = c >> 5;
      int lanew = mm + (((c & 31) >> 3) << 4);
      sm0[((w * 3 + kt) * 64 + lanew) * 8 + (c & 7)] = f2bf(xn[r][nt]);
    }
  }
  __syncthreads();

  // ---- phase 1: QKV GEMM (M=64 N=288 K=96), wave w owns m-tile w
  bf16x8 af[3];
#pragma unroll
  for (int kt = 0; kt < 3; ++kt) af[kt] = *(const bf16x8*)(sm0 + ((w * 3 + kt) * 64 + lane) * 8);
  for (int nt = 0; nt < 18; ++nt) {
    f32x4 acc = {0.f, 0.f, 0.f, 0.f};
#pragma unroll
    for (int kt = 0; kt < 3; ++kt) {
      int tile = (nt < 6) ? (WQ_T + kt * 6 + nt) : (WKV_T + kt * 12 + (nt - 6));
      acc = MFMA(af[kt], ldw(wswz, tile, lane), acc);
    }
    int c = nt * 16 + lcol;
#pragma unroll
    for (int r = 0; r < 4; ++r) {
      int m = w * 16 + lrow * 4 + r;
      float val = acc[r];
      if (c < 96) {                 // q (pre-scaled)
        val = (val + bq[c]) * 0.17677669529663687f;
        int head = c >> 5, d = c & 31;
        sm1[((head * 4 + w) * 64 + (m & 15) + ((d >> 3) << 4)) * 8 + (d & 7)] = f2bf(val);
      } else if (c < 192) {         // k
        int kc = c - 96;
        val += bkv[kc];
        int head = kc >> 5, d = kc & 31;
        sm1[((12 + head * 4 + w) * 64 + (m & 15) + ((d >> 3) << 4)) * 8 + (d & 7)] = f2bf(val);
      } else {                      // v (B-frag layout: k-dim = key token)
        int vc = c - 192;
        val += bkv[96 + vc];
        int head = vc >> 5, d = vc & 31;
        int ktile = m >> 5, nt2 = d >> 4;
        sm2[(((head * 2 + ktile) * 2 + nt2) * 64 + (d & 15) + (((m & 31) >> 3) << 4)) * 8 + (m & 7)] = f2bf(val);
      }
    }
  }
  __syncthreads();

  // ---- phase 2: scores. unit u=(head,mtq); wave w owns u = 3w..3w+2
  f32x4 sc[3][4];
#pragma unroll
  for (int uu = 0; uu < 3; ++uu) {
    int u = w * 3 + uu, head = u >> 2, mtq = u & 3;
    bf16x8 aq = *(const bf16x8*)(sm1 + ((head * 4 + mtq) * 64 + lane) * 8);
#pragma unroll
    for (int nt = 0; nt < 4; ++nt) {
      bf16x8 bk = *(const bf16x8*)(sm1 + ((12 + head * 4 + nt) * 64 + lane) * 8);
      f32x4 z = {0.f, 0.f, 0.f, 0.f};
      sc[uu][nt] = MFMA(aq, bk, z);
    }
  }
  __syncthreads();   // all q/k reads done; sm1 may now be overwritten with P

  // ---- phase 3: +rpb bias, softmax (in-register), write P to A-swz LDS
#pragma unroll
  for (int uu = 0; uu < 3; ++uu) {
    int u = w * 3 + uu, head = u >> 2, mtq = u & 3;
#pragma unroll
    for (int nt = 0; nt < 4; ++nt) {
      int ktok = nt * 16 + lcol;
#pragma unroll
      for (int r = 0; r < 4; ++r) {
        int qtok = mtq * 16 + lrow * 4 + r;
        int dy = (qtok >> 3) - (ktok >> 3) + 7;
        int dx = (qtok & 7) - (ktok & 7) + 7;
        sc[uu][nt][r] += rpb[(dy * 15 + dx) * 3 + head];
      }
    }
#pragma unroll
    for (int r = 0; r < 4; ++r) {
      float mx = fmaxf(fmaxf(sc[uu][0][r], sc[uu][1][r]), fmaxf(sc[uu][2][r], sc[uu][3][r]));
#pragma unroll
      for (int off = 1; off <= 8; off <<= 1) mx = fmaxf(mx, __shfl_xor(mx, off, 64));
      float p[4], sum = 0.f;
#pragma unroll
      for (int nt = 0; nt < 4; ++nt) { p[nt] = __expf(sc[uu][nt][r] - mx); sum += p[nt]; }
#pragma unroll
      for (int off = 1; off <= 8; off <<= 1) sum += __shfl_xor(sum, off, 64);
      float inv = 1.f / sum;
#pragma unroll
      for (int nt = 0; nt < 4; ++nt) sc[uu][nt][r] = p[nt] * inv;
    }
#pragma unroll
    for (int nt = 0; nt < 4; ++nt) {
      int ktok = nt * 16 + lcol;
      int ktile = ktok >> 5, lhi = (ktok & 31) >> 3;
#pragma unroll
      for (int r = 0; r < 4; ++r) {
        int mm = lrow * 4 + r;
        sm1[(((head * 4 + mtq) * 2 + ktile) * 64 + mm + (lhi << 4)) * 8 + (ktok & 7)] = f2bf(sc[uu][nt][r]);
      }
    }
  }
  __syncthreads();

  // ---- phase 4: PV, write y to A-swz LDS (reuse sm0; head = k-tile)
#pragma unroll
  for (int uu = 0; uu < 3; ++uu) {
    int u = w * 3 + uu, head = u >> 2, mtq = u & 3;
#pragma unroll
    for (int nt2 = 0; nt2 < 2; ++nt2) {
      f32x4 acc = {0.f, 0.f, 0.f, 0.f};
#pragma unroll
      for (int ktile = 0; ktile < 2; ++ktile) {
        bf16x8 ap = *(const bf16x8*)(sm1 + (((head * 4 + mtq) * 2 + ktile) * 64 + lane) * 8);
        bf16x8 bv8 = *(const bf16x8*)(sm2 + (((head * 2 + ktile) * 2 + nt2) * 64 + lane) * 8);
        acc = MFMA(ap, bv8, acc);
      }
      int d0 = nt2 * 16 + lcol;
#pragma unroll
      for (int r = 0; r < 4; ++r) {
        int mm = lrow * 4 + r;
        sm0[((mtq * 3 + head) * 64 + mm + ((d0 >> 3) << 4)) * 8 + (d0 & 7)] = f2bf(acc[r]);
      }
    }
  }
  __syncthreads();

  // ---- phase 5: proj + bias + residual -> x2
  bf16x8 ay[3];
#pragma unroll
  for (int kt = 0; kt < 3; ++kt) ay[kt] = *(const bf16x8*)(sm0 + ((w * 3 + kt) * 64 + lane) * 8);
#pragma unroll
  for (int nt = 0; nt < 6; ++nt) {
    f32x4 acc = {0.f, 0.f, 0.f, 0.f};
#pragma unroll
    for (int kt = 0; kt < 3; ++kt) acc = MFMA(ay[kt], ldw(wswz, WP_T + kt * 6 + nt, lane), acc);
    int c = nt * 16 + lcol;
    float bpc = bp[c];
#pragma unroll
    for (int r = 0; r < 4; ++r) x2[rowoff[r] + c] = acc[r] + bpc + xv[r][nt];
  }
}

// --------------------------- LN2 + FC1 + GELU ------------------------------
__global__ __launch_bounds__(256) void kleff1(
    const float* __restrict__ x2, const float* __restrict__ g2, const float* __restrict__ b2,
    const float* __restrict__ bl1, const unsigned short* __restrict__ wswz,
    unsigned short* __restrict__ h1) {
  __shared__ __align__(16) unsigned short sm0[4 * 3 * 64 * 8];   // 12.3KB
  __shared__ __align__(16) unsigned short trbuf[64 * 200];       // 25.6KB (192ch half, +8 pad)
  const int tid = threadIdx.x, lane = tid & 63, w = tid >> 6;
  const int lrow = lane >> 4, lcol = lane & 15;
  const long tbase = (long)xcd_swz(blockIdx.x) * 64;

  float xv[4][6], gv[6], bv[6];
#pragma unroll
  for (int nt = 0; nt < 6; ++nt) {
    int c = nt * 16 + lcol;
    gv[nt] = g2[c]; bv[nt] = b2[c];
#pragma unroll
    for (int r = 0; r < 4; ++r) xv[r][nt] = x2[(tbase + w * 16 + lrow * 4 + r) * 96 + c];
  }
#pragma unroll
  for (int r = 0; r < 4; ++r) {
    float s = 0.f, sq = 0.f;
#pragma unroll
    for (int nt = 0; nt < 6; ++nt) { float v = xv[r][nt]; s += v; sq += v * v; }
#pragma unroll
    for (int off = 1; off <= 8; off <<= 1) { s += __shfl_xor(s, off, 64); sq += __shfl_xor(sq, off, 64); }
    float mean = s * (1.f / 96.f);
    float var = sq * (1.f / 96.f) - mean * mean;
    float rs = rsqrtf(var + 1e-5f);
#pragma unroll
    for (int nt = 0; nt < 6; ++nt) xv[r][nt] = (xv[r][nt] - mean) * rs * gv[nt] + bv[nt];
  }
#pragma unroll
  for (int r = 0; r < 4; ++r) {
    int mm = lrow * 4 + r;
#pragma unroll
    for (int nt = 0; nt < 6; ++nt) {
      int c = nt * 16 + lcol;
      int kt = c >> 5;
      int lanew = mm + (((c & 31) >> 3) << 4);
      sm0[((w * 3 + kt) * 64 + lanew) * 8 + (c & 7)] = f2bf(xv[r][nt]);
    }
  }
  __syncthreads();

  bf16x8 af[3];
#pragma unroll
  for (int kt = 0; kt < 3; ++kt) af[kt] = *(const bf16x8*)(sm0 + ((w * 3 + kt) * 64 + lane) * 8);

  for (int half = 0; half < 2; ++half) {
#pragma unroll
    for (int nt2 = 0; nt2 < 12; ++nt2) {
      int nt = half * 12 + nt2;
      f32x4 acc = {0.f, 0.f, 0.f, 0.f};
#pragma unroll
      for (int kt = 0; kt < 3; ++kt) acc = MFMA(af[kt], ldw(wswz, W1_T + kt * 24 + nt, lane), acc);
      int cl = nt2 * 16 + lcol;                 // 0..191 within half
      float bb = bl1[half * 192 + cl];
#pragma unroll
      for (int r = 0; r < 4; ++r) {
        int m = w * 16 + lrow * 4 + r;
        trbuf[m * 200 + cl] = f2bf(gelu(acc[r] + bb));
      }
    }
    __syncthreads();
    // coalesced writeout: 1536 x 16B chunks
#pragma unroll
    for (int j = 0; j < 6; ++j) {
      int idx = tid + j * 256;
      int token = idx / 24, c0 = (idx % 24) * 8;
      uint4 v = *(const uint4*)(trbuf + token * 200 + c0);
      *(uint4*)(h1 + (tbase + token) * 384 + half * 192 + c0) = v;
    }
    __syncthreads();
  }
}

// --------------- depthwise 3x3 + GELU + FC2 + residual ---------------------
// conv computed per-lane directly into the consuming lane's A-fragment:
// lane l of wave w owns pixel w*16+(l&15), channels kt*32+(l>>4)*8 .. +7.
// Inline-asm load pipeline: D(k+2) and W(k+2) issued at end of phase k,
// vmcnt(15)+sched_barrier at each phase head. Invalid halo taps point at a
// zeroed 4KB page so all loads are unconditional (zero-padding for free).
__device__ __forceinline__ bf16x8 dwconv_gelu(const uint4* cur,
    const float* wsh, const float* wb, int ch) {
  f32x2 a2[4];
#pragma unroll
  for (int j = 0; j < 4; ++j) a2[j] = (f32x2){0.f, 0.f};
#pragma unroll
  for (int t = 0; t < 9; ++t) {
    f32x4 wlo = *(const f32x4*)(wsh + t * 384 + ch);
    f32x4 whi = *(const f32x4*)(wsh + t * 384 + ch + 4);
    const unsigned* du = (const unsigned*)(cur + t);
    f32x2 d0 = { asf(du[0] << 16), asf(du[0] & 0xffff0000u) };
    f32x2 d1 = { asf(du[1] << 16), asf(du[1] & 0xffff0000u) };
    f32x2 d2 = { asf(du[2] << 16), asf(du[2] & 0xffff0000u) };
    f32x2 d3 = { asf(du[3] << 16), asf(du[3] & 0xffff0000u) };
    f32x2 w0 = {wlo.x, wlo.y}, w1 = {wlo.z, wlo.w};
    f32x2 w2v = {whi.x, whi.y}, w3 = {whi.z, whi.w};
    a2[0] += d0 * w0; a2[1] += d1 * w1; a2[2] += d2 * w2v; a2[3] += d3 * w3;
  }
  f32x4 blo = *(const f32x4*)(wb + ch);
  f32x4 bhi = *(const f32x4*)(wb + ch + 4);
  union { unsigned u[4]; bf16x8 v; } pk;
  pk.u[0] = cvtpk_bf16(gelu(a2[0].x + blo.x), gelu(a2[0].y + blo.y));
  pk.u[1] = cvtpk_bf16(gelu(a2[1].x + blo.z), gelu(a2[1].y + blo.w));
  pk.u[2] = cvtpk_bf16(gelu(a2[2].x + bhi.x), gelu(a2[2].y + bhi.y));
  pk.u[3] = cvtpk_bf16(gelu(a2[3].x + bhi.z), gelu(a2[3].y + bhi.w));
  return pk.v;
}

// pinned 16B load the scheduler cannot sink
#define GLD16(dst, ptr, off)                                        \
  asm volatile("global_load_dwordx4 %0, %1, off offset:%c2"         \
               : "=v"(dst) : "v"(ptr), "i"(off))

// issue conv-data loads for k-tile kt into dD[s] (9 loads)
#define LOAD_D(s, kt)                                               \
  { _Pragma("unroll") for (int t = 0; t < 9; ++t)                   \
      GLD16(dD[s][t], p9[t], (kt) * 64); }

// issue W2 B-frag loads for next k-tile into dW[s] (6 loads); bump pointers
#define LOAD_W(s)                                                   \
  { GLD16(dW[s][0], wp0, 0);    GLD16(dW[s][1], wp0, 1024);         \
    GLD16(dW[s][2], wp0, 2048); GLD16(dW[s][3], wp0, 3072);         \
    GLD16(dW[s][4], wp4, 0);    GLD16(dW[s][5], wp4, 1024);         \
    wp0 += 6144; wp4 += 6144; }

#define VMWAIT(n)                                                   \
  { asm volatile("s_waitcnt vmcnt(" #n ")" ::: "memory");           \
    __builtin_amdgcn_sched_barrier(0); }

#define PHASE_COMPUTE(s, kt)                                        \
  { bf16x8 pa = dwconv_gelu(dD[s], wsh, wb, (kt) * 32 + cg0);       \
    _Pragma("unroll") for (int nt = 0; nt < 6; ++nt)                \
      acc[nt] = MFMA(pa, dW[s][nt], acc[nt]); }

__global__ __launch_bounds__(256, 2) void kleff2(
    const unsigned short* __restrict__ h1, const float* __restrict__ wdwT,
    const float* __restrict__ bdw, const float* __restrict__ bl2,
    const unsigned short* __restrict__ wswz, const float* __restrict__ x2,
    const char* __restrict__ zp, float* __restrict__ out) {
  __shared__ __align__(16) float wsh[9 * 384 + 384];   // 15.4KB: taps f32 + bias f32
  const int tid = threadIdx.x, lane = tid & 63, w = tid >> 6;
  const int lrow = lane >> 4, lcol = lane & 15;
  const int bid = xcd_swz(blockIdx.x);
  const int b = bid >> 10, ty0 = ((bid >> 5) & 31) * 8, tx0 = (bid & 31) * 8;

  // stage dw weights + bias once (960 float4)
  for (int i = tid; i < 960; i += 256) {
    float4 v = (i < 864) ? ((const float4*)wdwT)[i] : ((const float4*)bdw)[i - 864];
    ((float4*)wsh)[i] = v;
  }
  const float* wb = wsh + 3456;

  const int px = w * 16 + lcol;              // this lane's pixel 0..63
  const int gy = ty0 + (px >> 3), gx = tx0 + (px & 7);
  const int cg0 = lrow * 8;                  // channel sub-offset in k-tile

  // 9 per-tap pointers; out-of-image taps -> zeropage (reads return 0)
  const unsigned short* p9[9];
#pragma unroll
  for (int dy = 0; dy < 3; ++dy)
#pragma unroll
    for (int dx = 0; dx < 3; ++dx) {
      int yy = gy + dy - 1, xx = gx + dx - 1;
      bool ok = ((unsigned)yy < 256u) && ((unsigned)xx < 256u);
      const unsigned short* p =
          h1 + (((long)b * 65536 + (long)yy * 256 + xx) * 384 + cg0);
      p9[dy * 3 + dx] = ok ? p : (const unsigned short*)zp;
    }

  const char* wp0 = (const char*)wswz + W2_T * 1024 + lane * 16;
  const char* wp4 = wp0 + 4096;

  f32x4 acc[6];
#pragma unroll
  for (int nt = 0; nt < 6; ++nt) { f32x4 z = {0.f, 0.f, 0.f, 0.f}; acc[nt] = z; }

  __syncthreads();

  uint4 dD[2][9]; bf16x8 dW[2][6];
  // prologue: kt=0 and kt=1 in flight (30 loads)
  LOAD_W(0) LOAD_D(0, 0)
  LOAD_W(1) LOAD_D(1, 1)
  // steady state: wait for kt k (leave k+1 in flight), compute k, issue k+2
  VMWAIT(15) PHASE_COMPUTE(0, 0)  LOAD_W(0) LOAD_D(0, 2)
  VMWAIT(15) PHASE_COMPUTE(1, 1)  LOAD_W(1) LOAD_D(1, 3)
  VMWAIT(15) PHASE_COMPUTE(0, 2)  LOAD_W(0) LOAD_D(0, 4)
  VMWAIT(15) PHASE_COMPUTE(1, 3)  LOAD_W(1) LOAD_D(1, 5)
  VMWAIT(15) PHASE_COMPUTE(0, 4)  LOAD_W(0) LOAD_D(0, 6)
  VMWAIT(15) PHASE_COMPUTE(1, 5)  LOAD_W(1) LOAD_D(1, 7)
  VMWAIT(15) PHASE_COMPUTE(0, 6)  LOAD_W(0) LOAD_D(0, 8)
  VMWAIT(15) PHASE_COMPUTE(1, 7)  LOAD_W(1) LOAD_D(1, 9)
  VMWAIT(15) PHASE_COMPUTE(0, 8)  LOAD_W(0) LOAD_D(0, 10)
  VMWAIT(15) PHASE_COMPUTE(1, 9)  LOAD_W(1) LOAD_D(1, 11)
  VMWAIT(15) PHASE_COMPUTE(0, 10)
  VMWAIT(0)  PHASE_COMPUTE(1, 11)

  // ---- epilogue: + bl2 + residual(x2) -> out
#pragma unroll
  for (int nt = 0; nt < 6; ++nt) {
    int c = nt * 16 + lcol;
    float bb = bl2[c];
#pragma unroll
    for (int r = 0; r < 4; ++r) {
      int mm = w * 16 + lrow * 4 + r;
      int oy = ty0 + (mm >> 3), ox = tx0 + (mm & 7);
      long row = (long)b * 65536 + oy * 256 + ox;
      out[row * 96 + c] = acc[nt][r] + bb + x2[row * 96 + c];
    }
  }
}

// ---------------------------------------------------------------------------
extern "C" void kernel_launch(void* const* d_in, const int* in_sizes, int n_in,
                              void* d_out, int out_size, void* d_ws, size_t ws_size,
                              hipStream_t stream) {
  const float* x   = (const float*)d_in[0];
  const float* g1  = (const float*)d_in[1];
  const float* b1  = (const float*)d_in[2];
  const float* wq  = (const float*)d_in[3];
  const float* bq  = (const float*)d_in[4];
  const float* wkv = (const float*)d_in[5];
  const float* bkv = (const float*)d_in[6];
  const float* rpb = (const float*)d_in[7];
  const float* wp  = (const float*)d_in[8];
  const float* bp  = (const float*)d_in[9];
  const float* g2  = (const float*)d_in[10];
  const float* b2  = (const float*)d_in[11];
  const float* w1  = (const float*)d_in[12];
  const float* bl1 = (const float*)d_in[13];
  const float* wdw = (const float*)d_in[14];
  const float* bdw = (const float*)d_in[15];
  const float* w2  = (const float*)d_in[16];
  const float* bl2 = (const float*)d_in[17];

  char* ws = (char*)d_ws;
  unsigned short* wswz = (unsigned short*)ws;                      // 221 KB
  float* wdwT = (float*)(ws + (size_t)(256 << 10));                // 13.8 KB @256KB
  char* zp = ws + (size_t)(2 << 20);                               // 4 KB zeropage @2MB
  float* x2 = (float*)(ws + (size_t)(4 << 20));                    // 100.7 MB
  unsigned short* h1 = (unsigned short*)(ws + (size_t)(4 << 20) + 100663296); // 201.3 MB
  float* outp = (float*)d_out;

  hipMemsetAsync(zp, 0, 4096, stream);
  kwconv<<<68, 256, 0, stream>>>(wq, wkv, wp, w1, w2, wdw, wswz, wdwT);
  kattn<<<4096, 256, 0, stream>>>(x, g1, b1, bq, bkv, rpb, bp, wswz, x2);
  kleff1<<<4096, 256, 0, stream>>>(x2, g2, b2, bl1, wswz, h1);
  kleff2<<<4096, 256, 0, stream>>>(h1, wdwT, bdw, bl2, wswz, x2, zp, outp);
}

// Round 8
// 565.787 us; speedup vs baseline: 1.1595x; 1.0155x over previous
//
#include <hip/hip_runtime.h>
#include <math.h>

// ---------------------------------------------------------------------------
// Swin/Uformer block, MI355X. Sizes fixed: B=4 H=W=256 C=96 NH=3 HD=32 WIN=8
// N=64 HID=384. 3 kernels:
//   kwconv : f32 weights -> bf16 pre-swizzled B-frags; + wdw transposed f32
//   kattn  : LN1 + QKV + window-attn (+rpb bias, softmax) + proj + residual
//   kleff  : FUSED LN2 + FC1 + GELU + depthwise3x3 + GELU + FC2 + residual.
//            Per block: recompute LN2/FC1 for the 10x10 halo into LDS
//            (channel-halved), conv reads LDS (no divergent global gather,
//            no h1 round-trip), FC2 accumulates in per-lane A-fragments.
// MFMA 16x16x32 bf16 layouts used throughout:
//   A-frag: lane = (m%16) + 16*(k%32/8), elem = k%8
//   B-frag: lane = (n%16) + 16*(k%32/8), elem = k%8
//   C/D   : row  = 4*(lane/16)+reg, col = lane%16
// ---------------------------------------------------------------------------

typedef __attribute__((ext_vector_type(8))) short bf16x8;
typedef __attribute__((ext_vector_type(4))) float f32x4;
typedef __attribute__((ext_vector_type(2))) float f32x2;

#define MFMA(a, b, c) __builtin_amdgcn_mfma_f32_16x16x32_bf16((a), (b), (c), 0, 0, 0)

// weight tile bases (in 16x32 B-fragment tiles of 64 lanes * 16B)
#define WQ_T 0
#define WKV_T 18
#define WP_T 54
#define W1_T 72
#define W2_T 144
#define NTILES_TOT 216

__device__ __forceinline__ unsigned short f2bf(float f) {
  union { float f; unsigned u; } v; v.f = f;
  unsigned r = v.u + 0x7FFFu + ((v.u >> 16) & 1u);
  return (unsigned short)(r >> 16);
}
__device__ __forceinline__ float asf(unsigned u) {
  union { unsigned u; float f; } v; v.u = u; return v.f;
}
__device__ __forceinline__ unsigned cvtpk_bf16(float lo, float hi) {
  unsigned r;
  asm("v_cvt_pk_bf16_f32 %0, %1, %2" : "=v"(r) : "v"(lo), "v"(hi));
  return r;
}
// gelu(x) = x * sigmoid(2z), z = 0.7978845608 x (1 + 0.044715 x^2)
__device__ __forceinline__ float gelu(float x) {
  float t = x * x;
  float w = x * fmaf(t, -0.07135941f, -1.5957691f);   // -2z
  float a = __expf(w);
  return x * __builtin_amdgcn_rcpf(1.f + a);
}
__device__ __forceinline__ bf16x8 ldw(const unsigned short* wswz, int tile, int lane) {
  return *(const bf16x8*)(wswz + ((size_t)(tile * 64 + lane)) * 8);
}
__device__ __forceinline__ int xcd_swz(int bid) {   // 4096 % 8 == 0 -> bijective
  return (bid & 7) * 512 + (bid >> 3);
}

// --------------------------- weight convert/swizzle ------------------------
__global__ void kwconv(const float* __restrict__ wq, const float* __restrict__ wkv,
                       const float* __restrict__ wp, const float* __restrict__ w1,
                       const float* __restrict__ w2, const float* __restrict__ wdw,
                       unsigned short* __restrict__ wswz, float* __restrict__ wdwT) {
  int tid = blockIdx.x * 256 + threadIdx.x;
  if (tid >= NTILES_TOT * 64) {
    int i = tid - NTILES_TOT * 64;
    if (i < 3456) {                       // wdw (384,1,3,3) -> wdwT [tap][384]
      int ch = i % 384, tap = i / 384;
      wdwT[tap * 384 + ch] = wdw[ch * 9 + tap];
    }
    return;
  }
  int e = tid; const float* src; int N, NT;
  if (e < 1152)      { src = wq;  N = 96;  NT = 6; }
  else if (e < 3456) { src = wkv; N = 192; NT = 12; e -= 1152; }
  else if (e < 4608) { src = wp;  N = 96;  NT = 6;  e -= 3456; }
  else if (e < 9216) { src = w1;  N = 384; NT = 24; e -= 4608; }
  else               { src = w2;  N = 96;  NT = 6;  e -= 9216; }
  int lane = e & 63, t = e >> 6;
  int nt = t % NT, kt = t / NT;
  int k0 = kt * 32 + (lane >> 4) * 8;
  int n = nt * 16 + (lane & 15);
  unsigned short* dst = wswz + (size_t)tid * 8;
#pragma unroll
  for (int i = 0; i < 8; ++i) dst[i] = f2bf(src[(size_t)(k0 + i) * N + n]);
}

// --------------------------- attention block -------------------------------
__global__ __launch_bounds__(256) void kattn(
    const float* __restrict__ x, const float* __restrict__ g1, const float* __restrict__ b1,
    const float* __restrict__ bq, const float* __restrict__ bkv,
    const float* __restrict__ rpb, const float* __restrict__ bp,
    const unsigned short* __restrict__ wswz, float* __restrict__ x2) {
  __shared__ __align__(16) unsigned short sm0[4 * 3 * 64 * 8];   // xn_swz, later y_swz (12KB)
  __shared__ __align__(16) unsigned short sm1[24 * 64 * 8];      // q(12 tiles)+k(12) then p(24) (24KB)
  __shared__ __align__(16) unsigned short sm2[3 * 2 * 2 * 64 * 8]; // v (12KB)

  const int tid = threadIdx.x;
  const int lane = tid & 63, w = tid >> 6;
  const int lrow = lane >> 4, lcol = lane & 15;
  const int wi = xcd_swz(blockIdx.x);
  const int b = wi >> 10, wy = (wi >> 5) & 31, wx = wi & 31;

  long rowoff[4];
#pragma unroll
  for (int r = 0; r < 4; ++r) {
    int m = w * 16 + lrow * 4 + r;
    int gy = wy * 8 + (m >> 3), gx = wx * 8 + (m & 7);
    rowoff[r] = ((long)b * 65536 + gy * 256 + gx) * 96;
  }

  // ---- phase 0: load x (C/D-layout regs), LN1, write xn to A-swz LDS
  float xv[4][6], xn[4][6], gv[6], bv[6];
#pragma unroll
  for (int nt = 0; nt < 6; ++nt) {
    int c = nt * 16 + lcol;
    gv[nt] = g1[c]; bv[nt] = b1[c];
#pragma unroll
    for (int r = 0; r < 4; ++r) xv[r][nt] = x[rowoff[r] + c];
  }
#pragma unroll
  for (int r = 0; r < 4; ++r) {
    float s = 0.f, sq = 0.f;
#pragma unroll
    for (int nt = 0; nt < 6; ++nt) { float v = xv[r][nt]; s += v; sq += v * v; }
#pragma unroll
    for (int off = 1; off <= 8; off <<= 1) { s += __shfl_xor(s, off, 64); sq += __shfl_xor(sq, off, 64); }
    float mean = s * (1.f / 96.f);
    float var = sq * (1.f / 96.f) - mean * mean;
    float rs = rsqrtf(var + 1e-5f);
#pragma unroll
    for (int nt = 0; nt < 6; ++nt) xn[r][nt] = (xv[r][nt] - mean) * rs * gv[nt] + bv[nt];
  }
#pragma unroll
  for (int r = 0; r < 4; ++r) {
    int mm = lrow * 4 + r;
#pragma unroll
    for (int nt = 0; nt < 6; ++nt) {
      int c = nt * 16 + lcol;
      int kt = c >> 5;
      int lanew = mm + (((c & 31) >> 3) << 4);
      sm0[((w * 3 + kt) * 64 + lanew) * 8 + (c & 7)] = f2bf(xn[r][nt]);
    }
  }
  __syncthreads();

  // ---- phase 1: QKV GEMM (M=64 N=288 K=96), wave w owns m-tile w
  bf16x8 af[3];
#pragma unroll
  for (int kt = 0; kt < 3; ++kt) af[kt] = *(const bf16x8*)(sm0 + ((w * 3 + kt) * 64 + lane) * 8);
  for (int nt = 0; nt < 18; ++nt) {
    f32x4 acc = {0.f, 0.f, 0.f, 0.f};
#pragma unroll
    for (int kt = 0; kt < 3; ++kt) {
      int tile = (nt < 6) ? (WQ_T + kt * 6 + nt) : (WKV_T + kt * 12 + (nt - 6));
      acc = MFMA(af[kt], ldw(wswz, tile, lane), acc);
    }
    int c = nt * 16 + lcol;
#pragma unroll
    for (int r = 0; r < 4; ++r) {
      int m = w * 16 + lrow * 4 + r;
      float val = acc[r];
      if (c < 96) {                 // q (pre-scaled)
        val = (val + bq[c]) * 0.17677669529663687f;
        int head = c >> 5, d = c & 31;
        sm1[((head * 4 + w) * 64 + (m & 15) + ((d >> 3) << 4)) * 8 + (d & 7)] = f2bf(val);
      } else if (c < 192) {         // k
        int kc = c - 96;
        val += bkv[kc];
        int head = kc >> 5, d = kc & 31;
        sm1[((12 + head * 4 + w) * 64 + (m & 15) + ((d >> 3) << 4)) * 8 + (d & 7)] = f2bf(val);
      } else {                      // v (B-frag layout: k-dim = key token)
        int vc = c - 192;
        val += bkv[96 + vc];
        int head = vc >> 5, d = vc & 31;
        int ktile = m >> 5, nt2 = d >> 4;
        sm2[(((head * 2 + ktile) * 2 + nt2) * 64 + (d & 15) + (((m & 31) >> 3) << 4)) * 8 + (m & 7)] = f2bf(val);
      }
    }
  }
  __syncthreads();

  // ---- phase 2: scores. unit u=(head,mtq); wave w owns u = 3w..3w+2
  f32x4 sc[3][4];
#pragma unroll
  for (int uu = 0; uu < 3; ++uu) {
    int u = w * 3 + uu, head = u >> 2, mtq = u & 3;
    bf16x8 aq = *(const bf16x8*)(sm1 + ((head * 4 + mtq) * 64 + lane) * 8);
#pragma unroll
    for (int nt = 0; nt < 4; ++nt) {
      bf16x8 bk = *(const bf16x8*)(sm1 + ((12 + head * 4 + nt) * 64 + lane) * 8);
      f32x4 z = {0.f, 0.f, 0.f, 0.f};
      sc[uu][nt] = MFMA(aq, bk, z);
    }
  }
  __syncthreads();   // all q/k reads done; sm1 may now be overwritten with P

  // ---- phase 3: +rpb bias, softmax (in-register), write P to A-swz LDS
#pragma unroll
  for (int uu = 0; uu < 3; ++uu) {
    int u = w * 3 + uu, head = u >> 2, mtq = u & 3;
#pragma unroll
    for (int nt = 0; nt < 4; ++nt) {
      int ktok = nt * 16 + lcol;
#pragma unroll
      for (int r = 0; r < 4; ++r) {
        int qtok = mtq * 16 + lrow * 4 + r;
        int dy = (qtok >> 3) - (ktok >> 3) + 7;
        int dx = (qtok & 7) - (ktok & 7) + 7;
        sc[uu][nt][r] += rpb[(dy * 15 + dx) * 3 + head];
      }
    }
#pragma unroll
    for (int r = 0; r < 4; ++r) {
      float mx = fmaxf(fmaxf(sc[uu][0][r], sc[uu][1][r]), fmaxf(sc[uu][2][r], sc[uu][3][r]));
#pragma unroll
      for (int off = 1; off <= 8; off <<= 1) mx = fmaxf(mx, __shfl_xor(mx, off, 64));
      float p[4], sum = 0.f;
#pragma unroll
      for (int nt = 0; nt < 4; ++nt) { p[nt] = __expf(sc[uu][nt][r] - mx); sum += p[nt]; }
#pragma unroll
      for (int off = 1; off <= 8; off <<= 1) sum += __shfl_xor(sum, off, 64);
      float inv = 1.f / sum;
#pragma unroll
      for (int nt = 0; nt < 4; ++nt) sc[uu][nt][r] = p[nt] * inv;
    }
#pragma unroll
    for (int nt = 0; nt < 4; ++nt) {
      int ktok = nt * 16 + lcol;
      int ktile = ktok >> 5, lhi = (ktok & 31) >> 3;
#pragma unroll
      for (int r = 0; r < 4; ++r) {
        int mm = lrow * 4 + r;
        sm1[(((head * 4 + mtq) * 2 + ktile) * 64 + mm + (lhi << 4)) * 8 + (ktok & 7)] = f2bf(sc[uu][nt][r]);
      }
    }
  }
  __syncthreads();

  // ---- phase 4: PV, write y to A-swz LDS (reuse sm0; head = k-tile)
#pragma unroll
  for (int uu = 0; uu < 3; ++uu) {
    int u = w * 3 + uu, head = u >> 2, mtq = u & 3;
#pragma unroll
    for (int nt2 = 0; nt2 < 2; ++nt2) {
      f32x4 acc = {0.f, 0.f, 0.f, 0.f};
#pragma unroll
      for (int ktile = 0; ktile < 2; ++ktile) {
        bf16x8 ap = *(const bf16x8*)(sm1 + (((head * 4 + mtq) * 2 + ktile) * 64 + lane) * 8);
        bf16x8 bv8 = *(const bf16x8*)(sm2 + (((head * 2 + ktile) * 2 + nt2) * 64 + lane) * 8);
        acc = MFMA(ap, bv8, acc);
      }
      int d0 = nt2 * 16 + lcol;
#pragma unroll
      for (int r = 0; r < 4; ++r) {
        int mm = lrow * 4 + r;
        sm0[((mtq * 3 + head) * 64 + mm + ((d0 >> 3) << 4)) * 8 + (d0 & 7)] = f2bf(acc[r]);
      }
    }
  }
  __syncthreads();

  // ---- phase 5: proj + bias + residual -> x2
  bf16x8 ay[3];
#pragma unroll
  for (int kt = 0; kt < 3; ++kt) ay[kt] = *(const bf16x8*)(sm0 + ((w * 3 + kt) * 64 + lane) * 8);
#pragma unroll
  for (int nt = 0; nt < 6; ++nt) {
    f32x4 acc = {0.f, 0.f, 0.f, 0.f};
#pragma unroll
    for (int kt = 0; kt < 3; ++kt) acc = MFMA(ay[kt], ldw(wswz, WP_T + kt * 6 + nt, lane), acc);
    int c = nt * 16 + lcol;
    float bpc = bp[c];
#pragma unroll
    for (int r = 0; r < 4; ++r) x2[rowoff[r] + c] = acc[r] + bpc + xv[r][nt];
  }
}

// ---------------- FUSED LeFF: LN2+FC1+GELU+dwconv+GELU+FC2+residual --------
// Per block (8x8 window): LN2+FC1 recomputed for the 10x10 halo (112-token
// padded M, 7 m-tiles), channel-halved (192 ch per half) into h_lds; conv
// reads h_lds per-lane into MFMA A-frags; FC2 accumulates over both halves.
__device__ __forceinline__ bf16x8 dwconv_gelu(const uint4* cur,
    const float* wsh, const float* wb, int ch) {
  f32x2 a2[4];
#pragma unroll
  for (int j = 0; j < 4; ++j) a2[j] = (f32x2){0.f, 0.f};
#pragma unroll
  for (int t = 0; t < 9; ++t) {
    f32x4 wlo = *(const f32x4*)(wsh + t * 384 + ch);
    f32x4 whi = *(const f32x4*)(wsh + t * 384 + ch + 4);
    const unsigned* du = (const unsigned*)(cur + t);
    f32x2 d0 = { asf(du[0] << 16), asf(du[0] & 0xffff0000u) };
    f32x2 d1 = { asf(du[1] << 16), asf(du[1] & 0xffff0000u) };
    f32x2 d2 = { asf(du[2] << 16), asf(du[2] & 0xffff0000u) };
    f32x2 d3 = { asf(du[3] << 16), asf(du[3] & 0xffff0000u) };
    f32x2 w0 = {wlo.x, wlo.y}, w1 = {wlo.z, wlo.w};
    f32x2 w2v = {whi.x, whi.y}, w3 = {whi.z, whi.w};
    a2[0] += d0 * w0; a2[1] += d1 * w1; a2[2] += d2 * w2v; a2[3] += d3 * w3;
  }
  f32x4 blo = *(const f32x4*)(wb + ch);
  f32x4 bhi = *(const f32x4*)(wb + ch + 4);
  union { unsigned u[4]; bf16x8 v; } pk;
  pk.u[0] = cvtpk_bf16(gelu(a2[0].x + blo.x), gelu(a2[0].y + blo.y));
  pk.u[1] = cvtpk_bf16(gelu(a2[1].x + blo.z), gelu(a2[1].y + blo.w));
  pk.u[2] = cvtpk_bf16(gelu(a2[2].x + bhi.x), gelu(a2[2].y + bhi.y));
  pk.u[3] = cvtpk_bf16(gelu(a2[3].x + bhi.z), gelu(a2[3].y + bhi.w));
  return pk.v;
}

__global__ __launch_bounds__(256) void kleff(
    const float* __restrict__ x2, const float* __restrict__ g2,
    const float* __restrict__ b2, const float* __restrict__ bl1,
    const float* __restrict__ wdwT, const float* __restrict__ bdw,
    const float* __restrict__ bl2, const unsigned short* __restrict__ wswz,
    float* __restrict__ out) {
  __shared__ __align__(16) unsigned short xn_lds[21 * 64 * 8];  // 21.5KB A-frags (7mt x 3kt)
  __shared__ __align__(16) unsigned short h_lds[100 * 200];     // 40KB halo FC1-out half
  __shared__ __align__(16) float wsh[9 * 384 + 384];            // 15.4KB dw taps + bias

  const int tid = threadIdx.x, lane = tid & 63, w = tid >> 6;
  const int lrow = lane >> 4, lcol = lane & 15;
  const int bid = xcd_swz(blockIdx.x);
  const int b = bid >> 10, ty0 = ((bid >> 5) & 31) * 8, tx0 = (bid & 31) * 8;

  // stage dw weights + bias once (960 float4)
  for (int i = tid; i < 960; i += 256) {
    float4 v = (i < 864) ? ((const float4*)wdwT)[i] : ((const float4*)bdw)[i - 864];
    ((float4*)wsh)[i] = v;
  }
  const float* wb = wsh + 3456;

  const int mt1 = (w < 3) ? 4 + w : 3;   // 7 m-tiles; w=3 duplicates tile 3
  unsigned vmask = 0;                    // halo-token in-image bits (mi*4+r)

  // ---- phase A: LN2 over 10x10 halo tokens -> xn A-frag LDS
  {
    float gv[6], bv[6];
#pragma unroll
    for (int nt = 0; nt < 6; ++nt) { gv[nt] = g2[nt * 16 + lcol]; bv[nt] = b2[nt * 16 + lcol]; }
#pragma unroll
    for (int mi = 0; mi < 2; ++mi) {
      const int mt = mi ? mt1 : w;
      float xv[4][6];
#pragma unroll
      for (int r = 0; r < 4; ++r) {
        int t = mt * 16 + lrow * 4 + r;
        int hy = (t * 205) >> 11, hx = t - hy * 10;     // t/10, t%10 for t<112
        int gy = ty0 - 1 + hy, gx = tx0 - 1 + hx;
        bool ok = ((unsigned)gy < 256u) && ((unsigned)gx < 256u) && (t < 100);
        vmask |= (ok ? 1u : 0u) << (mi * 4 + r);
        int cgy = min(max(gy, 0), 255), cgx = min(max(gx, 0), 255);
        long roff = ((long)b * 65536 + cgy * 256 + cgx) * 96;
#pragma unroll
        for (int nt = 0; nt < 6; ++nt) xv[r][nt] = x2[roff + nt * 16 + lcol];
      }
#pragma unroll
      for (int r = 0; r < 4; ++r) {
        float s = 0.f, sq = 0.f;
#pragma unroll
        for (int nt = 0; nt < 6; ++nt) { float v = xv[r][nt]; s += v; sq += v * v; }
#pragma unroll
        for (int off = 1; off <= 8; off <<= 1) { s += __shfl_xor(s, off, 64); sq += __shfl_xor(sq, off, 64); }
        float mean = s * (1.f / 96.f);
        float var = sq * (1.f / 96.f) - mean * mean;
        float rs = rsqrtf(var + 1e-5f);
        int mm = lrow * 4 + r;
#pragma unroll
        for (int nt = 0; nt < 6; ++nt) {
          float val = (xv[r][nt] - mean) * rs * gv[nt] + bv[nt];
          int c = nt * 16 + lcol;
          int kt = c >> 5;
          int lanew = mm + (((c & 31) >> 3) << 4);
          xn_lds[((mt * 3 + kt) * 64 + lanew) * 8 + (c & 7)] = f2bf(val);
        }
      }
    }
  }
  __syncthreads();

  // persistent FC2 accumulators (interior m-tile w per wave)
  f32x4 acc[6];
#pragma unroll
  for (int nt = 0; nt < 6; ++nt) { f32x4 z = {0.f, 0.f, 0.f, 0.f}; acc[nt] = z; }

  // A-frags for FC1 (both owned m-tiles)
  bf16x8 af0[3], af1[3];
#pragma unroll
  for (int kt = 0; kt < 3; ++kt) {
    af0[kt] = *(const bf16x8*)(xn_lds + ((w * 3 + kt) * 64 + lane) * 8);
    af1[kt] = *(const bf16x8*)(xn_lds + ((mt1 * 3 + kt) * 64 + lane) * 8);
  }

  const int pint = w * 16 + lcol;         // lane's interior pixel 0..63
  const int iy = pint >> 3, ix = pint & 7;
  const int cg0 = lrow * 8;               // channel sub-offset within k-tile
  const int hbase = ((iy * 10) + ix) * 200 + cg0;  // h_lds elem offset, tap(0,0)

#pragma unroll
  for (int H = 0; H < 2; ++H) {
    // ---- FC1 half H: 12 n-tiles, write gelu -> h_lds (OOI tokens zeroed)
#pragma unroll
    for (int ntl = 0; ntl < 12; ++ntl) {
      int nt = H * 12 + ntl;
      bf16x8 wf0 = ldw(wswz, W1_T + 0 * 24 + nt, lane);
      bf16x8 wf1 = ldw(wswz, W1_T + 1 * 24 + nt, lane);
      bf16x8 wf2 = ldw(wswz, W1_T + 2 * 24 + nt, lane);
      float bb = bl1[H * 192 + ntl * 16 + lcol];
      f32x4 a0 = {0.f, 0.f, 0.f, 0.f}, a1 = {0.f, 0.f, 0.f, 0.f};
      a0 = MFMA(af0[0], wf0, a0); a0 = MFMA(af0[1], wf1, a0); a0 = MFMA(af0[2], wf2, a0);
      a1 = MFMA(af1[0], wf0, a1); a1 = MFMA(af1[1], wf1, a1); a1 = MFMA(af1[2], wf2, a1);
#pragma unroll
      for (int r = 0; r < 4; ++r) {
        int t0 = w * 16 + lrow * 4 + r;
        if (t0 < 100) {
          unsigned short hv = ((vmask >> r) & 1u) ? f2bf(gelu(a0[r] + bb)) : (unsigned short)0;
          h_lds[t0 * 200 + ntl * 16 + lcol] = hv;
        }
        int t1 = mt1 * 16 + lrow * 4 + r;
        if (t1 < 100) {
          unsigned short hv = ((vmask >> (4 + r)) & 1u) ? f2bf(gelu(a1[r] + bb)) : (unsigned short)0;
          h_lds[t1 * 200 + ntl * 16 + lcol] = hv;
        }
      }
    }
    __syncthreads();

    // ---- conv + FC2 half H: per-lane 9-tap from h_lds into A-frag, MFMA
#pragma unroll
    for (int ktl = 0; ktl < 6; ++ktl) {
      int chl = ktl * 32 + cg0;           // channel within half [0,192)
      uint4 dv[9];
#pragma unroll
      for (int dy = 0; dy < 3; ++dy)
#pragma unroll
        for (int dx = 0; dx < 3; ++dx)
          dv[dy * 3 + dx] = *(const uint4*)(h_lds + hbase + dy * 2000 + dx * 200 + ktl * 32);
      bf16x8 pk = dwconv_gelu(dv, wsh, wb, H * 192 + chl);
      int ktg = H * 6 + ktl;
#pragma unroll
      for (int nt = 0; nt < 6; ++nt)
        acc[nt] = MFMA(pk, ldw(wswz, W2_T + ktg * 6 + nt, lane), acc[nt]);
    }
    __syncthreads();   // before next half overwrites h_lds
  }

  // ---- epilogue: + bl2 + residual(x2) -> out (interior tokens)
#pragma unroll
  for (int nt = 0; nt < 6; ++nt) {
    int c = nt * 16 + lcol;
    float bb = bl2[c];
#pragma unroll
    for (int r = 0; r < 4; ++r) {
      int mm = w * 16 + lrow * 4 + r;
      int oy = ty0 + (mm >> 3), ox = tx0 + (mm & 7);
      long row = (long)b * 65536 + oy * 256 + ox;
      out[row * 96 + c] = acc[nt][r] + bb + x2[row * 96 + c];
    }
  }
}

// ---------------------------------------------------------------------------
extern "C" void kernel_launch(void* const* d_in, const int* in_sizes, int n_in,
                              void* d_out, int out_size, void* d_ws, size_t ws_size,
                              hipStream_t stream) {
  const float* x   = (const float*)d_in[0];
  const float* g1  = (const float*)d_in[1];
  const float* b1  = (const float*)d_in[2];
  const float* wq  = (const float*)d_in[3];
  const float* bq  = (const float*)d_in[4];
  const float* wkv = (const float*)d_in[5];
  const float* bkv = (const float*)d_in[6];
  const float* rpb = (const float*)d_in[7];
  const float* wp  = (const float*)d_in[8];
  const float* bp  = (const float*)d_in[9];
  const float* g2  = (const float*)d_in[10];
  const float* b2  = (const float*)d_in[11];
  const float* w1  = (const float*)d_in[12];
  const float* bl1 = (const float*)d_in[13];
  const float* wdw = (const float*)d_in[14];
  const float* bdw = (const float*)d_in[15];
  const float* w2  = (const float*)d_in[16];
  const float* bl2 = (const float*)d_in[17];

  char* ws = (char*)d_ws;
  unsigned short* wswz = (unsigned short*)ws;                      // 221 KB
  float* wdwT = (float*)(ws + (size_t)(256 << 10));                // 13.8 KB @256KB
  float* x2 = (float*)(ws + (size_t)(4 << 20));                    // 100.7 MB
  float* outp = (float*)d_out;

  kwconv<<<68, 256, 0, stream>>>(wq, wkv, wp, w1, w2, wdw, wswz, wdwT);
  kattn<<<4096, 256, 0, stream>>>(x, g1, b1, bq, bkv, rpb, bp, wswz, x2);
  kleff<<<4096, 256, 0, stream>>>(x2, g2, b2, bl1, wdwT, bdw, bl2, wswz, outp);
}